// Round 3
// baseline (949.609 us; speedup 1.0000x reference)
//
#include <hip/hip_runtime.h>
#include <hip/hip_bf16.h>

#define BB 8
#define NN 16384
#define SS 1024
#define NSMP 64
#define DD 128
#define R2 0.04f
#define EPSV 1e-5f

typedef _Float16 half2t __attribute__((ext_vector_type(2)));
typedef _Float16 half8t __attribute__((ext_vector_type(8)));
typedef float f32x4 __attribute__((ext_vector_type(4)));

// ---- compact workspace layout (bytes) ----
#define O_PT    0ull                 // pointsT fp16: 8*16384*128*2 = 33,554,432
#define O_IDX   33554432ull          // idx int32: 8192*64*4 = 2,097,152
#define O_MAXB  35651584ull          // 8192*256*4 = 8,388,608
#define O_MINB  44040192ull          // 8,388,608
#define O_W0T   52428800ull          // W0h fp16 [128][136] = 34,816
#define O_W1T   52463616ull          // W1h fp16 [128][136] = 34,816
#define O_W2T   52498432ull          // W2h fp16 [256][136] = 69,632
#define O_PS0   52568064ull          // 128*256*4 = 131,072 (1MB zero region starts here)
#define O_PQ0   52699136ull
#define O_PS1   52830208ull
#define O_PQ1   52961280ull
#define O_PS2   53092352ull          // 256*256*4 = 262,144
#define O_PQ2   53354496ull
#define O_SC0   53616640ull
#define O_SH0   53617152ull
#define O_SC1   53617664ull
#define O_SH1   53618176ull
#define O_SC2   53618688ull
#define O_SH2   53619712ull
#define WS_NEEDED 53620736ull

#define OUT_XYZ 0
#define OUT_FEAT 24576
#define OUT_FPS (24576 + 2097152)

// points [B,D,N] fp32 -> pointsT [B,N,D] fp16. 64n x 64c tile; half8 (16B) stores.
__global__ __launch_bounds__(256) void k_transpose_pts(const float* __restrict__ pts,
                                                       _Float16* __restrict__ ptsT) {
  __shared__ float tile[64][65];
  int b = blockIdx.z;
  int n0 = blockIdx.x * 64, c0 = blockIdx.y * 64;
  int t = threadIdx.x;
  int cg = t >> 6, ln = t & 63;
#pragma unroll
  for (int k = 0; k < 16; k++) {
    int c = cg * 16 + k;
    tile[c][ln] = pts[((size_t)b * DD + c0 + c) * NN + n0 + ln];
  }
  __syncthreads();
  int n = t >> 2, sub = t & 3;
#pragma unroll
  for (int j = 0; j < 2; j++) {
    int cb = sub * 16 + j * 8;
    half8t h;
#pragma unroll
    for (int k = 0; k < 8; k++) h[k] = (_Float16)tile[cb + k][n];
    *(half8t*)(ptsT + ((size_t)b * NN + n0 + n) * DD + c0 + cb) = h;
  }
}

// weights -> fp16, [out][in] stride 136, zero-padded; also zeroes the 1MB stats region.
// W0 channels remapped: xh has feats at c=0..127, relxyz at 128..130
__global__ __launch_bounds__(256) void k_wt(const float* __restrict__ W0, const float* __restrict__ W1,
                                            const float* __restrict__ W2, _Float16* __restrict__ W0h,
                                            _Float16* __restrict__ W1h, _Float16* __restrict__ W2h,
                                            float* __restrict__ zreg) {
  int id = blockIdx.x * 256 + threadIdx.x;
  if (id < 65536) {
    f32x4 z = {0.f, 0.f, 0.f, 0.f};
    ((f32x4*)zreg)[id] = z;
  }
  const int T0 = 128 * 136, T1 = 128 * 136, T2 = 256 * 136;
  if (id < T0) {
    int o = id / 136, c = id % 136;
    float v = 0.f;
    if (c < 131) {
      int c0 = (c < 128) ? (c + 3) : (c - 128);
      v = W0[o * 131 + c0];
    }
    W0h[id] = (_Float16)v;
  } else if (id < T0 + T1) {
    int j = id - T0;
    int o = j / 136, c = j % 136;
    W1h[j] = (_Float16)((c < 128) ? W1[o * 128 + c] : 0.f);
  } else if (id < T0 + T1 + T2) {
    int j = id - T0 - T1;
    int o = j / 136, c = j % 136;
    W2h[j] = (_Float16)((c < 128) ? W2[o * 128 + c] : 0.f);
  }
}

// fallback when workspace undersized
__global__ __launch_bounds__(256) void k_newxyz(const float* __restrict__ xyz, const int* __restrict__ fps,
                                                float* __restrict__ out) {
  int id = blockIdx.x * 256 + threadIdx.x;  // B*S
  int fi = fps[id];
  int b = id >> 10;
  const float* p = xyz + ((size_t)b * NN + fi) * 3;
  float* o = out + OUT_XYZ + (size_t)id * 3;
  o[0] = p[0]; o[1] = p[1]; o[2] = p[2];
  out[OUT_FPS + id] = (float)fi;
}

// one wave per (b,s): first-NS valid indices ascending, pad with first valid.
// Also emits new_xyz and fps passthrough outputs.
__global__ __launch_bounds__(256) void k_ballq(const float* __restrict__ xyz, const int* __restrict__ fps,
                                               int* __restrict__ idxb, float* __restrict__ out) {
  int w = (blockIdx.x * 256 + threadIdx.x) >> 6;
  int lane = threadIdx.x & 63;
  int b = w >> 10;
  int fi = fps[w];
  const float* cp = xyz + ((size_t)b * NN + fi) * 3;
  float cx = cp[0], cy = cp[1], cz = cp[2];
  if (lane < 3) out[OUT_XYZ + (size_t)w * 3 + lane] = (lane == 0) ? cx : ((lane == 1) ? cy : cz);
  if (lane == 3) out[OUT_FPS + w] = (float)fi;
  float A = __fadd_rn(__fadd_rn(__fmul_rn(cx, cx), __fmul_rn(cy, cy)), __fmul_rn(cz, cz));
  const float* xb = xyz + (size_t)b * NN * 3;
  int cnt = 0, firstn = -1;
  int* myidx = idxb + (size_t)w * NSMP;
  for (int nb = 0; nb < NN && cnt < NSMP; nb += 64) {
    int n = nb + lane;
    float px = xb[n * 3], py = xb[n * 3 + 1], pz = xb[n * 3 + 2];
    float Bv = __fadd_rn(__fadd_rn(__fmul_rn(px, px), __fmul_rn(py, py)), __fmul_rn(pz, pz));
    float dot = __fadd_rn(__fadd_rn(__fmul_rn(cx, px), __fmul_rn(cy, py)), __fmul_rn(cz, pz));
    float d = __fsub_rn(__fadd_rn(A, Bv), __fmul_rn(2.0f, dot));
    bool valid = !(d > R2);
    unsigned long long mask = __ballot(valid);
    if (firstn < 0 && mask) firstn = nb + __builtin_ctzll(mask);
    int prefix = __popcll(mask & ((1ull << lane) - 1ull));
    int pos = cnt + prefix;
    if (valid && pos < NSMP) myidx[pos] = n;
    cnt += __popcll(mask);
    if (cnt > NSMP) cnt = NSMP;
  }
  if (lane >= cnt) myidx[lane] = firstn;
}

// ---------- shared device pieces ----------

__device__ __forceinline__ void load_ball(const float* __restrict__ xyz,
                                          const _Float16* __restrict__ ptsT,
                                          const int* __restrict__ fps, const int* __restrict__ idxb,
                                          int bs, int b, int t, _Float16* xh, int* smidx, float* smc) {
  if (t < 64) smidx[t] = idxb[(size_t)bs * 64 + t];
  if (t < 3) {
    int fi = fps[bs];
    smc[t] = xyz[((size_t)b * NN + fi) * 3 + t];
  }
  __syncthreads();
  {
    int row = t >> 2, q = t & 3;
    int n = smidx[row];
    const half8t* src = (const half8t*)(ptsT + ((size_t)b * NN + n) * DD);
#pragma unroll
    for (int i = 0; i < 4; i++) {
      int j = q + i * 4;
      *(half8t*)(xh + row * 136 + j * 8) = src[j];
    }
  }
  if (t < 64) {
    int n = smidx[t];
    const float* p = xyz + ((size_t)b * NN + n) * 3;
    xh[t * 136 + 128] = (_Float16)(p[0] - smc[0]);
    xh[t * 136 + 129] = (_Float16)(p[1] - smc[1]);
    xh[t * 136 + 130] = (_Float16)(p[2] - smc[2]);
  }
  __syncthreads();
}

__device__ __forceinline__ void mfma_l0(const _Float16* xh, const _Float16* __restrict__ W0h,
                                        const float* __restrict__ b0, int m0, int lr, int lk,
                                        f32x4* acc) {
  half8t afr[4];
#pragma unroll
  for (int kt = 0; kt < 4; kt++)
    afr[kt] = *(const half8t*)(xh + (m0 + lr) * 136 + kt * 32 + lk * 8);
#pragma unroll
  for (int nt = 0; nt < 8; nt++) {
    float bv = b0[nt * 16 + lr];
    f32x4 cv = {bv, bv, bv, bv};
    acc[nt] = cv;
  }
#pragma unroll
  for (int kt = 0; kt < 4; kt++) {
#pragma unroll
    for (int nt = 0; nt < 8; nt++) {
      half8t bw = *(const half8t*)(W0h + (nt * 16 + lr) * 136 + kt * 32 + lk * 8);
      acc[nt] = __builtin_amdgcn_mfma_f32_16x16x32_f16(afr[kt], bw, acc[nt], 0, 0, 0);
    }
  }
  float xr[4][3];
#pragma unroll
  for (int r = 0; r < 4; r++) {
    int m = m0 + lk * 4 + r;
    xr[r][0] = (float)xh[m * 136 + 128];
    xr[r][1] = (float)xh[m * 136 + 129];
    xr[r][2] = (float)xh[m * 136 + 130];
  }
#pragma unroll
  for (int nt = 0; nt < 8; nt++) {
    const _Float16* wp = W0h + (nt * 16 + lr) * 136 + 128;
    float w0 = (float)wp[0], w1 = (float)wp[1], w2 = (float)wp[2];
#pragma unroll
    for (int r = 0; r < 4; r++)
      acc[nt][r] += xr[r][0] * w0 + xr[r][1] * w1 + xr[r][2] * w2;
  }
}

template <int NT>
__device__ __forceinline__ void mfma_lx(const _Float16* xh, const _Float16* __restrict__ Wh,
                                        const float* __restrict__ bias, int m0, int lr, int lk,
                                        f32x4* acc) {
  half8t afr[4];
#pragma unroll
  for (int kt = 0; kt < 4; kt++)
    afr[kt] = *(const half8t*)(xh + (m0 + lr) * 136 + kt * 32 + lk * 8);
#pragma unroll
  for (int nt = 0; nt < NT; nt++) {
    float bv = bias[nt * 16 + lr];
    f32x4 cv = {bv, bv, bv, bv};
    acc[nt] = cv;
  }
#pragma unroll
  for (int kt = 0; kt < 4; kt++) {
#pragma unroll
    for (int nt = 0; nt < NT; nt++) {
      half8t bw = *(const half8t*)(Wh + (nt * 16 + lr) * 136 + kt * 32 + lk * 8);
      acc[nt] = __builtin_amdgcn_mfma_f32_16x16x32_f16(afr[kt], bw, acc[nt], 0, 0, 0);
    }
  }
}

__device__ __forceinline__ void store_act(_Float16* xh, const float* __restrict__ sc,
                                          const float* __restrict__ sh, int m0, int lr, int lk,
                                          const f32x4* acc) {
#pragma unroll
  for (int nt = 0; nt < 8; nt++) {
    int col = nt * 16 + lr;
    float a = sc[col], c = sh[col];
#pragma unroll
    for (int r = 0; r < 4; r++) {
      float v = fmaxf(fmaf(acc[nt][r], a, c), 0.f);
      xh[(m0 + lk * 4 + r) * 136 + col] = (_Float16)v;
    }
  }
}

__device__ __forceinline__ void dump_xs(float* xs, const f32x4* acc, int m0, int lr, int lk) {
#pragma unroll
  for (int nt = 0; nt < 8; nt++)
#pragma unroll
    for (int r = 0; r < 4; r++)
      xs[(m0 + lk * 4 + r) * 133 + nt * 16 + lr] = acc[nt][r];
}

__device__ __forceinline__ void stats_epilogue(const float* xs, float* rbuf,
                                               float* __restrict__ psum, float* __restrict__ psq,
                                               int t, int bs) {
  int col = t & 127, hf = t >> 7;
  float s = 0.f, q = 0.f;
#pragma unroll 4
  for (int r = hf * 32; r < hf * 32 + 32; r++) {
    float v = xs[r * 133 + col];
    s += v;
    q = fmaf(v, v, q);
  }
  if (hf) { rbuf[col * 2] = s; rbuf[col * 2 + 1] = q; }
  __syncthreads();
  if (!hf) {
    s += rbuf[col * 2];
    q += rbuf[col * 2 + 1];
    int slot = bs & 255;
    atomicAdd(&psum[col * 256 + slot], s);
    atomicAdd(&psq[col * 256 + slot], q);
  }
}

// ---------- fused passes (no y0/y1 materialization) ----------

__global__ __launch_bounds__(256, 2) void k_pass1(const float* __restrict__ xyz,
                                                  const _Float16* __restrict__ ptsT,
                                                  const int* __restrict__ fps, const int* __restrict__ idxb,
                                                  const _Float16* __restrict__ W0h, const float* __restrict__ b0,
                                                  float* __restrict__ psum, float* __restrict__ psq) {
  __shared__ _Float16 xh[64 * 136];
  __shared__ float xs[64 * 133];
  __shared__ float rbuf[128 * 2];
  __shared__ int smidx[64];
  __shared__ float smc[3];
  int t = threadIdx.x;
  int bs = blockIdx.x;
  int b = bs >> 10;
  load_ball(xyz, ptsT, fps, idxb, bs, b, t, xh, smidx, smc);
  int lane = t & 63;
  int m0 = __builtin_amdgcn_readfirstlane((t >> 6) * 16);
  int lr = lane & 15, lk = lane >> 4;
  f32x4 acc[8];
  mfma_l0(xh, W0h, b0, m0, lr, lk, acc);
  dump_xs(xs, acc, m0, lr, lk);
  __syncthreads();
  stats_epilogue(xs, rbuf, psum, psq, t, bs);
}

__global__ __launch_bounds__(256, 2) void k_pass2(const float* __restrict__ xyz,
                                                  const _Float16* __restrict__ ptsT,
                                                  const int* __restrict__ fps, const int* __restrict__ idxb,
                                                  const _Float16* __restrict__ W0h, const float* __restrict__ b0,
                                                  const float* __restrict__ sc0, const float* __restrict__ sh0,
                                                  const _Float16* __restrict__ W1h, const float* __restrict__ b1,
                                                  float* __restrict__ psum, float* __restrict__ psq) {
  __shared__ _Float16 xh[64 * 136];
  __shared__ float xs[64 * 133];
  __shared__ float rbuf[128 * 2];
  __shared__ int smidx[64];
  __shared__ float smc[3];
  int t = threadIdx.x;
  int bs = blockIdx.x;
  int b = bs >> 10;
  load_ball(xyz, ptsT, fps, idxb, bs, b, t, xh, smidx, smc);
  int lane = t & 63;
  int m0 = __builtin_amdgcn_readfirstlane((t >> 6) * 16);
  int lr = lane & 15, lk = lane >> 4;
  f32x4 acc[8];
  mfma_l0(xh, W0h, b0, m0, lr, lk, acc);
  __syncthreads();
  store_act(xh, sc0, sh0, m0, lr, lk, acc);
  __syncthreads();
  mfma_lx<8>(xh, W1h, b1, m0, lr, lk, acc);
  dump_xs(xs, acc, m0, lr, lk);
  __syncthreads();
  stats_epilogue(xs, rbuf, psum, psq, t, bs);
}

__global__ __launch_bounds__(256, 2) void k_pass3(const float* __restrict__ xyz,
                                                  const _Float16* __restrict__ ptsT,
                                                  const int* __restrict__ fps, const int* __restrict__ idxb,
                                                  const _Float16* __restrict__ W0h, const float* __restrict__ b0,
                                                  const float* __restrict__ sc0, const float* __restrict__ sh0,
                                                  const _Float16* __restrict__ W1h, const float* __restrict__ b1,
                                                  const float* __restrict__ sc1, const float* __restrict__ sh1,
                                                  const _Float16* __restrict__ W2h, const float* __restrict__ b2,
                                                  float* __restrict__ maxb, float* __restrict__ minb,
                                                  float* __restrict__ psum, float* __restrict__ psq) {
  __shared__ _Float16 xh[64 * 136];
  __shared__ float xs[64 * 133];
  __shared__ float rbuf[128 * 4];
  __shared__ int smidx[64];
  __shared__ float smc[3];
  int t = threadIdx.x;
  int bs = blockIdx.x;
  int b = bs >> 10;
  load_ball(xyz, ptsT, fps, idxb, bs, b, t, xh, smidx, smc);
  int lane = t & 63;
  int m0 = __builtin_amdgcn_readfirstlane((t >> 6) * 16);
  int lr = lane & 15, lk = lane >> 4;
  f32x4 acc[8];
  mfma_l0(xh, W0h, b0, m0, lr, lk, acc);
  __syncthreads();
  store_act(xh, sc0, sh0, m0, lr, lk, acc);
  __syncthreads();
  mfma_lx<8>(xh, W1h, b1, m0, lr, lk, acc);
  __syncthreads();
  store_act(xh, sc1, sh1, m0, lr, lk, acc);
  __syncthreads();
  f32x4 acc2[16];
  mfma_lx<16>(xh, W2h, b2, m0, lr, lk, acc2);
  for (int ph = 0; ph < 2; ph++) {
#pragma unroll
    for (int nt = 0; nt < 8; nt++)
#pragma unroll
      for (int r = 0; r < 4; r++)
        xs[(m0 + lk * 4 + r) * 133 + nt * 16 + lr] = acc2[ph * 8 + nt][r];
    __syncthreads();
    {
      int col = t & 127, hf = t >> 7;
      float s = 0.f, q = 0.f, mx = -3.4e38f, mn = 3.4e38f;
#pragma unroll 4
      for (int r = hf * 32; r < hf * 32 + 32; r++) {
        float v = xs[r * 133 + col];
        s += v;
        q = fmaf(v, v, q);
        mx = fmaxf(mx, v);
        mn = fminf(mn, v);
      }
      if (hf) {
        rbuf[col * 4] = s; rbuf[col * 4 + 1] = q;
        rbuf[col * 4 + 2] = mx; rbuf[col * 4 + 3] = mn;
      }
      __syncthreads();
      if (!hf) {
        s += rbuf[col * 4];
        q += rbuf[col * 4 + 1];
        mx = fmaxf(mx, rbuf[col * 4 + 2]);
        mn = fminf(mn, rbuf[col * 4 + 3]);
        int o = ph * 128 + col;
        maxb[(size_t)bs * 256 + o] = mx;
        minb[(size_t)bs * 256 + o] = mn;
        int slot = bs & 255;
        atomicAdd(&psum[o * 256 + slot], s);
        atomicAdd(&psq[o * 256 + slot], q);
      }
    }
    __syncthreads();
  }
}

// fold BN stats into per-channel affine: a = g*rsqrt(var+eps); c = be - mean*a
// one block per channel; 256-wide parallel reduction over partial slots
__global__ __launch_bounds__(256) void k_fin(const float* __restrict__ psum, const float* __restrict__ psq,
                                             const float* __restrict__ g, const float* __restrict__ be,
                                             float* __restrict__ sc, float* __restrict__ sh) {
  int o = blockIdx.x, t = threadIdx.x;
  float s = psum[o * 256 + t];
  float q = psq[o * 256 + t];
#pragma unroll
  for (int off = 32; off > 0; off >>= 1) {
    s += __shfl_down(s, off);
    q += __shfl_down(q, off);
  }
  __shared__ float rs[4], rq[4];
  if ((t & 63) == 0) { rs[t >> 6] = s; rq[t >> 6] = q; }
  __syncthreads();
  if (t == 0) {
    s = rs[0] + rs[1] + rs[2] + rs[3];
    q = rq[0] + rq[1] + rq[2] + rq[3];
    const float inv = 1.0f / 524288.0f;
    float m = s * inv;
    float ey2 = q * inv;
    float v = fmaf(-m, m, ey2);
    v = fmaxf(v, 0.f);
    float r = rsqrtf(v + EPSV);
    float a = g[o] * r;
    sc[o] = a;
    sh[o] = fmaf(-m, a, be[o]);
  }
}

// out[b, o, s] = relu(a*sel + c), sel = max if a>=0 else min
__global__ __launch_bounds__(256) void k_out(const float* __restrict__ maxb, const float* __restrict__ minb,
                                             const float* __restrict__ sc, const float* __restrict__ sh,
                                             float* __restrict__ out) {
  int flat = blockIdx.x * 256 + threadIdx.x;  // 2,097,152
  int b = flat >> 18;
  int o = (flat >> 10) & 255;
  int s = flat & 1023;
  float a = sc[o], c_ = sh[o];
  size_t mi = ((size_t)(b * 1024 + s)) * 256 + o;
  float v = (a >= 0.f) ? maxb[mi] : minb[mi];
  out[OUT_FEAT + flat] = fmaxf(fmaf(a, v, c_), 0.f);
}

extern "C" void kernel_launch(void* const* d_in, const int* in_sizes, int n_in,
                              void* d_out, int out_size, void* d_ws, size_t ws_size,
                              hipStream_t stream) {
  const float* xyz = (const float*)d_in[0];
  const float* pts = (const float*)d_in[1];
  const int* fps = (const int*)d_in[2];
  const float* W0 = (const float*)d_in[3];
  const float* b0 = (const float*)d_in[4];
  const float* g0 = (const float*)d_in[5];
  const float* be0 = (const float*)d_in[6];
  const float* W1 = (const float*)d_in[7];
  const float* b1 = (const float*)d_in[8];
  const float* g1 = (const float*)d_in[9];
  const float* be1 = (const float*)d_in[10];
  const float* W2 = (const float*)d_in[11];
  const float* b2 = (const float*)d_in[12];
  const float* g2 = (const float*)d_in[13];
  const float* be2 = (const float*)d_in[14];
  float* out = (float*)d_out;
  char* ws = (char*)d_ws;

  if (ws_size < WS_NEEDED) {
    k_newxyz<<<32, 256, 0, stream>>>(xyz, fps, out);
    return;
  }

  _Float16* ptsT = (_Float16*)(ws + O_PT);
  int* idxb = (int*)(ws + O_IDX);
  float* maxbf = (float*)(ws + O_MAXB);
  float* minbf = (float*)(ws + O_MINB);
  _Float16* W0h = (_Float16*)(ws + O_W0T);
  _Float16* W1h = (_Float16*)(ws + O_W1T);
  _Float16* W2h = (_Float16*)(ws + O_W2T);
  float* ps0 = (float*)(ws + O_PS0);
  float* pq0 = (float*)(ws + O_PQ0);
  float* ps1 = (float*)(ws + O_PS1);
  float* pq1 = (float*)(ws + O_PQ1);
  float* ps2 = (float*)(ws + O_PS2);
  float* pq2 = (float*)(ws + O_PQ2);
  float* sc0 = (float*)(ws + O_SC0);
  float* sh0 = (float*)(ws + O_SH0);
  float* sc1 = (float*)(ws + O_SC1);
  float* sh1 = (float*)(ws + O_SH1);
  float* sc2 = (float*)(ws + O_SC2);
  float* sh2 = (float*)(ws + O_SH2);

  k_transpose_pts<<<dim3(NN / 64, DD / 64, BB), 256, 0, stream>>>(pts, ptsT);
  k_wt<<<272, 256, 0, stream>>>(W0, W1, W2, W0h, W1h, W2h, ps0);
  k_ballq<<<2048, 256, 0, stream>>>(xyz, fps, idxb, out);
  k_pass1<<<8192, 256, 0, stream>>>(xyz, ptsT, fps, idxb, W0h, b0, ps0, pq0);
  k_fin<<<128, 256, 0, stream>>>(ps0, pq0, g0, be0, sc0, sh0);
  k_pass2<<<8192, 256, 0, stream>>>(xyz, ptsT, fps, idxb, W0h, b0, sc0, sh0, W1h, b1, ps1, pq1);
  k_fin<<<128, 256, 0, stream>>>(ps1, pq1, g1, be1, sc1, sh1);
  k_pass3<<<8192, 256, 0, stream>>>(xyz, ptsT, fps, idxb, W0h, b0, sc0, sh0, W1h, b1, sc1, sh1,
                                    W2h, b2, maxbf, minbf, ps2, pq2);
  k_fin<<<256, 256, 0, stream>>>(ps2, pq2, g2, be2, sc2, sh2);
  k_out<<<8192, 256, 0, stream>>>(maxbf, minbf, sc2, sh2, out);
}

// Round 4
// 942.358 us; speedup vs baseline: 1.0077x; 1.0077x over previous
//
#include <hip/hip_runtime.h>
#include <hip/hip_bf16.h>

#define BB 8
#define NN 16384
#define SS 1024
#define NSMP 64
#define DD 128
#define R2 0.04f
#define EPSV 1e-5f

typedef _Float16 half2t __attribute__((ext_vector_type(2)));
typedef _Float16 half8t __attribute__((ext_vector_type(8)));
typedef float f32x4 __attribute__((ext_vector_type(4)));

// ---- compact workspace layout (bytes) ----
#define O_PT    0ull                 // pointsT fp16: 8*16384*128*2 = 33,554,432
#define O_IDX   33554432ull          // idx int32: 8192*64*4 = 2,097,152
#define O_MAXB  35651584ull          // 8192*256*4 = 8,388,608
#define O_MINB  44040192ull          // 8,388,608
#define O_W0T   52428800ull          // W0h fp16 [128][136] = 34,816
#define O_W1T   52463616ull          // W1h fp16 [128][136] = 34,816
#define O_W2T   52498432ull          // W2h fp16 [256][136] = 69,632
#define O_PS0   52568064ull          // 128*256*4 = 131,072 (1MB zero region starts here)
#define O_PQ0   52699136ull
#define O_PS1   52830208ull
#define O_PQ1   52961280ull
#define O_PS2   53092352ull          // 256*256*4 = 262,144
#define O_PQ2   53354496ull
#define O_SC0   53616640ull
#define O_SH0   53617152ull
#define O_SC1   53617664ull
#define O_SH1   53618176ull
#define O_SC2   53618688ull
#define O_SH2   53619712ull
#define WS_NEEDED 53620736ull

#define OUT_XYZ 0
#define OUT_FEAT 24576
#define OUT_FPS (24576 + 2097152)

// points [B,D,N] fp32 -> pointsT [B,N,D] fp16. 64n x 64c tile; half8 (16B) stores.
__global__ __launch_bounds__(256) void k_transpose_pts(const float* __restrict__ pts,
                                                       _Float16* __restrict__ ptsT) {
  __shared__ float tile[64][65];
  int b = blockIdx.z;
  int n0 = blockIdx.x * 64, c0 = blockIdx.y * 64;
  int t = threadIdx.x;
  int cg = t >> 6, ln = t & 63;
#pragma unroll
  for (int k = 0; k < 16; k++) {
    int c = cg * 16 + k;
    tile[c][ln] = pts[((size_t)b * DD + c0 + c) * NN + n0 + ln];
  }
  __syncthreads();
  int n = t >> 2, sub = t & 3;
#pragma unroll
  for (int j = 0; j < 2; j++) {
    int cb = sub * 16 + j * 8;
    half8t h;
#pragma unroll
    for (int k = 0; k < 8; k++) h[k] = (_Float16)tile[cb + k][n];
    *(half8t*)(ptsT + ((size_t)b * NN + n0 + n) * DD + c0 + cb) = h;
  }
}

// weights -> fp16, [out][in] stride 136, zero-padded; also zeroes the 1MB stats region.
// W0 channels remapped: xh has feats at c=0..127, relxyz at 128..130
__global__ __launch_bounds__(256) void k_wt(const float* __restrict__ W0, const float* __restrict__ W1,
                                            const float* __restrict__ W2, _Float16* __restrict__ W0h,
                                            _Float16* __restrict__ W1h, _Float16* __restrict__ W2h,
                                            float* __restrict__ zreg) {
  int id = blockIdx.x * 256 + threadIdx.x;
  if (id < 65536) {
    f32x4 z = {0.f, 0.f, 0.f, 0.f};
    ((f32x4*)zreg)[id] = z;
  }
  const int T0 = 128 * 136, T1 = 128 * 136, T2 = 256 * 136;
  if (id < T0) {
    int o = id / 136, c = id % 136;
    float v = 0.f;
    if (c < 131) {
      int c0 = (c < 128) ? (c + 3) : (c - 128);
      v = W0[o * 131 + c0];
    }
    W0h[id] = (_Float16)v;
  } else if (id < T0 + T1) {
    int j = id - T0;
    int o = j / 136, c = j % 136;
    W1h[j] = (_Float16)((c < 128) ? W1[o * 128 + c] : 0.f);
  } else if (id < T0 + T1 + T2) {
    int j = id - T0 - T1;
    int o = j / 136, c = j % 136;
    W2h[j] = (_Float16)((c < 128) ? W2[o * 128 + c] : 0.f);
  }
}

// fallback when workspace undersized
__global__ __launch_bounds__(256) void k_newxyz(const float* __restrict__ xyz, const int* __restrict__ fps,
                                                float* __restrict__ out) {
  int id = blockIdx.x * 256 + threadIdx.x;  // B*S
  int fi = fps[id];
  int b = id >> 10;
  const float* p = xyz + ((size_t)b * NN + fi) * 3;
  float* o = out + OUT_XYZ + (size_t)id * 3;
  o[0] = p[0]; o[1] = p[1]; o[2] = p[2];
  out[OUT_FPS + id] = (float)fi;
}

// one wave per (b,s): first-NS valid indices ascending, pad with first valid.
// Also emits new_xyz and fps passthrough outputs.
__global__ __launch_bounds__(256) void k_ballq(const float* __restrict__ xyz, const int* __restrict__ fps,
                                               int* __restrict__ idxb, float* __restrict__ out) {
  int w = (blockIdx.x * 256 + threadIdx.x) >> 6;
  int lane = threadIdx.x & 63;
  int b = w >> 10;
  int fi = fps[w];
  const float* cp = xyz + ((size_t)b * NN + fi) * 3;
  float cx = cp[0], cy = cp[1], cz = cp[2];
  if (lane < 3) out[OUT_XYZ + (size_t)w * 3 + lane] = (lane == 0) ? cx : ((lane == 1) ? cy : cz);
  if (lane == 3) out[OUT_FPS + w] = (float)fi;
  float A = __fadd_rn(__fadd_rn(__fmul_rn(cx, cx), __fmul_rn(cy, cy)), __fmul_rn(cz, cz));
  const float* xb = xyz + (size_t)b * NN * 3;
  int cnt = 0, firstn = -1;
  int* myidx = idxb + (size_t)w * NSMP;
  for (int nb = 0; nb < NN && cnt < NSMP; nb += 64) {
    int n = nb + lane;
    float px = xb[n * 3], py = xb[n * 3 + 1], pz = xb[n * 3 + 2];
    float Bv = __fadd_rn(__fadd_rn(__fmul_rn(px, px), __fmul_rn(py, py)), __fmul_rn(pz, pz));
    float dot = __fadd_rn(__fadd_rn(__fmul_rn(cx, px), __fmul_rn(cy, py)), __fmul_rn(cz, pz));
    float d = __fsub_rn(__fadd_rn(A, Bv), __fmul_rn(2.0f, dot));
    bool valid = !(d > R2);
    unsigned long long mask = __ballot(valid);
    if (firstn < 0 && mask) firstn = nb + __builtin_ctzll(mask);
    int prefix = __popcll(mask & ((1ull << lane) - 1ull));
    int pos = cnt + prefix;
    if (valid && pos < NSMP) myidx[pos] = n;
    cnt += __popcll(mask);
    if (cnt > NSMP) cnt = NSMP;
  }
  if (lane >= cnt) myidx[lane] = firstn;
}

// ---------- shared device pieces ----------

__device__ __forceinline__ void load_ball(const float* __restrict__ xyz,
                                          const _Float16* __restrict__ ptsT,
                                          const int* __restrict__ fps, const int* __restrict__ idxb,
                                          int bs, int b, int t, _Float16* xh, int* smidx, float* smc) {
  if (t < 64) smidx[t] = idxb[(size_t)bs * 64 + t];
  if (t < 3) {
    int fi = fps[bs];
    smc[t] = xyz[((size_t)b * NN + fi) * 3 + t];
  }
  __syncthreads();
  {
    int row = t >> 2, q = t & 3;
    int n = smidx[row];
    const half8t* src = (const half8t*)(ptsT + ((size_t)b * NN + n) * DD);
#pragma unroll
    for (int i = 0; i < 4; i++) {
      int j = q + i * 4;
      *(half8t*)(xh + row * 136 + j * 8) = src[j];
    }
  }
  if (t < 64) {
    int n = smidx[t];
    const float* p = xyz + ((size_t)b * NN + n) * 3;
    xh[t * 136 + 128] = (_Float16)(p[0] - smc[0]);
    xh[t * 136 + 129] = (_Float16)(p[1] - smc[1]);
    xh[t * 136 + 130] = (_Float16)(p[2] - smc[2]);
  }
  __syncthreads();
}

__device__ __forceinline__ void mfma_l0(const _Float16* xh, const _Float16* __restrict__ W0h,
                                        const float* __restrict__ b0, int m0, int lr, int lk,
                                        f32x4* acc) {
  half8t afr[4];
#pragma unroll
  for (int kt = 0; kt < 4; kt++)
    afr[kt] = *(const half8t*)(xh + (m0 + lr) * 136 + kt * 32 + lk * 8);
#pragma unroll
  for (int nt = 0; nt < 8; nt++) {
    float bv = b0[nt * 16 + lr];
    f32x4 cv = {bv, bv, bv, bv};
    acc[nt] = cv;
  }
#pragma unroll
  for (int kt = 0; kt < 4; kt++) {
#pragma unroll
    for (int nt = 0; nt < 8; nt++) {
      half8t bw = *(const half8t*)(W0h + (nt * 16 + lr) * 136 + kt * 32 + lk * 8);
      acc[nt] = __builtin_amdgcn_mfma_f32_16x16x32_f16(afr[kt], bw, acc[nt], 0, 0, 0);
    }
  }
  float xr[4][3];
#pragma unroll
  for (int r = 0; r < 4; r++) {
    int m = m0 + lk * 4 + r;
    xr[r][0] = (float)xh[m * 136 + 128];
    xr[r][1] = (float)xh[m * 136 + 129];
    xr[r][2] = (float)xh[m * 136 + 130];
  }
#pragma unroll
  for (int nt = 0; nt < 8; nt++) {
    const _Float16* wp = W0h + (nt * 16 + lr) * 136 + 128;
    float w0 = (float)wp[0], w1 = (float)wp[1], w2 = (float)wp[2];
#pragma unroll
    for (int r = 0; r < 4; r++)
      acc[nt][r] += xr[r][0] * w0 + xr[r][1] * w1 + xr[r][2] * w2;
  }
}

template <int NT>
__device__ __forceinline__ void mfma_lx(const _Float16* xh, const _Float16* __restrict__ Wh,
                                        const float* __restrict__ bias, int m0, int lr, int lk,
                                        f32x4* acc) {
  half8t afr[4];
#pragma unroll
  for (int kt = 0; kt < 4; kt++)
    afr[kt] = *(const half8t*)(xh + (m0 + lr) * 136 + kt * 32 + lk * 8);
#pragma unroll
  for (int nt = 0; nt < NT; nt++) {
    float bv = bias[nt * 16 + lr];
    f32x4 cv = {bv, bv, bv, bv};
    acc[nt] = cv;
  }
#pragma unroll
  for (int kt = 0; kt < 4; kt++) {
#pragma unroll
    for (int nt = 0; nt < NT; nt++) {
      half8t bw = *(const half8t*)(Wh + (nt * 16 + lr) * 136 + kt * 32 + lk * 8);
      acc[nt] = __builtin_amdgcn_mfma_f32_16x16x32_f16(afr[kt], bw, acc[nt], 0, 0, 0);
    }
  }
}

__device__ __forceinline__ void store_act(_Float16* xh, const float* __restrict__ sc,
                                          const float* __restrict__ sh, int m0, int lr, int lk,
                                          const f32x4* acc) {
#pragma unroll
  for (int nt = 0; nt < 8; nt++) {
    int col = nt * 16 + lr;
    float a = sc[col], c = sh[col];
#pragma unroll
    for (int r = 0; r < 4; r++) {
      float v = fmaxf(fmaf(acc[nt][r], a, c), 0.f);
      xh[(m0 + lk * 4 + r) * 136 + col] = (_Float16)v;
    }
  }
}

__device__ __forceinline__ void dump_xs(float* xs, const f32x4* acc, int m0, int lr, int lk) {
#pragma unroll
  for (int nt = 0; nt < 8; nt++)
#pragma unroll
    for (int r = 0; r < 4; r++)
      xs[(m0 + lk * 4 + r) * 133 + nt * 16 + lr] = acc[nt][r];
}

__device__ __forceinline__ void stats_epilogue(const float* xs, float* rbuf,
                                               float* __restrict__ psum, float* __restrict__ psq,
                                               int t, int bs) {
  int col = t & 127, hf = t >> 7;
  float s = 0.f, q = 0.f;
#pragma unroll 4
  for (int r = hf * 32; r < hf * 32 + 32; r++) {
    float v = xs[r * 133 + col];
    s += v;
    q = fmaf(v, v, q);
  }
  if (hf) { rbuf[col * 2] = s; rbuf[col * 2 + 1] = q; }
  __syncthreads();
  if (!hf) {
    s += rbuf[col * 2];
    q += rbuf[col * 2 + 1];
    int slot = bs & 255;
    atomicAdd(&psum[col * 256 + slot], s);
    atomicAdd(&psq[col * 256 + slot], q);
  }
}

// ---------- fused passes (no y0/y1 materialization) ----------

__global__ __launch_bounds__(256, 2) void k_pass1(const float* __restrict__ xyz,
                                                  const _Float16* __restrict__ ptsT,
                                                  const int* __restrict__ fps, const int* __restrict__ idxb,
                                                  const _Float16* __restrict__ W0h, const float* __restrict__ b0,
                                                  float* __restrict__ psum, float* __restrict__ psq) {
  __shared__ _Float16 xh[64 * 136];
  __shared__ float xs[64 * 133];
  __shared__ float rbuf[128 * 2];
  __shared__ int smidx[64];
  __shared__ float smc[3];
  int t = threadIdx.x;
  int bs = blockIdx.x;
  int b = bs >> 10;
  load_ball(xyz, ptsT, fps, idxb, bs, b, t, xh, smidx, smc);
  int lane = t & 63;
  int m0 = __builtin_amdgcn_readfirstlane((t >> 6) * 16);
  int lr = lane & 15, lk = lane >> 4;
  f32x4 acc[8];
  mfma_l0(xh, W0h, b0, m0, lr, lk, acc);
  dump_xs(xs, acc, m0, lr, lk);
  __syncthreads();
  stats_epilogue(xs, rbuf, psum, psq, t, bs);
}

__global__ __launch_bounds__(256, 2) void k_pass2(const float* __restrict__ xyz,
                                                  const _Float16* __restrict__ ptsT,
                                                  const int* __restrict__ fps, const int* __restrict__ idxb,
                                                  const _Float16* __restrict__ W0h, const float* __restrict__ b0,
                                                  const float* __restrict__ sc0, const float* __restrict__ sh0,
                                                  const _Float16* __restrict__ W1h, const float* __restrict__ b1,
                                                  float* __restrict__ psum, float* __restrict__ psq) {
  __shared__ _Float16 xh[64 * 136];
  __shared__ float xs[64 * 133];
  __shared__ float rbuf[128 * 2];
  __shared__ int smidx[64];
  __shared__ float smc[3];
  int t = threadIdx.x;
  int bs = blockIdx.x;
  int b = bs >> 10;
  load_ball(xyz, ptsT, fps, idxb, bs, b, t, xh, smidx, smc);
  int lane = t & 63;
  int m0 = __builtin_amdgcn_readfirstlane((t >> 6) * 16);
  int lr = lane & 15, lk = lane >> 4;
  f32x4 acc[8];
  mfma_l0(xh, W0h, b0, m0, lr, lk, acc);
  __syncthreads();
  store_act(xh, sc0, sh0, m0, lr, lk, acc);
  __syncthreads();
  mfma_lx<8>(xh, W1h, b1, m0, lr, lk, acc);
  dump_xs(xs, acc, m0, lr, lk);
  __syncthreads();
  stats_epilogue(xs, rbuf, psum, psq, t, bs);
}

__global__ __launch_bounds__(256, 2) void k_pass3(const float* __restrict__ xyz,
                                                  const _Float16* __restrict__ ptsT,
                                                  const int* __restrict__ fps, const int* __restrict__ idxb,
                                                  const _Float16* __restrict__ W0h, const float* __restrict__ b0,
                                                  const float* __restrict__ sc0, const float* __restrict__ sh0,
                                                  const _Float16* __restrict__ W1h, const float* __restrict__ b1,
                                                  const float* __restrict__ sc1, const float* __restrict__ sh1,
                                                  const _Float16* __restrict__ W2h, const float* __restrict__ b2,
                                                  float* __restrict__ maxb, float* __restrict__ minb,
                                                  float* __restrict__ psum, float* __restrict__ psq) {
  __shared__ _Float16 xh[64 * 136];
  __shared__ float xs[64 * 133];
  __shared__ float rbuf[128 * 4];
  __shared__ int smidx[64];
  __shared__ float smc[3];
  int t = threadIdx.x;
  int bs = blockIdx.x;
  int b = bs >> 10;
  load_ball(xyz, ptsT, fps, idxb, bs, b, t, xh, smidx, smc);
  int lane = t & 63;
  int m0 = __builtin_amdgcn_readfirstlane((t >> 6) * 16);
  int lr = lane & 15, lk = lane >> 4;
  f32x4 acc[8];
  mfma_l0(xh, W0h, b0, m0, lr, lk, acc);
  __syncthreads();
  store_act(xh, sc0, sh0, m0, lr, lk, acc);
  __syncthreads();
  mfma_lx<8>(xh, W1h, b1, m0, lr, lk, acc);
  __syncthreads();
  store_act(xh, sc1, sh1, m0, lr, lk, acc);
  __syncthreads();
  f32x4 acc2[16];
  mfma_lx<16>(xh, W2h, b2, m0, lr, lk, acc2);
  for (int ph = 0; ph < 2; ph++) {
#pragma unroll
    for (int nt = 0; nt < 8; nt++)
#pragma unroll
      for (int r = 0; r < 4; r++)
        xs[(m0 + lk * 4 + r) * 133 + nt * 16 + lr] = acc2[ph * 8 + nt][r];
    __syncthreads();
    {
      int col = t & 127, hf = t >> 7;
      float s = 0.f, q = 0.f, mx = -3.4e38f, mn = 3.4e38f;
#pragma unroll 4
      for (int r = hf * 32; r < hf * 32 + 32; r++) {
        float v = xs[r * 133 + col];
        s += v;
        q = fmaf(v, v, q);
        mx = fmaxf(mx, v);
        mn = fminf(mn, v);
      }
      if (hf) {
        rbuf[col * 4] = s; rbuf[col * 4 + 1] = q;
        rbuf[col * 4 + 2] = mx; rbuf[col * 4 + 3] = mn;
      }
      __syncthreads();
      if (!hf) {
        s += rbuf[col * 4];
        q += rbuf[col * 4 + 1];
        mx = fmaxf(mx, rbuf[col * 4 + 2]);
        mn = fminf(mn, rbuf[col * 4 + 3]);
        int o = ph * 128 + col;
        maxb[(size_t)bs * 256 + o] = mx;
        minb[(size_t)bs * 256 + o] = mn;
        int slot = bs & 255;
        atomicAdd(&psum[o * 256 + slot], s);
        atomicAdd(&psq[o * 256 + slot], q);
      }
    }
    __syncthreads();
  }
}

// fold BN stats into per-channel affine: a = g*rsqrt(var+eps); c = be - mean*a
// one block per channel; 256-wide parallel reduction over partial slots
__global__ __launch_bounds__(256) void k_fin(const float* __restrict__ psum, const float* __restrict__ psq,
                                             const float* __restrict__ g, const float* __restrict__ be,
                                             float* __restrict__ sc, float* __restrict__ sh) {
  int o = blockIdx.x, t = threadIdx.x;
  float s = psum[o * 256 + t];
  float q = psq[o * 256 + t];
#pragma unroll
  for (int off = 32; off > 0; off >>= 1) {
    s += __shfl_down(s, off);
    q += __shfl_down(q, off);
  }
  __shared__ float rs[4], rq[4];
  if ((t & 63) == 0) { rs[t >> 6] = s; rq[t >> 6] = q; }
  __syncthreads();
  if (t == 0) {
    s = rs[0] + rs[1] + rs[2] + rs[3];
    q = rq[0] + rq[1] + rq[2] + rq[3];
    const float inv = 1.0f / 524288.0f;
    float m = s * inv;
    float ey2 = q * inv;
    float v = fmaf(-m, m, ey2);
    v = fmaxf(v, 0.f);
    float r = rsqrtf(v + EPSV);
    float a = g[o] * r;
    sc[o] = a;
    sh[o] = fmaf(-m, a, be[o]);
  }
}

// out[b, o, s] = relu(a*sel + c), sel = max if a>=0 else min
__global__ __launch_bounds__(256) void k_out(const float* __restrict__ maxb, const float* __restrict__ minb,
                                             const float* __restrict__ sc, const float* __restrict__ sh,
                                             float* __restrict__ out) {
  int flat = blockIdx.x * 256 + threadIdx.x;  // 2,097,152
  int b = flat >> 18;
  int o = (flat >> 10) & 255;
  int s = flat & 1023;
  float a = sc[o], c_ = sh[o];
  size_t mi = ((size_t)(b * 1024 + s)) * 256 + o;
  float v = (a >= 0.f) ? maxb[mi] : minb[mi];
  out[OUT_FEAT + flat] = fmaxf(fmaf(a, v, c_), 0.f);
}

extern "C" void kernel_launch(void* const* d_in, const int* in_sizes, int n_in,
                              void* d_out, int out_size, void* d_ws, size_t ws_size,
                              hipStream_t stream) {
  const float* xyz = (const float*)d_in[0];
  const float* pts = (const float*)d_in[1];
  const int* fps = (const int*)d_in[2];
  const float* W0 = (const float*)d_in[3];
  const float* b0 = (const float*)d_in[4];
  const float* g0 = (const float*)d_in[5];
  const float* be0 = (const float*)d_in[6];
  const float* W1 = (const float*)d_in[7];
  const float* b1 = (const float*)d_in[8];
  const float* g1 = (const float*)d_in[9];
  const float* be1 = (const float*)d_in[10];
  const float* W2 = (const float*)d_in[11];
  const float* b2 = (const float*)d_in[12];
  const float* g2 = (const float*)d_in[13];
  const float* be2 = (const float*)d_in[14];
  float* out = (float*)d_out;
  char* ws = (char*)d_ws;

  if (ws_size < WS_NEEDED) {
    k_newxyz<<<32, 256, 0, stream>>>(xyz, fps, out);
    return;
  }

  _Float16* ptsT = (_Float16*)(ws + O_PT);
  int* idxb = (int*)(ws + O_IDX);
  float* maxbf = (float*)(ws + O_MAXB);
  float* minbf = (float*)(ws + O_MINB);
  _Float16* W0h = (_Float16*)(ws + O_W0T);
  _Float16* W1h = (_Float16*)(ws + O_W1T);
  _Float16* W2h = (_Float16*)(ws + O_W2T);
  float* ps0 = (float*)(ws + O_PS0);
  float* pq0 = (float*)(ws + O_PQ0);
  float* ps1 = (float*)(ws + O_PS1);
  float* pq1 = (float*)(ws + O_PQ1);
  float* ps2 = (float*)(ws + O_PS2);
  float* pq2 = (float*)(ws + O_PQ2);
  float* sc0 = (float*)(ws + O_SC0);
  float* sh0 = (float*)(ws + O_SH0);
  float* sc1 = (float*)(ws + O_SC1);
  float* sh1 = (float*)(ws + O_SH1);
  float* sc2 = (float*)(ws + O_SC2);
  float* sh2 = (float*)(ws + O_SH2);

  k_transpose_pts<<<dim3(NN / 64, DD / 64, BB), 256, 0, stream>>>(pts, ptsT);
  k_wt<<<272, 256, 0, stream>>>(W0, W1, W2, W0h, W1h, W2h, ps0);
  k_ballq<<<2048, 256, 0, stream>>>(xyz, fps, idxb, out);
  k_pass1<<<8192, 256, 0, stream>>>(xyz, ptsT, fps, idxb, W0h, b0, ps0, pq0);
  k_fin<<<128, 256, 0, stream>>>(ps0, pq0, g0, be0, sc0, sh0);
  k_pass2<<<8192, 256, 0, stream>>>(xyz, ptsT, fps, idxb, W0h, b0, sc0, sh0, W1h, b1, ps1, pq1);
  k_fin<<<128, 256, 0, stream>>>(ps1, pq1, g1, be1, sc1, sh1);
  k_pass3<<<8192, 256, 0, stream>>>(xyz, ptsT, fps, idxb, W0h, b0, sc0, sh0, W1h, b1, sc1, sh1,
                                    W2h, b2, maxbf, minbf, ps2, pq2);
  k_fin<<<256, 256, 0, stream>>>(ps2, pq2, g2, be2, sc2, sh2);
  k_out<<<8192, 256, 0, stream>>>(maxbf, minbf, sc2, sh2, out);
}

// Round 7
// 852.216 us; speedup vs baseline: 1.1143x; 1.1058x over previous
//
#include <hip/hip_runtime.h>

#define BB 8
#define NN 16384
#define SS 1024
#define NSMP 64
#define DD 128
#define R2 0.04f
#define EPSV 1e-5f

typedef _Float16 half2t __attribute__((ext_vector_type(2)));
typedef _Float16 half8t __attribute__((ext_vector_type(8)));
typedef float f32x4 __attribute__((ext_vector_type(4)));

// ---- workspace layout (bytes); MUST stay under 256 MiB (harness ws size) ----
#define O_PT    0ull                 // pointsT fp16: 8*16384*128*2 = 33,554,432
#define O_IDX   33554432ull          // idx int32: 8192*64*4 = 2,097,152
#define O_MAXB  35651584ull          // 8192*256*4 = 8,388,608
#define O_MINB  44040192ull          // 8,388,608
#define O_W0T   52428800ull          // W0h fp16 [128][136] = 34,816
#define O_W1T   52463616ull          // W1h fp16 [128][136] = 34,816
#define O_W2T   52498432ull          // W2h fp16 [256][136] = 69,632
#define O_PS0   52568064ull          // per-block partials [8192][128] f32 = 4,194,304
#define O_PQ0   56762368ull          // 4,194,304
#define O_PS1   60956672ull          // 4,194,304
#define O_PQ1   65150976ull          // 4,194,304
#define O_PS2   69345280ull          // [8192][256] f32 = 8,388,608
#define O_PQ2   77733888ull          // 8,388,608
#define O_SC0   86122496ull
#define O_SH0   86123008ull
#define O_SC1   86123520ull
#define O_SH1   86124032ull
#define O_SC2   86124544ull
#define O_SH2   86125568ull
#define WS_NEEDED 86126592ull

#define OUT_XYZ 0
#define OUT_FEAT 24576
#define OUT_FPS (24576 + 2097152)

// points [B,D,N] fp32 -> pointsT [B,N,D] fp16. 64n x 64c tile; half8 (16B) stores.
__global__ __launch_bounds__(256) void k_transpose_pts(const float* __restrict__ pts,
                                                       _Float16* __restrict__ ptsT) {
  __shared__ float tile[64][65];
  int b = blockIdx.z;
  int n0 = blockIdx.x * 64, c0 = blockIdx.y * 64;
  int t = threadIdx.x;
  int cg = t >> 6, ln = t & 63;
#pragma unroll
  for (int k = 0; k < 16; k++) {
    int c = cg * 16 + k;
    tile[c][ln] = pts[((size_t)b * DD + c0 + c) * NN + n0 + ln];
  }
  __syncthreads();
  int n = t >> 2, sub = t & 3;
#pragma unroll
  for (int j = 0; j < 2; j++) {
    int cb = sub * 16 + j * 8;
    half8t h;
#pragma unroll
    for (int k = 0; k < 8; k++) h[k] = (_Float16)tile[cb + k][n];
    *(half8t*)(ptsT + ((size_t)b * NN + n0 + n) * DD + c0 + cb) = h;
  }
}

// weights -> fp16, [out][in] stride 136, zero-padded.
// W0 channels remapped: xh has feats at c=0..127, relxyz at 128..130
__global__ __launch_bounds__(256) void k_wt(const float* __restrict__ W0, const float* __restrict__ W1,
                                            const float* __restrict__ W2, _Float16* __restrict__ W0h,
                                            _Float16* __restrict__ W1h, _Float16* __restrict__ W2h) {
  int id = blockIdx.x * 256 + threadIdx.x;
  const int T0 = 128 * 136, T1 = 128 * 136, T2 = 256 * 136;
  if (id < T0) {
    int o = id / 136, c = id % 136;
    float v = 0.f;
    if (c < 131) {
      int c0 = (c < 128) ? (c + 3) : (c - 128);
      v = W0[o * 131 + c0];
    }
    W0h[id] = (_Float16)v;
  } else if (id < T0 + T1) {
    int j = id - T0;
    int o = j / 136, c = j % 136;
    W1h[j] = (_Float16)((c < 128) ? W1[o * 128 + c] : 0.f);
  } else if (id < T0 + T1 + T2) {
    int j = id - T0 - T1;
    int o = j / 136, c = j % 136;
    W2h[j] = (_Float16)((c < 128) ? W2[o * 128 + c] : 0.f);
  }
}

// fallback when workspace undersized
__global__ __launch_bounds__(256) void k_newxyz(const float* __restrict__ xyz, const int* __restrict__ fps,
                                                float* __restrict__ out) {
  int id = blockIdx.x * 256 + threadIdx.x;  // B*S
  int fi = fps[id];
  int b = id >> 10;
  const float* p = xyz + ((size_t)b * NN + fi) * 3;
  float* o = out + OUT_XYZ + (size_t)id * 3;
  o[0] = p[0]; o[1] = p[1]; o[2] = p[2];
  out[OUT_FPS + id] = (float)fi;
}

// one wave per (b,s): first-NS valid indices ascending, pad with first valid.
// Also emits new_xyz and fps passthrough outputs.
__global__ __launch_bounds__(256) void k_ballq(const float* __restrict__ xyz, const int* __restrict__ fps,
                                               int* __restrict__ idxb, float* __restrict__ out) {
  int w = (blockIdx.x * 256 + threadIdx.x) >> 6;
  int lane = threadIdx.x & 63;
  int b = w >> 10;
  int fi = fps[w];
  const float* cp = xyz + ((size_t)b * NN + fi) * 3;
  float cx = cp[0], cy = cp[1], cz = cp[2];
  if (lane < 3) out[OUT_XYZ + (size_t)w * 3 + lane] = (lane == 0) ? cx : ((lane == 1) ? cy : cz);
  if (lane == 3) out[OUT_FPS + w] = (float)fi;
  float A = __fadd_rn(__fadd_rn(__fmul_rn(cx, cx), __fmul_rn(cy, cy)), __fmul_rn(cz, cz));
  const float* xb = xyz + (size_t)b * NN * 3;
  int cnt = 0, firstn = -1;
  int* myidx = idxb + (size_t)w * NSMP;
  for (int nb = 0; nb < NN && cnt < NSMP; nb += 64) {
    int n = nb + lane;
    float px = xb[n * 3], py = xb[n * 3 + 1], pz = xb[n * 3 + 2];
    float Bv = __fadd_rn(__fadd_rn(__fmul_rn(px, px), __fmul_rn(py, py)), __fmul_rn(pz, pz));
    float dot = __fadd_rn(__fadd_rn(__fmul_rn(cx, px), __fmul_rn(cy, py)), __fmul_rn(cz, pz));
    float d = __fsub_rn(__fadd_rn(A, Bv), __fmul_rn(2.0f, dot));
    bool valid = !(d > R2);
    unsigned long long mask = __ballot(valid);
    if (firstn < 0 && mask) firstn = nb + __builtin_ctzll(mask);
    int prefix = __popcll(mask & ((1ull << lane) - 1ull));
    int pos = cnt + prefix;
    if (valid && pos < NSMP) myidx[pos] = n;
    cnt += __popcll(mask);
    if (cnt > NSMP) cnt = NSMP;
  }
  if (lane >= cnt) myidx[lane] = firstn;
}

// ---------- shared device pieces ----------

__device__ __forceinline__ void load_ball(const float* __restrict__ xyz,
                                          const _Float16* __restrict__ ptsT,
                                          const int* __restrict__ fps, const int* __restrict__ idxb,
                                          int bs, int b, int t, _Float16* xh, int* smidx, float* smc) {
  if (t < 64) smidx[t] = idxb[(size_t)bs * 64 + t];
  if (t < 3) {
    int fi = fps[bs];
    smc[t] = xyz[((size_t)b * NN + fi) * 3 + t];
  }
  __syncthreads();
  {
    int row = t >> 2, q = t & 3;
    int n = smidx[row];
    const half8t* src = (const half8t*)(ptsT + ((size_t)b * NN + n) * DD);
#pragma unroll
    for (int i = 0; i < 4; i++) {
      int j = q + i * 4;
      *(half8t*)(xh + row * 136 + j * 8) = src[j];
    }
  }
  if (t < 64) {
    int n = smidx[t];
    const float* p = xyz + ((size_t)b * NN + n) * 3;
    xh[t * 136 + 128] = (_Float16)(p[0] - smc[0]);
    xh[t * 136 + 129] = (_Float16)(p[1] - smc[1]);
    xh[t * 136 + 130] = (_Float16)(p[2] - smc[2]);
  }
  __syncthreads();
}

__device__ __forceinline__ void mfma_l0(const _Float16* xh, const _Float16* __restrict__ W0h,
                                        const float* __restrict__ b0, int m0, int lr, int lk,
                                        f32x4* acc) {
  half8t afr[4];
#pragma unroll
  for (int kt = 0; kt < 4; kt++)
    afr[kt] = *(const half8t*)(xh + (m0 + lr) * 136 + kt * 32 + lk * 8);
#pragma unroll
  for (int nt = 0; nt < 8; nt++) {
    float bv = b0[nt * 16 + lr];
    f32x4 cv = {bv, bv, bv, bv};
    acc[nt] = cv;
  }
#pragma unroll
  for (int kt = 0; kt < 4; kt++) {
#pragma unroll
    for (int nt = 0; nt < 8; nt++) {
      half8t bw = *(const half8t*)(W0h + (nt * 16 + lr) * 136 + kt * 32 + lk * 8);
      acc[nt] = __builtin_amdgcn_mfma_f32_16x16x32_f16(afr[kt], bw, acc[nt], 0, 0, 0);
    }
  }
  float xr[4][3];
#pragma unroll
  for (int r = 0; r < 4; r++) {
    int m = m0 + lk * 4 + r;
    xr[r][0] = (float)xh[m * 136 + 128];
    xr[r][1] = (float)xh[m * 136 + 129];
    xr[r][2] = (float)xh[m * 136 + 130];
  }
#pragma unroll
  for (int nt = 0; nt < 8; nt++) {
    const _Float16* wp = W0h + (nt * 16 + lr) * 136 + 128;
    float w0 = (float)wp[0], w1 = (float)wp[1], w2 = (float)wp[2];
#pragma unroll
    for (int r = 0; r < 4; r++)
      acc[nt][r] += xr[r][0] * w0 + xr[r][1] * w1 + xr[r][2] * w2;
  }
}

template <int NT>
__device__ __forceinline__ void mfma_lx(const _Float16* xh, const _Float16* __restrict__ Wh,
                                        const float* __restrict__ bias, int m0, int lr, int lk,
                                        f32x4* acc) {
  half8t afr[4];
#pragma unroll
  for (int kt = 0; kt < 4; kt++)
    afr[kt] = *(const half8t*)(xh + (m0 + lr) * 136 + kt * 32 + lk * 8);
#pragma unroll
  for (int nt = 0; nt < NT; nt++) {
    float bv = bias[nt * 16 + lr];
    f32x4 cv = {bv, bv, bv, bv};
    acc[nt] = cv;
  }
#pragma unroll
  for (int kt = 0; kt < 4; kt++) {
#pragma unroll
    for (int nt = 0; nt < NT; nt++) {
      half8t bw = *(const half8t*)(Wh + (nt * 16 + lr) * 136 + kt * 32 + lk * 8);
      acc[nt] = __builtin_amdgcn_mfma_f32_16x16x32_f16(afr[kt], bw, acc[nt], 0, 0, 0);
    }
  }
}

__device__ __forceinline__ void store_act(_Float16* xh, const float* __restrict__ sc,
                                          const float* __restrict__ sh, int m0, int lr, int lk,
                                          const f32x4* acc) {
#pragma unroll
  for (int nt = 0; nt < 8; nt++) {
    int col = nt * 16 + lr;
    float a = sc[col], c = sh[col];
#pragma unroll
    for (int r = 0; r < 4; r++) {
      float v = fmaxf(fmaf(acc[nt][r], a, c), 0.f);
      xh[(m0 + lk * 4 + r) * 136 + col] = (_Float16)v;
    }
  }
}

// per-wave sum/sumsq reduction from acc (NT groups of 16 cols), no atomics:
// in-lane over 4 rows, shfl_xor over lk lanes, cross-wave via wb, then
// 1 coalesced per-block store into psum/psq[bs][NCH].
template <int NT>
__device__ __forceinline__ void stats_from_acc(const f32x4* acc, int lane, int wv, int lr,
                                               float (*wb_s)[NT * 16], float (*wb_q)[NT * 16],
                                               float* __restrict__ psum, float* __restrict__ psq,
                                               int t, int bs) {
  float s[NT], q[NT];
#pragma unroll
  for (int nt = 0; nt < NT; nt++) {
    f32x4 a = acc[nt];
    s[nt] = (a[0] + a[1]) + (a[2] + a[3]);
    q[nt] = fmaf(a[0], a[0], fmaf(a[1], a[1], fmaf(a[2], a[2], a[3] * a[3])));
  }
#pragma unroll
  for (int nt = 0; nt < NT; nt++) {
    s[nt] += __shfl_xor(s[nt], 16);
    s[nt] += __shfl_xor(s[nt], 32);
    q[nt] += __shfl_xor(q[nt], 16);
    q[nt] += __shfl_xor(q[nt], 32);
  }
  if (lane < 16) {
#pragma unroll
    for (int nt = 0; nt < NT; nt++) {
      wb_s[wv][nt * 16 + lane] = s[nt];
      wb_q[wv][nt * 16 + lane] = q[nt];
    }
  }
  __syncthreads();
  const int NCH = NT * 16;
  if (t < NCH) {
    float S = (wb_s[0][t] + wb_s[1][t]) + (wb_s[2][t] + wb_s[3][t]);
    float Q = (wb_q[0][t] + wb_q[1][t]) + (wb_q[2][t] + wb_q[3][t]);
    psum[(size_t)bs * NCH + t] = S;
    psq[(size_t)bs * NCH + t] = Q;
  }
}

// ---------- fused passes (no y materialization, no atomics) ----------

__global__ __launch_bounds__(256, 2) void k_pass1(const float* __restrict__ xyz,
                                                  const _Float16* __restrict__ ptsT,
                                                  const int* __restrict__ fps, const int* __restrict__ idxb,
                                                  const _Float16* __restrict__ W0h, const float* __restrict__ b0,
                                                  float* __restrict__ psum, float* __restrict__ psq) {
  __shared__ _Float16 xh[64 * 136];
  __shared__ float wb_s[4][128], wb_q[4][128];
  __shared__ int smidx[64];
  __shared__ float smc[3];
  int t = threadIdx.x;
  int bs = blockIdx.x;
  int b = bs >> 10;
  load_ball(xyz, ptsT, fps, idxb, bs, b, t, xh, smidx, smc);
  int lane = t & 63, wv = t >> 6;
  int m0 = __builtin_amdgcn_readfirstlane(wv * 16);
  int lr = lane & 15, lk = lane >> 4;
  f32x4 acc[8];
  mfma_l0(xh, W0h, b0, m0, lr, lk, acc);
  stats_from_acc<8>(acc, lane, wv, lr, wb_s, wb_q, psum, psq, t, bs);
}

__global__ __launch_bounds__(256, 2) void k_pass2(const float* __restrict__ xyz,
                                                  const _Float16* __restrict__ ptsT,
                                                  const int* __restrict__ fps, const int* __restrict__ idxb,
                                                  const _Float16* __restrict__ W0h, const float* __restrict__ b0,
                                                  const float* __restrict__ sc0, const float* __restrict__ sh0,
                                                  const _Float16* __restrict__ W1h, const float* __restrict__ b1,
                                                  float* __restrict__ psum, float* __restrict__ psq) {
  __shared__ _Float16 xh[64 * 136];
  __shared__ float wb_s[4][128], wb_q[4][128];
  __shared__ int smidx[64];
  __shared__ float smc[3];
  int t = threadIdx.x;
  int bs = blockIdx.x;
  int b = bs >> 10;
  load_ball(xyz, ptsT, fps, idxb, bs, b, t, xh, smidx, smc);
  int lane = t & 63, wv = t >> 6;
  int m0 = __builtin_amdgcn_readfirstlane(wv * 16);
  int lr = lane & 15, lk = lane >> 4;
  f32x4 acc[8];
  mfma_l0(xh, W0h, b0, m0, lr, lk, acc);
  __syncthreads();  // all waves done reading xh
  store_act(xh, sc0, sh0, m0, lr, lk, acc);
  __syncthreads();
  mfma_lx<8>(xh, W1h, b1, m0, lr, lk, acc);
  stats_from_acc<8>(acc, lane, wv, lr, wb_s, wb_q, psum, psq, t, bs);
}

__global__ __launch_bounds__(256, 2) void k_pass3(const float* __restrict__ xyz,
                                                  const _Float16* __restrict__ ptsT,
                                                  const int* __restrict__ fps, const int* __restrict__ idxb,
                                                  const _Float16* __restrict__ W0h, const float* __restrict__ b0,
                                                  const float* __restrict__ sc0, const float* __restrict__ sh0,
                                                  const _Float16* __restrict__ W1h, const float* __restrict__ b1,
                                                  const float* __restrict__ sc1, const float* __restrict__ sh1,
                                                  const _Float16* __restrict__ W2h, const float* __restrict__ b2,
                                                  float* __restrict__ maxb, float* __restrict__ minb,
                                                  float* __restrict__ psum, float* __restrict__ psq) {
  __shared__ _Float16 xh[64 * 136];
  __shared__ float wb_s[4][256], wb_q[4][256], wb_mx[4][256], wb_mn[4][256];
  __shared__ int smidx[64];
  __shared__ float smc[3];
  int t = threadIdx.x;
  int bs = blockIdx.x;
  int b = bs >> 10;
  load_ball(xyz, ptsT, fps, idxb, bs, b, t, xh, smidx, smc);
  int lane = t & 63, wv = t >> 6;
  int m0 = __builtin_amdgcn_readfirstlane(wv * 16);
  int lr = lane & 15, lk = lane >> 4;
  f32x4 acc[8];
  mfma_l0(xh, W0h, b0, m0, lr, lk, acc);
  __syncthreads();
  store_act(xh, sc0, sh0, m0, lr, lk, acc);
  __syncthreads();
  mfma_lx<8>(xh, W1h, b1, m0, lr, lk, acc);
  __syncthreads();
  store_act(xh, sc1, sh1, m0, lr, lk, acc);
  __syncthreads();
  f32x4 acc2[16];
  mfma_lx<16>(xh, W2h, b2, m0, lr, lk, acc2);
  // reduction: sum/sumsq/max/min per col, from registers
  float s[16], q[16], mx[16], mn[16];
#pragma unroll
  for (int nt = 0; nt < 16; nt++) {
    f32x4 a = acc2[nt];
    s[nt] = (a[0] + a[1]) + (a[2] + a[3]);
    q[nt] = fmaf(a[0], a[0], fmaf(a[1], a[1], fmaf(a[2], a[2], a[3] * a[3])));
    mx[nt] = fmaxf(fmaxf(a[0], a[1]), fmaxf(a[2], a[3]));
    mn[nt] = fminf(fminf(a[0], a[1]), fminf(a[2], a[3]));
  }
#pragma unroll
  for (int nt = 0; nt < 16; nt++) {
    s[nt] += __shfl_xor(s[nt], 16);
    s[nt] += __shfl_xor(s[nt], 32);
    q[nt] += __shfl_xor(q[nt], 16);
    q[nt] += __shfl_xor(q[nt], 32);
    mx[nt] = fmaxf(mx[nt], __shfl_xor(mx[nt], 16));
    mx[nt] = fmaxf(mx[nt], __shfl_xor(mx[nt], 32));
    mn[nt] = fminf(mn[nt], __shfl_xor(mn[nt], 16));
    mn[nt] = fminf(mn[nt], __shfl_xor(mn[nt], 32));
  }
  if (lane < 16) {
#pragma unroll
    for (int nt = 0; nt < 16; nt++) {
      int col = nt * 16 + lane;
      wb_s[wv][col] = s[nt];
      wb_q[wv][col] = q[nt];
      wb_mx[wv][col] = mx[nt];
      wb_mn[wv][col] = mn[nt];
    }
  }
  __syncthreads();
  {
    float S = (wb_s[0][t] + wb_s[1][t]) + (wb_s[2][t] + wb_s[3][t]);
    float Q = (wb_q[0][t] + wb_q[1][t]) + (wb_q[2][t] + wb_q[3][t]);
    float MX = fmaxf(fmaxf(wb_mx[0][t], wb_mx[1][t]), fmaxf(wb_mx[2][t], wb_mx[3][t]));
    float MN = fminf(fminf(wb_mn[0][t], wb_mn[1][t]), fminf(wb_mn[2][t], wb_mn[3][t]));
    maxb[(size_t)bs * 256 + t] = MX;
    minb[(size_t)bs * 256 + t] = MN;
    psum[(size_t)bs * 256 + t] = S;
    psq[(size_t)bs * 256 + t] = Q;
  }
}

// fold BN stats into per-channel affine: a = g*rsqrt(var+eps); c = be - mean*a
// one block per channel; threads stride the 8192 per-block partials (no atomics anywhere)
__global__ __launch_bounds__(256) void k_fin(const float* __restrict__ psum, const float* __restrict__ psq,
                                             const float* __restrict__ g, const float* __restrict__ be,
                                             float* __restrict__ sc, float* __restrict__ sh, int nch) {
  int o = blockIdx.x, t = threadIdx.x;
  float s = 0.f, q = 0.f;
  for (int k = t; k < 8192; k += 256) {
    s += psum[(size_t)k * nch + o];
    q += psq[(size_t)k * nch + o];
  }
#pragma unroll
  for (int off = 32; off > 0; off >>= 1) {
    s += __shfl_down(s, off);
    q += __shfl_down(q, off);
  }
  __shared__ float rs[4], rq[4];
  if ((t & 63) == 0) { rs[t >> 6] = s; rq[t >> 6] = q; }
  __syncthreads();
  if (t == 0) {
    s = (rs[0] + rs[1]) + (rs[2] + rs[3]);
    q = (rq[0] + rq[1]) + (rq[2] + rq[3]);
    const float inv = 1.0f / 524288.0f;
    float m = s * inv;
    float ey2 = q * inv;
    float v = fmaf(-m, m, ey2);
    v = fmaxf(v, 0.f);
    float r = rsqrtf(v + EPSV);
    float a = g[o] * r;
    sc[o] = a;
    sh[o] = fmaf(-m, a, be[o]);
  }
}

// out[b, o, s] = relu(a*sel + c), sel = max if a>=0 else min
__global__ __launch_bounds__(256) void k_out(const float* __restrict__ maxb, const float* __restrict__ minb,
                                             const float* __restrict__ sc, const float* __restrict__ sh,
                                             float* __restrict__ out) {
  int flat = blockIdx.x * 256 + threadIdx.x;  // 2,097,152
  int b = flat >> 18;
  int o = (flat >> 10) & 255;
  int s = flat & 1023;
  float a = sc[o], c_ = sh[o];
  size_t mi = ((size_t)(b * 1024 + s)) * 256 + o;
  float v = (a >= 0.f) ? maxb[mi] : minb[mi];
  out[OUT_FEAT + flat] = fmaxf(fmaf(a, v, c_), 0.f);
}

extern "C" void kernel_launch(void* const* d_in, const int* in_sizes, int n_in,
                              void* d_out, int out_size, void* d_ws, size_t ws_size,
                              hipStream_t stream) {
  const float* xyz = (const float*)d_in[0];
  const float* pts = (const float*)d_in[1];
  const int* fps = (const int*)d_in[2];
  const float* W0 = (const float*)d_in[3];
  const float* b0 = (const float*)d_in[4];
  const float* g0 = (const float*)d_in[5];
  const float* be0 = (const float*)d_in[6];
  const float* W1 = (const float*)d_in[7];
  const float* b1 = (const float*)d_in[8];
  const float* g1 = (const float*)d_in[9];
  const float* be1 = (const float*)d_in[10];
  const float* W2 = (const float*)d_in[11];
  const float* b2 = (const float*)d_in[12];
  const float* g2 = (const float*)d_in[13];
  const float* be2 = (const float*)d_in[14];
  float* out = (float*)d_out;
  char* ws = (char*)d_ws;

  if (ws_size < WS_NEEDED) {
    k_newxyz<<<32, 256, 0, stream>>>(xyz, fps, out);
    return;
  }

  _Float16* ptsT = (_Float16*)(ws + O_PT);
  int* idxb = (int*)(ws + O_IDX);
  float* maxbf = (float*)(ws + O_MAXB);
  float* minbf = (float*)(ws + O_MINB);
  _Float16* W0h = (_Float16*)(ws + O_W0T);
  _Float16* W1h = (_Float16*)(ws + O_W1T);
  _Float16* W2h = (_Float16*)(ws + O_W2T);
  float* ps0 = (float*)(ws + O_PS0);
  float* pq0 = (float*)(ws + O_PQ0);
  float* ps1 = (float*)(ws + O_PS1);
  float* pq1 = (float*)(ws + O_PQ1);
  float* ps2 = (float*)(ws + O_PS2);
  float* pq2 = (float*)(ws + O_PQ2);
  float* sc0 = (float*)(ws + O_SC0);
  float* sh0 = (float*)(ws + O_SH0);
  float* sc1 = (float*)(ws + O_SC1);
  float* sh1 = (float*)(ws + O_SH1);
  float* sc2 = (float*)(ws + O_SC2);
  float* sh2 = (float*)(ws + O_SH2);

  k_transpose_pts<<<dim3(NN / 64, DD / 64, BB), 256, 0, stream>>>(pts, ptsT);
  k_wt<<<272, 256, 0, stream>>>(W0, W1, W2, W0h, W1h, W2h);
  k_ballq<<<2048, 256, 0, stream>>>(xyz, fps, idxb, out);
  k_pass1<<<8192, 256, 0, stream>>>(xyz, ptsT, fps, idxb, W0h, b0, ps0, pq0);
  k_fin<<<128, 256, 0, stream>>>(ps0, pq0, g0, be0, sc0, sh0, 128);
  k_pass2<<<8192, 256, 0, stream>>>(xyz, ptsT, fps, idxb, W0h, b0, sc0, sh0, W1h, b1, ps1, pq1);
  k_fin<<<128, 256, 0, stream>>>(ps1, pq1, g1, be1, sc1, sh1, 128);
  k_pass3<<<8192, 256, 0, stream>>>(xyz, ptsT, fps, idxb, W0h, b0, sc0, sh0, W1h, b1, sc1, sh1,
                                    W2h, b2, maxbf, minbf, ps2, pq2);
  k_fin<<<256, 256, 0, stream>>>(ps2, pq2, g2, be2, sc2, sh2, 256);
  k_out<<<8192, 256, 0, stream>>>(maxbf, minbf, sc2, sh2, out);
}

// Round 8
// 518.141 us; speedup vs baseline: 1.8327x; 1.6448x over previous
//
#include <hip/hip_runtime.h>

#define BB 8
#define NN 16384
#define SS 1024
#define NSMP 64
#define DD 128
#define R2 0.04f
#define EPSV 1e-5f

typedef _Float16 half8t __attribute__((ext_vector_type(8)));
typedef float f32x4 __attribute__((ext_vector_type(4)));

// ---- workspace layout (bytes); MUST stay under 256 MiB (harness ws size) ----
#define O_PT    0ull                 // pointsT fp16: 8*16384*128*2 = 33,554,432
#define O_IDX   33554432ull          // idx int32: 8192*64*4 = 2,097,152
#define O_MAXB  35651584ull          // 8192*256*4 = 8,388,608
#define O_MINB  44040192ull          // 8,388,608
#define O_W0T   52428800ull          // W0h fp16 [128][136] = 34,816
#define O_W1T   52463616ull          // W1h fp16 [128][136] = 34,816
#define O_W2T   52498432ull          // W2h fp16 [256][136] = 69,632
#define O_PS0   52568064ull          // per-block partials [8192][128] f32 = 4,194,304
#define O_PQ0   56762368ull          // 4,194,304
#define O_PS1   60956672ull          // 4,194,304
#define O_PQ1   65150976ull          // 4,194,304
#define O_PS2   69345280ull          // [8192][256] f32 = 8,388,608
#define O_PQ2   77733888ull          // 8,388,608
#define O_SC0   86122496ull
#define O_SH0   86123008ull
#define O_SC1   86123520ull
#define O_SH1   86124032ull
#define O_SC2   86124544ull
#define O_SH2   86125568ull
#define WS_NEEDED 86126592ull

#define OUT_XYZ 0
#define OUT_FEAT 24576
#define OUT_FPS (24576 + 2097152)

// points [B,D,N] fp32 -> pointsT [B,N,D] fp16. 64n x 64c tile; half8 (16B) stores.
__global__ __launch_bounds__(256) void k_transpose_pts(const float* __restrict__ pts,
                                                       _Float16* __restrict__ ptsT) {
  __shared__ float tile[64][65];
  int b = blockIdx.z;
  int n0 = blockIdx.x * 64, c0 = blockIdx.y * 64;
  int t = threadIdx.x;
  int cg = t >> 6, ln = t & 63;
#pragma unroll
  for (int k = 0; k < 16; k++) {
    int c = cg * 16 + k;
    tile[c][ln] = pts[((size_t)b * DD + c0 + c) * NN + n0 + ln];
  }
  __syncthreads();
  int n = t >> 2, sub = t & 3;
#pragma unroll
  for (int j = 0; j < 2; j++) {
    int cb = sub * 16 + j * 8;
    half8t h;
#pragma unroll
    for (int k = 0; k < 8; k++) h[k] = (_Float16)tile[cb + k][n];
    *(half8t*)(ptsT + ((size_t)b * NN + n0 + n) * DD + c0 + cb) = h;
  }
}

// weights -> fp16, [out][in] stride 136, zero-padded.
// W0 channels remapped: xh has feats at c=0..127, relxyz at 128..130
__global__ __launch_bounds__(256) void k_wt(const float* __restrict__ W0, const float* __restrict__ W1,
                                            const float* __restrict__ W2, _Float16* __restrict__ W0h,
                                            _Float16* __restrict__ W1h, _Float16* __restrict__ W2h) {
  int id = blockIdx.x * 256 + threadIdx.x;
  const int T0 = 128 * 136, T1 = 128 * 136, T2 = 256 * 136;
  if (id < T0) {
    int o = id / 136, c = id % 136;
    float v = 0.f;
    if (c < 131) {
      int c0 = (c < 128) ? (c + 3) : (c - 128);
      v = W0[o * 131 + c0];
    }
    W0h[id] = (_Float16)v;
  } else if (id < T0 + T1) {
    int j = id - T0;
    int o = j / 136, c = j % 136;
    W1h[j] = (_Float16)((c < 128) ? W1[o * 128 + c] : 0.f);
  } else if (id < T0 + T1 + T2) {
    int j = id - T0 - T1;
    int o = j / 136, c = j % 136;
    W2h[j] = (_Float16)((c < 128) ? W2[o * 128 + c] : 0.f);
  }
}

// fallback when workspace undersized
__global__ __launch_bounds__(256) void k_newxyz(const float* __restrict__ xyz, const int* __restrict__ fps,
                                                float* __restrict__ out) {
  int id = blockIdx.x * 256 + threadIdx.x;  // B*S
  int fi = fps[id];
  int b = id >> 10;
  const float* p = xyz + ((size_t)b * NN + fi) * 3;
  float* o = out + OUT_XYZ + (size_t)id * 3;
  o[0] = p[0]; o[1] = p[1]; o[2] = p[2];
  out[OUT_FPS + id] = (float)fi;
}

// one wave per (b,s): first-NS valid indices ascending, pad with first valid.
// Also emits new_xyz and fps passthrough outputs.
__global__ __launch_bounds__(256) void k_ballq(const float* __restrict__ xyz, const int* __restrict__ fps,
                                               int* __restrict__ idxb, float* __restrict__ out) {
  int w = (blockIdx.x * 256 + threadIdx.x) >> 6;
  int lane = threadIdx.x & 63;
  int b = w >> 10;
  int fi = fps[w];
  const float* cp = xyz + ((size_t)b * NN + fi) * 3;
  float cx = cp[0], cy = cp[1], cz = cp[2];
  if (lane < 3) out[OUT_XYZ + (size_t)w * 3 + lane] = (lane == 0) ? cx : ((lane == 1) ? cy : cz);
  if (lane == 3) out[OUT_FPS + w] = (float)fi;
  float A = __fadd_rn(__fadd_rn(__fmul_rn(cx, cx), __fmul_rn(cy, cy)), __fmul_rn(cz, cz));
  const float* xb = xyz + (size_t)b * NN * 3;
  int cnt = 0, firstn = -1;
  int* myidx = idxb + (size_t)w * NSMP;
  for (int nb = 0; nb < NN && cnt < NSMP; nb += 64) {
    int n = nb + lane;
    float px = xb[n * 3], py = xb[n * 3 + 1], pz = xb[n * 3 + 2];
    float Bv = __fadd_rn(__fadd_rn(__fmul_rn(px, px), __fmul_rn(py, py)), __fmul_rn(pz, pz));
    float dot = __fadd_rn(__fadd_rn(__fmul_rn(cx, px), __fmul_rn(cy, py)), __fmul_rn(cz, pz));
    float d = __fsub_rn(__fadd_rn(A, Bv), __fmul_rn(2.0f, dot));
    bool valid = !(d > R2);
    unsigned long long mask = __ballot(valid);
    if (firstn < 0 && mask) firstn = nb + __builtin_ctzll(mask);
    int prefix = __popcll(mask & ((1ull << lane) - 1ull));
    int pos = cnt + prefix;
    if (valid && pos < NSMP) myidx[pos] = n;
    cnt += __popcll(mask);
    if (cnt > NSMP) cnt = NSMP;
  }
  if (lane >= cnt) myidx[lane] = firstn;
}

// ---------- shared device pieces ----------

__device__ __forceinline__ void load_ball(const float* __restrict__ xyz,
                                          const _Float16* __restrict__ ptsT,
                                          const int* __restrict__ fps, const int* __restrict__ idxb,
                                          int bs, int b, int t, _Float16* xh, int* smidx, float* smc) {
  if (t < 64) smidx[t] = idxb[(size_t)bs * 64 + t];
  if (t < 3) {
    int fi = fps[bs];
    smc[t] = xyz[((size_t)b * NN + fi) * 3 + t];
  }
  __syncthreads();
  {
    int row = t >> 2, q = t & 3;
    int n = smidx[row];
    const half8t* src = (const half8t*)(ptsT + ((size_t)b * NN + n) * DD);
#pragma unroll
    for (int i = 0; i < 4; i++) {
      int j = q + i * 4;
      *(half8t*)(xh + row * 136 + j * 8) = src[j];
    }
  }
  if (t < 64) {
    int n = smidx[t];
    const float* p = xyz + ((size_t)b * NN + n) * 3;
    xh[t * 136 + 128] = (_Float16)(p[0] - smc[0]);
    xh[t * 136 + 129] = (_Float16)(p[1] - smc[1]);
    xh[t * 136 + 130] = (_Float16)(p[2] - smc[2]);
  }
  __syncthreads();
}

// Layer over K=128 with wave-owned column group (NT groups of 16 cols, base cb).
// Each wave computes ALL 64 rows (m=0..3 tiles) for its cols.
// W rows are read ONCE per block (each row by exactly one wave) — 4x less L2 traffic
// than the wave-owns-rows decomposition.
template <int NT>
__device__ __forceinline__ void layer_cols(const _Float16* xh, const _Float16* __restrict__ Wh,
                                           const float* __restrict__ bias, int cb, int lr, int lk,
                                           f32x4 acc[4][NT]) {
  half8t bw[NT][4];
#pragma unroll
  for (int nt = 0; nt < NT; nt++)
#pragma unroll
    for (int kt = 0; kt < 4; kt++)
      bw[nt][kt] = *(const half8t*)(Wh + (cb + nt * 16 + lr) * 136 + kt * 32 + lk * 8);
  float bv[NT];
#pragma unroll
  for (int nt = 0; nt < NT; nt++) bv[nt] = bias[cb + nt * 16 + lr];
#pragma unroll
  for (int m = 0; m < 4; m++) {
    half8t afr[4];
#pragma unroll
    for (int kt = 0; kt < 4; kt++)
      afr[kt] = *(const half8t*)(xh + (m * 16 + lr) * 136 + kt * 32 + lk * 8);
#pragma unroll
    for (int nt = 0; nt < NT; nt++) {
      f32x4 cv = {bv[nt], bv[nt], bv[nt], bv[nt]};
      acc[m][nt] = cv;
    }
#pragma unroll
    for (int kt = 0; kt < 4; kt++)
#pragma unroll
      for (int nt = 0; nt < NT; nt++)
        acc[m][nt] = __builtin_amdgcn_mfma_f32_16x16x32_f16(afr[kt], bw[nt][kt], acc[m][nt], 0, 0, 0);
  }
}

// add the 3 relative-xyz channels (c=128..130) for layer0 on the VALU
__device__ __forceinline__ void l0_relxyz(const _Float16* xh, const _Float16* __restrict__ W0h,
                                          int cb, int lr, int lk, f32x4 acc[4][2]) {
  float wx[2][3];
#pragma unroll
  for (int nt = 0; nt < 2; nt++) {
    const _Float16* wp = W0h + (cb + nt * 16 + lr) * 136 + 128;
    wx[nt][0] = (float)wp[0]; wx[nt][1] = (float)wp[1]; wx[nt][2] = (float)wp[2];
  }
#pragma unroll
  for (int m = 0; m < 4; m++) {
#pragma unroll
    for (int r = 0; r < 4; r++) {
      int row = m * 16 + lk * 4 + r;
      float x0 = (float)xh[row * 136 + 128];
      float x1 = (float)xh[row * 136 + 129];
      float x2 = (float)xh[row * 136 + 130];
#pragma unroll
      for (int nt = 0; nt < 2; nt++)
        acc[m][nt][r] += x0 * wx[nt][0] + x1 * wx[nt][1] + x2 * wx[nt][2];
    }
  }
}

// affine+relu -> xh (wave writes all rows of its own cols)
template <int NT>
__device__ __forceinline__ void store_act_cols(_Float16* xh, const float* __restrict__ sc,
                                               const float* __restrict__ sh, int cb, int lr, int lk,
                                               const f32x4 acc[4][NT]) {
#pragma unroll
  for (int nt = 0; nt < NT; nt++) {
    int col = cb + nt * 16 + lr;
    float a = sc[col], c = sh[col];
#pragma unroll
    for (int m = 0; m < 4; m++)
#pragma unroll
      for (int r = 0; r < 4; r++) {
        float v = fmaxf(fmaf(acc[m][nt][r], a, c), 0.f);
        xh[(m * 16 + lk * 4 + r) * 136 + col] = (_Float16)v;
      }
  }
}

// wave-private stats over all 64 rows of the wave's NT*16 cols; no LDS, no barrier.
template <int NT>
__device__ __forceinline__ void stats_cols(const f32x4 acc[4][NT], int lane, int cb, int lr,
                                           float* __restrict__ psum, float* __restrict__ psq,
                                           int bs, int nch) {
  float s[NT], q[NT];
#pragma unroll
  for (int nt = 0; nt < NT; nt++) { s[nt] = 0.f; q[nt] = 0.f; }
#pragma unroll
  for (int m = 0; m < 4; m++)
#pragma unroll
    for (int nt = 0; nt < NT; nt++) {
      f32x4 a = acc[m][nt];
      s[nt] += (a[0] + a[1]) + (a[2] + a[3]);
      q[nt] += fmaf(a[0], a[0], fmaf(a[1], a[1], fmaf(a[2], a[2], a[3] * a[3])));
    }
#pragma unroll
  for (int nt = 0; nt < NT; nt++) {
    s[nt] += __shfl_xor(s[nt], 16);
    s[nt] += __shfl_xor(s[nt], 32);
    q[nt] += __shfl_xor(q[nt], 16);
    q[nt] += __shfl_xor(q[nt], 32);
  }
  if (lane < 16) {
#pragma unroll
    for (int nt = 0; nt < NT; nt++) {
      int col = cb + nt * 16 + lr;
      psum[(size_t)bs * nch + col] = s[nt];
      psq[(size_t)bs * nch + col] = q[nt];
    }
  }
}

// ---------- fused passes (no y materialization, no atomics, col-owned waves) ----------

__global__ __launch_bounds__(256, 2) void k_pass1(const float* __restrict__ xyz,
                                                  const _Float16* __restrict__ ptsT,
                                                  const int* __restrict__ fps, const int* __restrict__ idxb,
                                                  const _Float16* __restrict__ W0h, const float* __restrict__ b0,
                                                  float* __restrict__ psum, float* __restrict__ psq) {
  __shared__ _Float16 xh[64 * 136];
  __shared__ int smidx[64];
  __shared__ float smc[3];
  int t = threadIdx.x;
  int bs = blockIdx.x;
  int b = bs >> 10;
  load_ball(xyz, ptsT, fps, idxb, bs, b, t, xh, smidx, smc);
  int lane = t & 63, wv = t >> 6;
  int lr = lane & 15, lk = lane >> 4;
  int cb = __builtin_amdgcn_readfirstlane(wv * 32);
  f32x4 acc[4][2];
  layer_cols<2>(xh, W0h, b0, cb, lr, lk, acc);
  l0_relxyz(xh, W0h, cb, lr, lk, acc);
  stats_cols<2>(acc, lane, cb, lr, psum, psq, bs, 128);
}

__global__ __launch_bounds__(256, 2) void k_pass2(const float* __restrict__ xyz,
                                                  const _Float16* __restrict__ ptsT,
                                                  const int* __restrict__ fps, const int* __restrict__ idxb,
                                                  const _Float16* __restrict__ W0h, const float* __restrict__ b0,
                                                  const float* __restrict__ sc0, const float* __restrict__ sh0,
                                                  const _Float16* __restrict__ W1h, const float* __restrict__ b1,
                                                  float* __restrict__ psum, float* __restrict__ psq) {
  __shared__ _Float16 xh[64 * 136];
  __shared__ int smidx[64];
  __shared__ float smc[3];
  int t = threadIdx.x;
  int bs = blockIdx.x;
  int b = bs >> 10;
  load_ball(xyz, ptsT, fps, idxb, bs, b, t, xh, smidx, smc);
  int lane = t & 63, wv = t >> 6;
  int lr = lane & 15, lk = lane >> 4;
  int cb = __builtin_amdgcn_readfirstlane(wv * 32);
  f32x4 acc[4][2];
  layer_cols<2>(xh, W0h, b0, cb, lr, lk, acc);
  l0_relxyz(xh, W0h, cb, lr, lk, acc);
  __syncthreads();  // all waves done reading xh (layer0 inputs)
  store_act_cols<2>(xh, sc0, sh0, cb, lr, lk, acc);
  __syncthreads();
  layer_cols<2>(xh, W1h, b1, cb, lr, lk, acc);
  stats_cols<2>(acc, lane, cb, lr, psum, psq, bs, 128);
}

__global__ __launch_bounds__(256, 2) void k_pass3(const float* __restrict__ xyz,
                                                  const _Float16* __restrict__ ptsT,
                                                  const int* __restrict__ fps, const int* __restrict__ idxb,
                                                  const _Float16* __restrict__ W0h, const float* __restrict__ b0,
                                                  const float* __restrict__ sc0, const float* __restrict__ sh0,
                                                  const _Float16* __restrict__ W1h, const float* __restrict__ b1,
                                                  const float* __restrict__ sc1, const float* __restrict__ sh1,
                                                  const _Float16* __restrict__ W2h, const float* __restrict__ b2,
                                                  float* __restrict__ maxb, float* __restrict__ minb,
                                                  float* __restrict__ psum, float* __restrict__ psq) {
  __shared__ _Float16 xh[64 * 136];
  __shared__ int smidx[64];
  __shared__ float smc[3];
  int t = threadIdx.x;
  int bs = blockIdx.x;
  int b = bs >> 10;
  load_ball(xyz, ptsT, fps, idxb, bs, b, t, xh, smidx, smc);
  int lane = t & 63, wv = t >> 6;
  int lr = lane & 15, lk = lane >> 4;
  int cb = __builtin_amdgcn_readfirstlane(wv * 32);
  f32x4 acc[4][2];
  layer_cols<2>(xh, W0h, b0, cb, lr, lk, acc);
  l0_relxyz(xh, W0h, cb, lr, lk, acc);
  __syncthreads();
  store_act_cols<2>(xh, sc0, sh0, cb, lr, lk, acc);
  __syncthreads();
  layer_cols<2>(xh, W1h, b1, cb, lr, lk, acc);
  __syncthreads();
  store_act_cols<2>(xh, sc1, sh1, cb, lr, lk, acc);
  __syncthreads();
  // layer2: wave owns 64 cols; stream m-tiles, keep only stats (64 reg W cache)
  int cq = __builtin_amdgcn_readfirstlane(wv * 64);
  half8t bw[4][4];
#pragma unroll
  for (int nt = 0; nt < 4; nt++)
#pragma unroll
    for (int kt = 0; kt < 4; kt++)
      bw[nt][kt] = *(const half8t*)(W2h + (cq + nt * 16 + lr) * 136 + kt * 32 + lk * 8);
  float bv[4];
#pragma unroll
  for (int nt = 0; nt < 4; nt++) bv[nt] = b2[cq + nt * 16 + lr];
  float s[4] = {0.f, 0.f, 0.f, 0.f}, q[4] = {0.f, 0.f, 0.f, 0.f};
  float mx[4], mn[4];
#pragma unroll
  for (int nt = 0; nt < 4; nt++) { mx[nt] = -3.4e38f; mn[nt] = 3.4e38f; }
#pragma unroll
  for (int m = 0; m < 4; m++) {
    half8t afr[4];
#pragma unroll
    for (int kt = 0; kt < 4; kt++)
      afr[kt] = *(const half8t*)(xh + (m * 16 + lr) * 136 + kt * 32 + lk * 8);
    f32x4 a2[4];
#pragma unroll
    for (int nt = 0; nt < 4; nt++) {
      f32x4 cv = {bv[nt], bv[nt], bv[nt], bv[nt]};
      a2[nt] = cv;
    }
#pragma unroll
    for (int kt = 0; kt < 4; kt++)
#pragma unroll
      for (int nt = 0; nt < 4; nt++)
        a2[nt] = __builtin_amdgcn_mfma_f32_16x16x32_f16(afr[kt], bw[nt][kt], a2[nt], 0, 0, 0);
#pragma unroll
    for (int nt = 0; nt < 4; nt++) {
      f32x4 a = a2[nt];
      s[nt] += (a[0] + a[1]) + (a[2] + a[3]);
      q[nt] += fmaf(a[0], a[0], fmaf(a[1], a[1], fmaf(a[2], a[2], a[3] * a[3])));
      mx[nt] = fmaxf(mx[nt], fmaxf(fmaxf(a[0], a[1]), fmaxf(a[2], a[3])));
      mn[nt] = fminf(mn[nt], fminf(fminf(a[0], a[1]), fminf(a[2], a[3])));
    }
  }
#pragma unroll
  for (int nt = 0; nt < 4; nt++) {
    s[nt] += __shfl_xor(s[nt], 16);
    s[nt] += __shfl_xor(s[nt], 32);
    q[nt] += __shfl_xor(q[nt], 16);
    q[nt] += __shfl_xor(q[nt], 32);
    mx[nt] = fmaxf(mx[nt], __shfl_xor(mx[nt], 16));
    mx[nt] = fmaxf(mx[nt], __shfl_xor(mx[nt], 32));
    mn[nt] = fminf(mn[nt], __shfl_xor(mn[nt], 16));
    mn[nt] = fminf(mn[nt], __shfl_xor(mn[nt], 32));
  }
  if (lane < 16) {
#pragma unroll
    for (int nt = 0; nt < 4; nt++) {
      int col = cq + nt * 16 + lr;
      maxb[(size_t)bs * 256 + col] = mx[nt];
      minb[(size_t)bs * 256 + col] = mn[nt];
      psum[(size_t)bs * 256 + col] = s[nt];
      psq[(size_t)bs * 256 + col] = q[nt];
    }
  }
}

// fold BN stats into per-channel affine: a = g*rsqrt(var+eps); c = be - mean*a
// one block per channel; threads stride the 8192 per-block partials (no atomics anywhere)
__global__ __launch_bounds__(256) void k_fin(const float* __restrict__ psum, const float* __restrict__ psq,
                                             const float* __restrict__ g, const float* __restrict__ be,
                                             float* __restrict__ sc, float* __restrict__ sh, int nch) {
  int o = blockIdx.x, t = threadIdx.x;
  float s = 0.f, q = 0.f;
  for (int k = t; k < 8192; k += 256) {
    s += psum[(size_t)k * nch + o];
    q += psq[(size_t)k * nch + o];
  }
#pragma unroll
  for (int off = 32; off > 0; off >>= 1) {
    s += __shfl_down(s, off);
    q += __shfl_down(q, off);
  }
  __shared__ float rs[4], rq[4];
  if ((t & 63) == 0) { rs[t >> 6] = s; rq[t >> 6] = q; }
  __syncthreads();
  if (t == 0) {
    s = (rs[0] + rs[1]) + (rs[2] + rs[3]);
    q = (rq[0] + rq[1]) + (rq[2] + rq[3]);
    const float inv = 1.0f / 524288.0f;
    float m = s * inv;
    float ey2 = q * inv;
    float v = fmaf(-m, m, ey2);
    v = fmaxf(v, 0.f);
    float r = rsqrtf(v + EPSV);
    float a = g[o] * r;
    sc[o] = a;
    sh[o] = fmaf(-m, a, be[o]);
  }
}

// out[b, o, s] = relu(a*sel + c), sel = max if a>=0 else min
__global__ __launch_bounds__(256) void k_out(const float* __restrict__ maxb, const float* __restrict__ minb,
                                             const float* __restrict__ sc, const float* __restrict__ sh,
                                             float* __restrict__ out) {
  int flat = blockIdx.x * 256 + threadIdx.x;  // 2,097,152
  int b = flat >> 18;
  int o = (flat >> 10) & 255;
  int s = flat & 1023;
  float a = sc[o], c_ = sh[o];
  size_t mi = ((size_t)(b * 1024 + s)) * 256 + o;
  float v = (a >= 0.f) ? maxb[mi] : minb[mi];
  out[OUT_FEAT + flat] = fmaxf(fmaf(a, v, c_), 0.f);
}

extern "C" void kernel_launch(void* const* d_in, const int* in_sizes, int n_in,
                              void* d_out, int out_size, void* d_ws, size_t ws_size,
                              hipStream_t stream) {
  const float* xyz = (const float*)d_in[0];
  const float* pts = (const float*)d_in[1];
  const int* fps = (const int*)d_in[2];
  const float* W0 = (const float*)d_in[3];
  const float* b0 = (const float*)d_in[4];
  const float* g0 = (const float*)d_in[5];
  const float* be0 = (const float*)d_in[6];
  const float* W1 = (const float*)d_in[7];
  const float* b1 = (const float*)d_in[8];
  const float* g1 = (const float*)d_in[9];
  const float* be1 = (const float*)d_in[10];
  const float* W2 = (const float*)d_in[11];
  const float* b2 = (const float*)d_in[12];
  const float* g2 = (const float*)d_in[13];
  const float* be2 = (const float*)d_in[14];
  float* out = (float*)d_out;
  char* ws = (char*)d_ws;

  if (ws_size < WS_NEEDED) {
    k_newxyz<<<32, 256, 0, stream>>>(xyz, fps, out);
    return;
  }

  _Float16* ptsT = (_Float16*)(ws + O_PT);
  int* idxb = (int*)(ws + O_IDX);
  float* maxbf = (float*)(ws + O_MAXB);
  float* minbf = (float*)(ws + O_MINB);
  _Float16* W0h = (_Float16*)(ws + O_W0T);
  _Float16* W1h = (_Float16*)(ws + O_W1T);
  _Float16* W2h = (_Float16*)(ws + O_W2T);
  float* ps0 = (float*)(ws + O_PS0);
  float* pq0 = (float*)(ws + O_PQ0);
  float* ps1 = (float*)(ws + O_PS1);
  float* pq1 = (float*)(ws + O_PQ1);
  float* ps2 = (float*)(ws + O_PS2);
  float* pq2 = (float*)(ws + O_PQ2);
  float* sc0 = (float*)(ws + O_SC0);
  float* sh0 = (float*)(ws + O_SH0);
  float* sc1 = (float*)(ws + O_SC1);
  float* sh1 = (float*)(ws + O_SH1);
  float* sc2 = (float*)(ws + O_SC2);
  float* sh2 = (float*)(ws + O_SH2);

  k_transpose_pts<<<dim3(NN / 64, DD / 64, BB), 256, 0, stream>>>(pts, ptsT);
  k_wt<<<272, 256, 0, stream>>>(W0, W1, W2, W0h, W1h, W2h);
  k_ballq<<<2048, 256, 0, stream>>>(xyz, fps, idxb, out);
  k_pass1<<<8192, 256, 0, stream>>>(xyz, ptsT, fps, idxb, W0h, b0, ps0, pq0);
  k_fin<<<128, 256, 0, stream>>>(ps0, pq0, g0, be0, sc0, sh0, 128);
  k_pass2<<<8192, 256, 0, stream>>>(xyz, ptsT, fps, idxb, W0h, b0, sc0, sh0, W1h, b1, ps1, pq1);
  k_fin<<<128, 256, 0, stream>>>(ps1, pq1, g1, be1, sc1, sh1, 128);
  k_pass3<<<8192, 256, 0, stream>>>(xyz, ptsT, fps, idxb, W0h, b0, sc0, sh0, W1h, b1, sc1, sh1,
                                    W2h, b2, maxbf, minbf, ps2, pq2);
  k_fin<<<256, 256, 0, stream>>>(ps2, pq2, g2, be2, sc2, sh2, 256);
  k_out<<<8192, 256, 0, stream>>>(maxbf, minbf, sc2, sh2, out);
}

// Round 9
// 485.200 us; speedup vs baseline: 1.9571x; 1.0679x over previous
//
#include <hip/hip_runtime.h>

#define BB 8
#define NN 16384
#define SS 1024
#define NSMP 64
#define DD 128
#define R2 0.04f
#define EPSV 1e-5f

typedef _Float16 half8t __attribute__((ext_vector_type(8)));
typedef float f32x4 __attribute__((ext_vector_type(4)));

// ---- workspace layout (bytes); MUST stay under 256 MiB (harness ws size) ----
#define O_PT    0ull                 // pointsT fp16: 8*16384*128*2 = 33,554,432
#define O_IDX   33554432ull          // idx int32: 8192*64*4 = 2,097,152
#define O_MAXB  35651584ull          // 8192*256*4 = 8,388,608
#define O_MINB  44040192ull          // 8,388,608
#define O_W0T   52428800ull          // W0h fp16 [128][136] = 34,816
#define O_W1T   52463616ull          // W1h fp16 [128][136] = 34,816
#define O_W2T   52498432ull          // W2h fp16 [256][136] = 69,632
#define O_PS0   52568064ull          // per-block partials [8192][128] f32 = 4,194,304
#define O_PQ0   56762368ull          // 4,194,304
#define O_PS1   60956672ull          // 4,194,304
#define O_PQ1   65150976ull          // 4,194,304
#define O_PS2   69345280ull          // [8192][256] f32 = 8,388,608
#define O_PQ2   77733888ull          // 8,388,608
#define O_SC0   86122496ull
#define O_SH0   86123008ull
#define O_SC1   86123520ull
#define O_SH1   86124032ull
#define O_SC2   86124544ull
#define O_SH2   86125568ull
#define O_Y     86126592ull          // y fp16 [8192][64][128] = 134,217,728 (in-place L0->L1)
#define WS_NEEDED 220344320ull

#define OUT_XYZ 0
#define OUT_FEAT 24576
#define OUT_FPS (24576 + 2097152)

// points [B,D,N] fp32 -> pointsT [B,N,D] fp16. 64n x 64c tile; half8 (16B) stores.
__global__ __launch_bounds__(256) void k_transpose_pts(const float* __restrict__ pts,
                                                       _Float16* __restrict__ ptsT) {
  __shared__ float tile[64][65];
  int b = blockIdx.z;
  int n0 = blockIdx.x * 64, c0 = blockIdx.y * 64;
  int t = threadIdx.x;
  int cg = t >> 6, ln = t & 63;
#pragma unroll
  for (int k = 0; k < 16; k++) {
    int c = cg * 16 + k;
    tile[c][ln] = pts[((size_t)b * DD + c0 + c) * NN + n0 + ln];
  }
  __syncthreads();
  int n = t >> 2, sub = t & 3;
#pragma unroll
  for (int j = 0; j < 2; j++) {
    int cb = sub * 16 + j * 8;
    half8t h;
#pragma unroll
    for (int k = 0; k < 8; k++) h[k] = (_Float16)tile[cb + k][n];
    *(half8t*)(ptsT + ((size_t)b * NN + n0 + n) * DD + c0 + cb) = h;
  }
}

// weights -> fp16, [out][in] stride 136, zero-padded.
// W0 channels remapped: xh has feats at c=0..127, relxyz at 128..130
__global__ __launch_bounds__(256) void k_wt(const float* __restrict__ W0, const float* __restrict__ W1,
                                            const float* __restrict__ W2, _Float16* __restrict__ W0h,
                                            _Float16* __restrict__ W1h, _Float16* __restrict__ W2h) {
  int id = blockIdx.x * 256 + threadIdx.x;
  const int T0 = 128 * 136, T1 = 128 * 136, T2 = 256 * 136;
  if (id < T0) {
    int o = id / 136, c = id % 136;
    float v = 0.f;
    if (c < 131) {
      int c0 = (c < 128) ? (c + 3) : (c - 128);
      v = W0[o * 131 + c0];
    }
    W0h[id] = (_Float16)v;
  } else if (id < T0 + T1) {
    int j = id - T0;
    int o = j / 136, c = j % 136;
    W1h[j] = (_Float16)((c < 128) ? W1[o * 128 + c] : 0.f);
  } else if (id < T0 + T1 + T2) {
    int j = id - T0 - T1;
    int o = j / 136, c = j % 136;
    W2h[j] = (_Float16)((c < 128) ? W2[o * 128 + c] : 0.f);
  }
}

// fallback when workspace undersized
__global__ __launch_bounds__(256) void k_newxyz(const float* __restrict__ xyz, const int* __restrict__ fps,
                                                float* __restrict__ out) {
  int id = blockIdx.x * 256 + threadIdx.x;  // B*S
  int fi = fps[id];
  int b = id >> 10;
  const float* p = xyz + ((size_t)b * NN + fi) * 3;
  float* o = out + OUT_XYZ + (size_t)id * 3;
  o[0] = p[0]; o[1] = p[1]; o[2] = p[2];
  out[OUT_FPS + id] = (float)fi;
}

// one wave per (b,s): first-NS valid indices ascending, pad with first valid.
// Also emits new_xyz and fps passthrough outputs.
__global__ __launch_bounds__(256) void k_ballq(const float* __restrict__ xyz, const int* __restrict__ fps,
                                               int* __restrict__ idxb, float* __restrict__ out) {
  int w = (blockIdx.x * 256 + threadIdx.x) >> 6;
  int lane = threadIdx.x & 63;
  int b = w >> 10;
  int fi = fps[w];
  const float* cp = xyz + ((size_t)b * NN + fi) * 3;
  float cx = cp[0], cy = cp[1], cz = cp[2];
  if (lane < 3) out[OUT_XYZ + (size_t)w * 3 + lane] = (lane == 0) ? cx : ((lane == 1) ? cy : cz);
  if (lane == 3) out[OUT_FPS + w] = (float)fi;
  float A = __fadd_rn(__fadd_rn(__fmul_rn(cx, cx), __fmul_rn(cy, cy)), __fmul_rn(cz, cz));
  const float* xb = xyz + (size_t)b * NN * 3;
  int cnt = 0, firstn = -1;
  int* myidx = idxb + (size_t)w * NSMP;
  for (int nb = 0; nb < NN && cnt < NSMP; nb += 64) {
    int n = nb + lane;
    float px = xb[n * 3], py = xb[n * 3 + 1], pz = xb[n * 3 + 2];
    float Bv = __fadd_rn(__fadd_rn(__fmul_rn(px, px), __fmul_rn(py, py)), __fmul_rn(pz, pz));
    float dot = __fadd_rn(__fadd_rn(__fmul_rn(cx, px), __fmul_rn(cy, py)), __fmul_rn(cz, pz));
    float d = __fsub_rn(__fadd_rn(A, Bv), __fmul_rn(2.0f, dot));
    bool valid = !(d > R2);
    unsigned long long mask = __ballot(valid);
    if (firstn < 0 && mask) firstn = nb + __builtin_ctzll(mask);
    int prefix = __popcll(mask & ((1ull << lane) - 1ull));
    int pos = cnt + prefix;
    if (valid && pos < NSMP) myidx[pos] = n;
    cnt += __popcll(mask);
    if (cnt > NSMP) cnt = NSMP;
  }
  if (lane >= cnt) myidx[lane] = firstn;
}

// ---------- shared device pieces ----------

__device__ __forceinline__ void load_ball(const float* __restrict__ xyz,
                                          const _Float16* __restrict__ ptsT,
                                          const int* __restrict__ fps, const int* __restrict__ idxb,
                                          int bs, int b, int t, _Float16* xh, int* smidx, float* smc) {
  if (t < 64) smidx[t] = idxb[(size_t)bs * 64 + t];
  if (t < 3) {
    int fi = fps[bs];
    smc[t] = xyz[((size_t)b * NN + fi) * 3 + t];
  }
  __syncthreads();
  {
    int row = t >> 2, q = t & 3;
    int n = smidx[row];
    const half8t* src = (const half8t*)(ptsT + ((size_t)b * NN + n) * DD);
#pragma unroll
    for (int i = 0; i < 4; i++) {
      int j = q + i * 4;
      *(half8t*)(xh + row * 136 + j * 8) = src[j];
    }
  }
  if (t < 64) {
    int n = smidx[t];
    const float* p = xyz + ((size_t)b * NN + n) * 3;
    xh[t * 136 + 128] = (_Float16)(p[0] - smc[0]);
    xh[t * 136 + 129] = (_Float16)(p[1] - smc[1]);
    xh[t * 136 + 130] = (_Float16)(p[2] - smc[2]);
  }
  __syncthreads();
}

// coalesced read of y[bs] (64x128 fp16) + per-channel affine+relu -> xh
__device__ __forceinline__ void read_y_aff(const _Float16* __restrict__ yb,
                                           const float* __restrict__ sc, const float* __restrict__ sh,
                                           int t, _Float16* xh) {
#pragma unroll
  for (int i = 0; i < 4; i++) {
    int flat = (i * 256 + t) * 8;
    int row = flat >> 7, col = flat & 127;
    half8t h = *(const half8t*)(yb + flat);
    half8t o;
#pragma unroll
    for (int k = 0; k < 8; k++) {
      float v = fmaxf(fmaf((float)h[k], sc[col + k], sh[col + k]), 0.f);
      o[k] = (_Float16)v;
    }
    *(half8t*)(xh + row * 136 + col) = o;
  }
  __syncthreads();
}

// Layer over K=128 with wave-owned column group (NT groups of 16 cols, base cb).
// Each wave computes ALL 64 rows (m=0..3 tiles) for its cols; W rows read once per block.
template <int NT>
__device__ __forceinline__ void layer_cols(const _Float16* xh, const _Float16* __restrict__ Wh,
                                           const float* __restrict__ bias, int cb, int lr, int lk,
                                           f32x4 acc[4][NT]) {
  half8t bw[NT][4];
#pragma unroll
  for (int nt = 0; nt < NT; nt++)
#pragma unroll
    for (int kt = 0; kt < 4; kt++)
      bw[nt][kt] = *(const half8t*)(Wh + (cb + nt * 16 + lr) * 136 + kt * 32 + lk * 8);
  float bv[NT];
#pragma unroll
  for (int nt = 0; nt < NT; nt++) bv[nt] = bias[cb + nt * 16 + lr];
#pragma unroll
  for (int m = 0; m < 4; m++) {
    half8t afr[4];
#pragma unroll
    for (int kt = 0; kt < 4; kt++)
      afr[kt] = *(const half8t*)(xh + (m * 16 + lr) * 136 + kt * 32 + lk * 8);
#pragma unroll
    for (int nt = 0; nt < NT; nt++) {
      f32x4 cv = {bv[nt], bv[nt], bv[nt], bv[nt]};
      acc[m][nt] = cv;
    }
#pragma unroll
    for (int kt = 0; kt < 4; kt++)
#pragma unroll
      for (int nt = 0; nt < NT; nt++)
        acc[m][nt] = __builtin_amdgcn_mfma_f32_16x16x32_f16(afr[kt], bw[nt][kt], acc[m][nt], 0, 0, 0);
  }
}

// add the 3 relative-xyz channels (c=128..130) for layer0 on the VALU
__device__ __forceinline__ void l0_relxyz(const _Float16* xh, const _Float16* __restrict__ W0h,
                                          int cb, int lr, int lk, f32x4 acc[4][2]) {
  float wx[2][3];
#pragma unroll
  for (int nt = 0; nt < 2; nt++) {
    const _Float16* wp = W0h + (cb + nt * 16 + lr) * 136 + 128;
    wx[nt][0] = (float)wp[0]; wx[nt][1] = (float)wp[1]; wx[nt][2] = (float)wp[2];
  }
#pragma unroll
  for (int m = 0; m < 4; m++) {
#pragma unroll
    for (int r = 0; r < 4; r++) {
      int row = m * 16 + lk * 4 + r;
      float x0 = (float)xh[row * 136 + 128];
      float x1 = (float)xh[row * 136 + 129];
      float x2 = (float)xh[row * 136 + 130];
#pragma unroll
      for (int nt = 0; nt < 2; nt++)
        acc[m][nt][r] += x0 * wx[nt][0] + x1 * wx[nt][1] + x2 * wx[nt][2];
    }
  }
}

// wave-private stats over all 64 rows of the wave's NT*16 cols; no LDS, no barrier.
template <int NT>
__device__ __forceinline__ void stats_cols(const f32x4 acc[4][NT], int lane, int cb, int lr,
                                           float* __restrict__ psum, float* __restrict__ psq,
                                           int bs, int nch) {
  float s[NT], q[NT];
#pragma unroll
  for (int nt = 0; nt < NT; nt++) { s[nt] = 0.f; q[nt] = 0.f; }
#pragma unroll
  for (int m = 0; m < 4; m++)
#pragma unroll
    for (int nt = 0; nt < NT; nt++) {
      f32x4 a = acc[m][nt];
      s[nt] += (a[0] + a[1]) + (a[2] + a[3]);
      q[nt] += fmaf(a[0], a[0], fmaf(a[1], a[1], fmaf(a[2], a[2], a[3] * a[3])));
    }
#pragma unroll
  for (int nt = 0; nt < NT; nt++) {
    s[nt] += __shfl_xor(s[nt], 16);
    s[nt] += __shfl_xor(s[nt], 32);
    q[nt] += __shfl_xor(q[nt], 16);
    q[nt] += __shfl_xor(q[nt], 32);
  }
  if (lane < 16) {
#pragma unroll
    for (int nt = 0; nt < NT; nt++) {
      int col = cb + nt * 16 + lr;
      psum[(size_t)bs * nch + col] = s[nt];
      psq[(size_t)bs * nch + col] = q[nt];
    }
  }
}

// raw acc -> y[bs] (fp16 scalar stores; each wave writes its own cols, all rows)
template <int NT>
__device__ __forceinline__ void write_y_cols(_Float16* __restrict__ yb, int cb, int lr, int lk,
                                             const f32x4 acc[4][NT]) {
#pragma unroll
  for (int nt = 0; nt < NT; nt++) {
    int col = cb + nt * 16 + lr;
#pragma unroll
    for (int m = 0; m < 4; m++)
#pragma unroll
      for (int r = 0; r < 4; r++)
        yb[(m * 16 + lk * 4 + r) * 128 + col] = (_Float16)acc[m][nt][r];
  }
}

// ---------- single-layer passes (y materialized in-place; no recompute) ----------

// pass1: gather -> L0 -> stats0 + write raw y0
__global__ __launch_bounds__(256) void k_pass1(const float* __restrict__ xyz,
                                               const _Float16* __restrict__ ptsT,
                                               const int* __restrict__ fps, const int* __restrict__ idxb,
                                               const _Float16* __restrict__ W0h, const float* __restrict__ b0,
                                               _Float16* __restrict__ y,
                                               float* __restrict__ psum, float* __restrict__ psq) {
  __shared__ _Float16 xh[64 * 136];
  __shared__ int smidx[64];
  __shared__ float smc[3];
  int t = threadIdx.x;
  int bs = blockIdx.x;
  int b = bs >> 10;
  load_ball(xyz, ptsT, fps, idxb, bs, b, t, xh, smidx, smc);
  int lane = t & 63, wv = t >> 6;
  int lr = lane & 15, lk = lane >> 4;
  int cb = __builtin_amdgcn_readfirstlane(wv * 32);
  f32x4 acc[4][2];
  layer_cols<2>(xh, W0h, b0, cb, lr, lk, acc);
  l0_relxyz(xh, W0h, cb, lr, lk, acc);
  stats_cols<2>(acc, lane, cb, lr, psum, psq, bs, 128);
  write_y_cols<2>(y + (size_t)bs * 8192, cb, lr, lk, acc);
}

// pass2: read y0 + aff0+relu -> L1 -> stats1 + write raw y1 (in-place over y0)
__global__ __launch_bounds__(256) void k_pass2(const float* __restrict__ sc0, const float* __restrict__ sh0,
                                               const _Float16* __restrict__ W1h, const float* __restrict__ b1,
                                               _Float16* __restrict__ y,
                                               float* __restrict__ psum, float* __restrict__ psq) {
  __shared__ _Float16 xh[64 * 136];
  int t = threadIdx.x;
  int bs = blockIdx.x;
  _Float16* yb = y + (size_t)bs * 8192;
  read_y_aff(yb, sc0, sh0, t, xh);
  int lane = t & 63, wv = t >> 6;
  int lr = lane & 15, lk = lane >> 4;
  int cb = __builtin_amdgcn_readfirstlane(wv * 32);
  f32x4 acc[4][2];
  layer_cols<2>(xh, W1h, b1, cb, lr, lk, acc);
  stats_cols<2>(acc, lane, cb, lr, psum, psq, bs, 128);
  write_y_cols<2>(yb, cb, lr, lk, acc);
}

// pass3: read y1 + aff1+relu -> L2 -> max/min + stats2
__global__ __launch_bounds__(256) void k_pass3(const float* __restrict__ sc1, const float* __restrict__ sh1,
                                               const _Float16* __restrict__ W2h, const float* __restrict__ b2,
                                               const _Float16* __restrict__ y,
                                               float* __restrict__ maxb, float* __restrict__ minb,
                                               float* __restrict__ psum, float* __restrict__ psq) {
  __shared__ _Float16 xh[64 * 136];
  int t = threadIdx.x;
  int bs = blockIdx.x;
  read_y_aff(y + (size_t)bs * 8192, sc1, sh1, t, xh);
  int lane = t & 63, wv = t >> 6;
  int lr = lane & 15, lk = lane >> 4;
  // layer2: wave owns 64 cols; stream m-tiles, keep only stats (reg W cache)
  int cq = __builtin_amdgcn_readfirstlane(wv * 64);
  half8t bw[4][4];
#pragma unroll
  for (int nt = 0; nt < 4; nt++)
#pragma unroll
    for (int kt = 0; kt < 4; kt++)
      bw[nt][kt] = *(const half8t*)(W2h + (cq + nt * 16 + lr) * 136 + kt * 32 + lk * 8);
  float bv[4];
#pragma unroll
  for (int nt = 0; nt < 4; nt++) bv[nt] = b2[cq + nt * 16 + lr];
  float s[4] = {0.f, 0.f, 0.f, 0.f}, q[4] = {0.f, 0.f, 0.f, 0.f};
  float mx[4], mn[4];
#pragma unroll
  for (int nt = 0; nt < 4; nt++) { mx[nt] = -3.4e38f; mn[nt] = 3.4e38f; }
#pragma unroll
  for (int m = 0; m < 4; m++) {
    half8t afr[4];
#pragma unroll
    for (int kt = 0; kt < 4; kt++)
      afr[kt] = *(const half8t*)(xh + (m * 16 + lr) * 136 + kt * 32 + lk * 8);
    f32x4 a2[4];
#pragma unroll
    for (int nt = 0; nt < 4; nt++) {
      f32x4 cv = {bv[nt], bv[nt], bv[nt], bv[nt]};
      a2[nt] = cv;
    }
#pragma unroll
    for (int kt = 0; kt < 4; kt++)
#pragma unroll
      for (int nt = 0; nt < 4; nt++)
        a2[nt] = __builtin_amdgcn_mfma_f32_16x16x32_f16(afr[kt], bw[nt][kt], a2[nt], 0, 0, 0);
#pragma unroll
    for (int nt = 0; nt < 4; nt++) {
      f32x4 a = a2[nt];
      s[nt] += (a[0] + a[1]) + (a[2] + a[3]);
      q[nt] += fmaf(a[0], a[0], fmaf(a[1], a[1], fmaf(a[2], a[2], a[3] * a[3])));
      mx[nt] = fmaxf(mx[nt], fmaxf(fmaxf(a[0], a[1]), fmaxf(a[2], a[3])));
      mn[nt] = fminf(mn[nt], fminf(fminf(a[0], a[1]), fminf(a[2], a[3])));
    }
  }
#pragma unroll
  for (int nt = 0; nt < 4; nt++) {
    s[nt] += __shfl_xor(s[nt], 16);
    s[nt] += __shfl_xor(s[nt], 32);
    q[nt] += __shfl_xor(q[nt], 16);
    q[nt] += __shfl_xor(q[nt], 32);
    mx[nt] = fmaxf(mx[nt], __shfl_xor(mx[nt], 16));
    mx[nt] = fmaxf(mx[nt], __shfl_xor(mx[nt], 32));
    mn[nt] = fminf(mn[nt], __shfl_xor(mn[nt], 16));
    mn[nt] = fminf(mn[nt], __shfl_xor(mn[nt], 32));
  }
  if (lane < 16) {
#pragma unroll
    for (int nt = 0; nt < 4; nt++) {
      int col = cq + nt * 16 + lr;
      maxb[(size_t)bs * 256 + col] = mx[nt];
      minb[(size_t)bs * 256 + col] = mn[nt];
      psum[(size_t)bs * 256 + col] = s[nt];
      psq[(size_t)bs * 256 + col] = q[nt];
    }
  }
}

// fold BN stats into per-channel affine: a = g*rsqrt(var+eps); c = be - mean*a
// one block per channel; threads stride the 8192 per-block partials (no atomics anywhere)
__global__ __launch_bounds__(256) void k_fin(const float* __restrict__ psum, const float* __restrict__ psq,
                                             const float* __restrict__ g, const float* __restrict__ be,
                                             float* __restrict__ sc, float* __restrict__ sh, int nch) {
  int o = blockIdx.x, t = threadIdx.x;
  float s = 0.f, q = 0.f;
  for (int k = t; k < 8192; k += 256) {
    s += psum[(size_t)k * nch + o];
    q += psq[(size_t)k * nch + o];
  }
#pragma unroll
  for (int off = 32; off > 0; off >>= 1) {
    s += __shfl_down(s, off);
    q += __shfl_down(q, off);
  }
  __shared__ float rs[4], rq[4];
  if ((t & 63) == 0) { rs[t >> 6] = s; rq[t >> 6] = q; }
  __syncthreads();
  if (t == 0) {
    s = (rs[0] + rs[1]) + (rs[2] + rs[3]);
    q = (rq[0] + rq[1]) + (rq[2] + rq[3]);
    const float inv = 1.0f / 524288.0f;
    float m = s * inv;
    float ey2 = q * inv;
    float v = fmaf(-m, m, ey2);
    v = fmaxf(v, 0.f);
    float r = rsqrtf(v + EPSV);
    float a = g[o] * r;
    sc[o] = a;
    sh[o] = fmaf(-m, a, be[o]);
  }
}

// out[b, o, s] = relu(a*sel + c), sel = max if a>=0 else min
__global__ __launch_bounds__(256) void k_out(const float* __restrict__ maxb, const float* __restrict__ minb,
                                             const float* __restrict__ sc, const float* __restrict__ sh,
                                             float* __restrict__ out) {
  int flat = blockIdx.x * 256 + threadIdx.x;  // 2,097,152
  int b = flat >> 18;
  int o = (flat >> 10) & 255;
  int s = flat & 1023;
  float a = sc[o], c_ = sh[o];
  size_t mi = ((size_t)(b * 1024 + s)) * 256 + o;
  float v = (a >= 0.f) ? maxb[mi] : minb[mi];
  out[OUT_FEAT + flat] = fmaxf(fmaf(a, v, c_), 0.f);
}

extern "C" void kernel_launch(void* const* d_in, const int* in_sizes, int n_in,
                              void* d_out, int out_size, void* d_ws, size_t ws_size,
                              hipStream_t stream) {
  const float* xyz = (const float*)d_in[0];
  const float* pts = (const float*)d_in[1];
  const int* fps = (const int*)d_in[2];
  const float* W0 = (const float*)d_in[3];
  const float* b0 = (const float*)d_in[4];
  const float* g0 = (const float*)d_in[5];
  const float* be0 = (const float*)d_in[6];
  const float* W1 = (const float*)d_in[7];
  const float* b1 = (const float*)d_in[8];
  const float* g1 = (const float*)d_in[9];
  const float* be1 = (const float*)d_in[10];
  const float* W2 = (const float*)d_in[11];
  const float* b2 = (const float*)d_in[12];
  const float* g2 = (const float*)d_in[13];
  const float* be2 = (const float*)d_in[14];
  float* out = (float*)d_out;
  char* ws = (char*)d_ws;

  if (ws_size < WS_NEEDED) {
    k_newxyz<<<32, 256, 0, stream>>>(xyz, fps, out);
    return;
  }

  _Float16* ptsT = (_Float16*)(ws + O_PT);
  int* idxb = (int*)(ws + O_IDX);
  float* maxbf = (float*)(ws + O_MAXB);
  float* minbf = (float*)(ws + O_MINB);
  _Float16* W0h = (_Float16*)(ws + O_W0T);
  _Float16* W1h = (_Float16*)(ws + O_W1T);
  _Float16* W2h = (_Float16*)(ws + O_W2T);
  float* ps0 = (float*)(ws + O_PS0);
  float* pq0 = (float*)(ws + O_PQ0);
  float* ps1 = (float*)(ws + O_PS1);
  float* pq1 = (float*)(ws + O_PQ1);
  float* ps2 = (float*)(ws + O_PS2);
  float* pq2 = (float*)(ws + O_PQ2);
  float* sc0 = (float*)(ws + O_SC0);
  float* sh0 = (float*)(ws + O_SH0);
  float* sc1 = (float*)(ws + O_SC1);
  float* sh1 = (float*)(ws + O_SH1);
  float* sc2 = (float*)(ws + O_SC2);
  float* sh2 = (float*)(ws + O_SH2);
  _Float16* y = (_Float16*)(ws + O_Y);

  k_transpose_pts<<<dim3(NN / 64, DD / 64, BB), 256, 0, stream>>>(pts, ptsT);
  k_wt<<<272, 256, 0, stream>>>(W0, W1, W2, W0h, W1h, W2h);
  k_ballq<<<2048, 256, 0, stream>>>(xyz, fps, idxb, out);
  k_pass1<<<8192, 256, 0, stream>>>(xyz, ptsT, fps, idxb, W0h, b0, y, ps0, pq0);
  k_fin<<<128, 256, 0, stream>>>(ps0, pq0, g0, be0, sc0, sh0, 128);
  k_pass2<<<8192, 256, 0, stream>>>(sc0, sh0, W1h, b1, y, ps1, pq1);
  k_fin<<<128, 256, 0, stream>>>(ps1, pq1, g1, be1, sc1, sh1, 128);
  k_pass3<<<8192, 256, 0, stream>>>(sc1, sh1, W2h, b2, y, maxbf, minbf, ps2, pq2);
  k_fin<<<256, 256, 0, stream>>>(ps2, pq2, g2, be2, sc2, sh2, 256);
  k_out<<<8192, 256, 0, stream>>>(maxbf, minbf, sc2, sh2, out);
}

// Round 10
// 430.610 us; speedup vs baseline: 2.2053x; 1.1268x over previous
//
#include <hip/hip_runtime.h>

#define BB 8
#define NN 16384
#define SS 1024
#define NSMP 64
#define DD 128
#define R2 0.04f
#define EPSV 1e-5f

typedef _Float16 half8t __attribute__((ext_vector_type(8)));
typedef float f32x4 __attribute__((ext_vector_type(4)));

// ---- workspace layout (bytes); MUST stay under 256 MiB (harness ws size) ----
#define O_PT    0ull                 // pointsT fp16: 8*16384*128*2 = 33,554,432
#define O_IDX   33554432ull          // idx int32: 8192*64*4 = 2,097,152
#define O_MAXB  35651584ull          // 8192*256*4 = 8,388,608
#define O_MINB  44040192ull          // 8,388,608
#define O_W0T   52428800ull          // W0h fp16 [128][136] = 34,816
#define O_W1T   52463616ull          // W1h fp16 [128][136] = 34,816
#define O_W2T   52498432ull          // W2h fp16 [256][136] = 69,632
#define O_PS0   52568064ull          // per-block partials [8192][128] f32 = 4,194,304
#define O_PQ0   56762368ull          // 4,194,304
#define O_PS1   60956672ull          // 4,194,304
#define O_PQ1   65150976ull          // 4,194,304
#define O_PS2   69345280ull          // [8192][256] f32 = 8,388,608
#define O_PQ2   77733888ull          // 8,388,608
#define O_SC0   86122496ull
#define O_SH0   86123008ull
#define O_SC1   86123520ull
#define O_SH1   86124032ull
#define O_SC2   86124544ull
#define O_SH2   86125568ull
#define O_Y     86126592ull          // y fp16 [8192][64][128] = 134,217,728 (in-place L0->L1)
#define WS_NEEDED 220344320ull

#define OUT_XYZ 0
#define OUT_FEAT 24576
#define OUT_FPS (24576 + 2097152)

// points [B,D,N] fp32 -> pointsT [B,N,D] fp16. 64n x 64c tile; half8 (16B) stores.
__global__ __launch_bounds__(256) void k_transpose_pts(const float* __restrict__ pts,
                                                       _Float16* __restrict__ ptsT) {
  __shared__ float tile[64][65];
  int b = blockIdx.z;
  int n0 = blockIdx.x * 64, c0 = blockIdx.y * 64;
  int t = threadIdx.x;
  int cg = t >> 6, ln = t & 63;
#pragma unroll
  for (int k = 0; k < 16; k++) {
    int c = cg * 16 + k;
    tile[c][ln] = pts[((size_t)b * DD + c0 + c) * NN + n0 + ln];
  }
  __syncthreads();
  int n = t >> 2, sub = t & 3;
#pragma unroll
  for (int j = 0; j < 2; j++) {
    int cb = sub * 16 + j * 8;
    half8t h;
#pragma unroll
    for (int k = 0; k < 8; k++) h[k] = (_Float16)tile[cb + k][n];
    *(half8t*)(ptsT + ((size_t)b * NN + n0 + n) * DD + c0 + cb) = h;
  }
}

// weights -> fp16, [out][in] stride 136, zero-padded.
// W0 channels remapped: xh has feats at c=0..127, relxyz at 128..130
__global__ __launch_bounds__(256) void k_wt(const float* __restrict__ W0, const float* __restrict__ W1,
                                            const float* __restrict__ W2, _Float16* __restrict__ W0h,
                                            _Float16* __restrict__ W1h, _Float16* __restrict__ W2h) {
  int id = blockIdx.x * 256 + threadIdx.x;
  const int T0 = 128 * 136, T1 = 128 * 136, T2 = 256 * 136;
  if (id < T0) {
    int o = id / 136, c = id % 136;
    float v = 0.f;
    if (c < 131) {
      int c0 = (c < 128) ? (c + 3) : (c - 128);
      v = W0[o * 131 + c0];
    }
    W0h[id] = (_Float16)v;
  } else if (id < T0 + T1) {
    int j = id - T0;
    int o = j / 136, c = j % 136;
    W1h[j] = (_Float16)((c < 128) ? W1[o * 128 + c] : 0.f);
  } else if (id < T0 + T1 + T2) {
    int j = id - T0 - T1;
    int o = j / 136, c = j % 136;
    W2h[j] = (_Float16)((c < 128) ? W2[o * 128 + c] : 0.f);
  }
}

// fallback when workspace undersized
__global__ __launch_bounds__(256) void k_newxyz(const float* __restrict__ xyz, const int* __restrict__ fps,
                                                float* __restrict__ out) {
  int id = blockIdx.x * 256 + threadIdx.x;  // B*S
  int fi = fps[id];
  int b = id >> 10;
  const float* p = xyz + ((size_t)b * NN + fi) * 3;
  float* o = out + OUT_XYZ + (size_t)id * 3;
  o[0] = p[0]; o[1] = p[1]; o[2] = p[2];
  out[OUT_FPS + id] = (float)fi;
}

// one wave per (b,s): first-NS valid indices ascending, pad with first valid.
// 4 points per lane per iteration (256 pts/iter) — worst-case tail waves do 64
// iterations instead of 256 (latency-bound loop). Ordering: point n = nb+4*lane+j
// is l-major => ascending n; prefix via 4 ballots + masked popcounts (no shfl chain).
// Distance arithmetic kept bit-identical to the passing version (__f*_rn, same assoc).
__global__ __launch_bounds__(256) void k_ballq(const float* __restrict__ xyz, const int* __restrict__ fps,
                                               int* __restrict__ idxb, float* __restrict__ out) {
  int w = (blockIdx.x * 256 + threadIdx.x) >> 6;
  int lane = threadIdx.x & 63;
  int b = w >> 10;
  int fi = fps[w];
  const float* cp = xyz + ((size_t)b * NN + fi) * 3;
  float cx = cp[0], cy = cp[1], cz = cp[2];
  if (lane < 3) out[OUT_XYZ + (size_t)w * 3 + lane] = (lane == 0) ? cx : ((lane == 1) ? cy : cz);
  if (lane == 3) out[OUT_FPS + w] = (float)fi;
  float A = __fadd_rn(__fadd_rn(__fmul_rn(cx, cx), __fmul_rn(cy, cy)), __fmul_rn(cz, cz));
  const float* xb = xyz + (size_t)b * NN * 3;
  int cnt = 0, firstn = -1;
  int* myidx = idxb + (size_t)w * NSMP;
  unsigned long long below = (lane == 0) ? 0ull : (~0ull >> (64 - lane));
  for (int nb = 0; nb < NN && cnt < NSMP; nb += 256) {
    int n0 = nb + lane * 4;
    const f32x4* p4 = (const f32x4*)(xb + (size_t)n0 * 3);
    f32x4 f0 = p4[0], f1 = p4[1], f2 = p4[2];
    float px[4] = {f0[0], f0[3], f1[2], f2[1]};
    float py[4] = {f0[1], f1[0], f1[3], f2[2]};
    float pz[4] = {f0[2], f1[1], f2[0], f2[3]};
    unsigned m = 0;
#pragma unroll
    for (int j = 0; j < 4; j++) {
      float Bv = __fadd_rn(__fadd_rn(__fmul_rn(px[j], px[j]), __fmul_rn(py[j], py[j])),
                           __fmul_rn(pz[j], pz[j]));
      float dot = __fadd_rn(__fadd_rn(__fmul_rn(cx, px[j]), __fmul_rn(cy, py[j])),
                            __fmul_rn(cz, pz[j]));
      float d = __fsub_rn(__fadd_rn(A, Bv), __fmul_rn(2.0f, dot));
      if (!(d > R2)) m |= 1u << j;
    }
    unsigned long long bl0 = __ballot((m & 1u) != 0u);
    unsigned long long bl1 = __ballot((m & 2u) != 0u);
    unsigned long long bl2 = __ballot((m & 4u) != 0u);
    unsigned long long bl3 = __ballot((m & 8u) != 0u);
    unsigned long long anyb = bl0 | bl1 | bl2 | bl3;
    if (firstn < 0 && anyb) {
      int l0 = __builtin_ctzll(anyb);
      int j0 = ((bl0 >> l0) & 1ull) ? 0 : ((bl1 >> l0) & 1ull) ? 1 : ((bl2 >> l0) & 1ull) ? 2 : 3;
      firstn = nb + l0 * 4 + j0;
    }
    int excl = __popcll(bl0 & below) + __popcll(bl1 & below) +
               __popcll(bl2 & below) + __popcll(bl3 & below);
    int pos = cnt + excl;
#pragma unroll
    for (int j = 0; j < 4; j++) {
      if (m & (1u << j)) {
        if (pos < NSMP) myidx[pos] = n0 + j;
        pos++;
      }
    }
    cnt += __popcll(bl0) + __popcll(bl1) + __popcll(bl2) + __popcll(bl3);
    if (cnt > NSMP) cnt = NSMP;
  }
  if (lane >= cnt) myidx[lane] = firstn;
}

// ---------- shared device pieces ----------

__device__ __forceinline__ void load_ball(const float* __restrict__ xyz,
                                          const _Float16* __restrict__ ptsT,
                                          const int* __restrict__ fps, const int* __restrict__ idxb,
                                          int bs, int b, int t, _Float16* xh, int* smidx, float* smc) {
  if (t < 64) smidx[t] = idxb[(size_t)bs * 64 + t];
  if (t < 3) {
    int fi = fps[bs];
    smc[t] = xyz[((size_t)b * NN + fi) * 3 + t];
  }
  __syncthreads();
  {
    int row = t >> 2, q = t & 3;
    int n = smidx[row];
    const half8t* src = (const half8t*)(ptsT + ((size_t)b * NN + n) * DD);
#pragma unroll
    for (int i = 0; i < 4; i++) {
      int j = q + i * 4;
      *(half8t*)(xh + row * 136 + j * 8) = src[j];
    }
  }
  if (t < 64) {
    int n = smidx[t];
    const float* p = xyz + ((size_t)b * NN + n) * 3;
    xh[t * 136 + 128] = (_Float16)(p[0] - smc[0]);
    xh[t * 136 + 129] = (_Float16)(p[1] - smc[1]);
    xh[t * 136 + 130] = (_Float16)(p[2] - smc[2]);
  }
  __syncthreads();
}

// coalesced read of y[bs] (64x128 fp16) + per-channel affine+relu -> xh
__device__ __forceinline__ void read_y_aff(const _Float16* __restrict__ yb,
                                           const float* __restrict__ sc, const float* __restrict__ sh,
                                           int t, _Float16* xh) {
#pragma unroll
  for (int i = 0; i < 4; i++) {
    int flat = (i * 256 + t) * 8;
    int row = flat >> 7, col = flat & 127;
    half8t h = *(const half8t*)(yb + flat);
    half8t o;
#pragma unroll
    for (int k = 0; k < 8; k++) {
      float v = fmaxf(fmaf((float)h[k], sc[col + k], sh[col + k]), 0.f);
      o[k] = (_Float16)v;
    }
    *(half8t*)(xh + row * 136 + col) = o;
  }
  __syncthreads();
}

// Layer over K=128 with wave-owned column group (NT groups of 16 cols, base cb).
// Each wave computes ALL 64 rows (m=0..3 tiles) for its cols; W rows read once per block.
template <int NT>
__device__ __forceinline__ void layer_cols(const _Float16* xh, const _Float16* __restrict__ Wh,
                                           const float* __restrict__ bias, int cb, int lr, int lk,
                                           f32x4 acc[4][NT]) {
  half8t bw[NT][4];
#pragma unroll
  for (int nt = 0; nt < NT; nt++)
#pragma unroll
    for (int kt = 0; kt < 4; kt++)
      bw[nt][kt] = *(const half8t*)(Wh + (cb + nt * 16 + lr) * 136 + kt * 32 + lk * 8);
  float bv[NT];
#pragma unroll
  for (int nt = 0; nt < NT; nt++) bv[nt] = bias[cb + nt * 16 + lr];
#pragma unroll
  for (int m = 0; m < 4; m++) {
    half8t afr[4];
#pragma unroll
    for (int kt = 0; kt < 4; kt++)
      afr[kt] = *(const half8t*)(xh + (m * 16 + lr) * 136 + kt * 32 + lk * 8);
#pragma unroll
    for (int nt = 0; nt < NT; nt++) {
      f32x4 cv = {bv[nt], bv[nt], bv[nt], bv[nt]};
      acc[m][nt] = cv;
    }
#pragma unroll
    for (int kt = 0; kt < 4; kt++)
#pragma unroll
      for (int nt = 0; nt < NT; nt++)
        acc[m][nt] = __builtin_amdgcn_mfma_f32_16x16x32_f16(afr[kt], bw[nt][kt], acc[m][nt], 0, 0, 0);
  }
}

// add the 3 relative-xyz channels (c=128..130) for layer0 on the VALU
__device__ __forceinline__ void l0_relxyz(const _Float16* xh, const _Float16* __restrict__ W0h,
                                          int cb, int lr, int lk, f32x4 acc[4][2]) {
  float wx[2][3];
#pragma unroll
  for (int nt = 0; nt < 2; nt++) {
    const _Float16* wp = W0h + (cb + nt * 16 + lr) * 136 + 128;
    wx[nt][0] = (float)wp[0]; wx[nt][1] = (float)wp[1]; wx[nt][2] = (float)wp[2];
  }
#pragma unroll
  for (int m = 0; m < 4; m++) {
#pragma unroll
    for (int r = 0; r < 4; r++) {
      int row = m * 16 + lk * 4 + r;
      float x0 = (float)xh[row * 136 + 128];
      float x1 = (float)xh[row * 136 + 129];
      float x2 = (float)xh[row * 136 + 130];
#pragma unroll
      for (int nt = 0; nt < 2; nt++)
        acc[m][nt][r] += x0 * wx[nt][0] + x1 * wx[nt][1] + x2 * wx[nt][2];
    }
  }
}

// wave-private stats over all 64 rows of the wave's NT*16 cols; no LDS, no barrier.
template <int NT>
__device__ __forceinline__ void stats_cols(const f32x4 acc[4][NT], int lane, int cb, int lr,
                                           float* __restrict__ psum, float* __restrict__ psq,
                                           int bs, int nch) {
  float s[NT], q[NT];
#pragma unroll
  for (int nt = 0; nt < NT; nt++) { s[nt] = 0.f; q[nt] = 0.f; }
#pragma unroll
  for (int m = 0; m < 4; m++)
#pragma unroll
    for (int nt = 0; nt < NT; nt++) {
      f32x4 a = acc[m][nt];
      s[nt] += (a[0] + a[1]) + (a[2] + a[3]);
      q[nt] += fmaf(a[0], a[0], fmaf(a[1], a[1], fmaf(a[2], a[2], a[3] * a[3])));
    }
#pragma unroll
  for (int nt = 0; nt < NT; nt++) {
    s[nt] += __shfl_xor(s[nt], 16);
    s[nt] += __shfl_xor(s[nt], 32);
    q[nt] += __shfl_xor(q[nt], 16);
    q[nt] += __shfl_xor(q[nt], 32);
  }
  if (lane < 16) {
#pragma unroll
    for (int nt = 0; nt < NT; nt++) {
      int col = cb + nt * 16 + lr;
      psum[(size_t)bs * nch + col] = s[nt];
      psq[(size_t)bs * nch + col] = q[nt];
    }
  }
}

// raw acc -> y[bs] (fp16 scalar stores; each wave writes its own cols, all rows)
template <int NT>
__device__ __forceinline__ void write_y_cols(_Float16* __restrict__ yb, int cb, int lr, int lk,
                                             const f32x4 acc[4][NT]) {
#pragma unroll
  for (int nt = 0; nt < NT; nt++) {
    int col = cb + nt * 16 + lr;
#pragma unroll
    for (int m = 0; m < 4; m++)
#pragma unroll
      for (int r = 0; r < 4; r++)
        yb[(m * 16 + lk * 4 + r) * 128 + col] = (_Float16)acc[m][nt][r];
  }
}

// ---------- single-layer passes (y materialized in-place; no recompute) ----------

// pass1: gather -> L0 -> stats0 + write raw y0
__global__ __launch_bounds__(256) void k_pass1(const float* __restrict__ xyz,
                                               const _Float16* __restrict__ ptsT,
                                               const int* __restrict__ fps, const int* __restrict__ idxb,
                                               const _Float16* __restrict__ W0h, const float* __restrict__ b0,
                                               _Float16* __restrict__ y,
                                               float* __restrict__ psum, float* __restrict__ psq) {
  __shared__ _Float16 xh[64 * 136];
  __shared__ int smidx[64];
  __shared__ float smc[3];
  int t = threadIdx.x;
  int bs = blockIdx.x;
  int b = bs >> 10;
  load_ball(xyz, ptsT, fps, idxb, bs, b, t, xh, smidx, smc);
  int lane = t & 63, wv = t >> 6;
  int lr = lane & 15, lk = lane >> 4;
  int cb = __builtin_amdgcn_readfirstlane(wv * 32);
  f32x4 acc[4][2];
  layer_cols<2>(xh, W0h, b0, cb, lr, lk, acc);
  l0_relxyz(xh, W0h, cb, lr, lk, acc);
  stats_cols<2>(acc, lane, cb, lr, psum, psq, bs, 128);
  write_y_cols<2>(y + (size_t)bs * 8192, cb, lr, lk, acc);
}

// pass2: read y0 + aff0+relu -> L1 -> stats1 + write raw y1 (in-place over y0)
__global__ __launch_bounds__(256) void k_pass2(const float* __restrict__ sc0, const float* __restrict__ sh0,
                                               const _Float16* __restrict__ W1h, const float* __restrict__ b1,
                                               _Float16* __restrict__ y,
                                               float* __restrict__ psum, float* __restrict__ psq) {
  __shared__ _Float16 xh[64 * 136];
  int t = threadIdx.x;
  int bs = blockIdx.x;
  _Float16* yb = y + (size_t)bs * 8192;
  read_y_aff(yb, sc0, sh0, t, xh);
  int lane = t & 63, wv = t >> 6;
  int lr = lane & 15, lk = lane >> 4;
  int cb = __builtin_amdgcn_readfirstlane(wv * 32);
  f32x4 acc[4][2];
  layer_cols<2>(xh, W1h, b1, cb, lr, lk, acc);
  stats_cols<2>(acc, lane, cb, lr, psum, psq, bs, 128);
  write_y_cols<2>(yb, cb, lr, lk, acc);
}

// pass3: read y1 + aff1+relu -> L2 -> max/min + stats2
__global__ __launch_bounds__(256) void k_pass3(const float* __restrict__ sc1, const float* __restrict__ sh1,
                                               const _Float16* __restrict__ W2h, const float* __restrict__ b2,
                                               const _Float16* __restrict__ y,
                                               float* __restrict__ maxb, float* __restrict__ minb,
                                               float* __restrict__ psum, float* __restrict__ psq) {
  __shared__ _Float16 xh[64 * 136];
  int t = threadIdx.x;
  int bs = blockIdx.x;
  read_y_aff(y + (size_t)bs * 8192, sc1, sh1, t, xh);
  int lane = t & 63, wv = t >> 6;
  int lr = lane & 15, lk = lane >> 4;
  // layer2: wave owns 64 cols; stream m-tiles, keep only stats (reg W cache)
  int cq = __builtin_amdgcn_readfirstlane(wv * 64);
  half8t bw[4][4];
#pragma unroll
  for (int nt = 0; nt < 4; nt++)
#pragma unroll
    for (int kt = 0; kt < 4; kt++)
      bw[nt][kt] = *(const half8t*)(W2h + (cq + nt * 16 + lr) * 136 + kt * 32 + lk * 8);
  float bv[4];
#pragma unroll
  for (int nt = 0; nt < 4; nt++) bv[nt] = b2[cq + nt * 16 + lr];
  float s[4] = {0.f, 0.f, 0.f, 0.f}, q[4] = {0.f, 0.f, 0.f, 0.f};
  float mx[4], mn[4];
#pragma unroll
  for (int nt = 0; nt < 4; nt++) { mx[nt] = -3.4e38f; mn[nt] = 3.4e38f; }
#pragma unroll
  for (int m = 0; m < 4; m++) {
    half8t afr[4];
#pragma unroll
    for (int kt = 0; kt < 4; kt++)
      afr[kt] = *(const half8t*)(xh + (m * 16 + lr) * 136 + kt * 32 + lk * 8);
    f32x4 a2[4];
#pragma unroll
    for (int nt = 0; nt < 4; nt++) {
      f32x4 cv = {bv[nt], bv[nt], bv[nt], bv[nt]};
      a2[nt] = cv;
    }
#pragma unroll
    for (int kt = 0; kt < 4; kt++)
#pragma unroll
      for (int nt = 0; nt < 4; nt++)
        a2[nt] = __builtin_amdgcn_mfma_f32_16x16x32_f16(afr[kt], bw[nt][kt], a2[nt], 0, 0, 0);
#pragma unroll
    for (int nt = 0; nt < 4; nt++) {
      f32x4 a = a2[nt];
      s[nt] += (a[0] + a[1]) + (a[2] + a[3]);
      q[nt] += fmaf(a[0], a[0], fmaf(a[1], a[1], fmaf(a[2], a[2], a[3] * a[3])));
      mx[nt] = fmaxf(mx[nt], fmaxf(fmaxf(a[0], a[1]), fmaxf(a[2], a[3])));
      mn[nt] = fminf(mn[nt], fminf(fminf(a[0], a[1]), fminf(a[2], a[3])));
    }
  }
#pragma unroll
  for (int nt = 0; nt < 4; nt++) {
    s[nt] += __shfl_xor(s[nt], 16);
    s[nt] += __shfl_xor(s[nt], 32);
    q[nt] += __shfl_xor(q[nt], 16);
    q[nt] += __shfl_xor(q[nt], 32);
    mx[nt] = fmaxf(mx[nt], __shfl_xor(mx[nt], 16));
    mx[nt] = fmaxf(mx[nt], __shfl_xor(mx[nt], 32));
    mn[nt] = fminf(mn[nt], __shfl_xor(mn[nt], 16));
    mn[nt] = fminf(mn[nt], __shfl_xor(mn[nt], 32));
  }
  if (lane < 16) {
#pragma unroll
    for (int nt = 0; nt < 4; nt++) {
      int col = cq + nt * 16 + lr;
      maxb[(size_t)bs * 256 + col] = mx[nt];
      minb[(size_t)bs * 256 + col] = mn[nt];
      psum[(size_t)bs * 256 + col] = s[nt];
      psq[(size_t)bs * 256 + col] = q[nt];
    }
  }
}

// fold BN stats into per-channel affine: a = g*rsqrt(var+eps); c = be - mean*a
// one block per channel; threads stride the 8192 per-block partials (no atomics anywhere)
__global__ __launch_bounds__(256) void k_fin(const float* __restrict__ psum, const float* __restrict__ psq,
                                             const float* __restrict__ g, const float* __restrict__ be,
                                             float* __restrict__ sc, float* __restrict__ sh, int nch) {
  int o = blockIdx.x, t = threadIdx.x;
  float s = 0.f, q = 0.f;
  for (int k = t; k < 8192; k += 256) {
    s += psum[(size_t)k * nch + o];
    q += psq[(size_t)k * nch + o];
  }
#pragma unroll
  for (int off = 32; off > 0; off >>= 1) {
    s += __shfl_down(s, off);
    q += __shfl_down(q, off);
  }
  __shared__ float rs[4], rq[4];
  if ((t & 63) == 0) { rs[t >> 6] = s; rq[t >> 6] = q; }
  __syncthreads();
  if (t == 0) {
    s = (rs[0] + rs[1]) + (rs[2] + rs[3]);
    q = (rq[0] + rq[1]) + (rq[2] + rq[3]);
    const float inv = 1.0f / 524288.0f;
    float m = s * inv;
    float ey2 = q * inv;
    float v = fmaf(-m, m, ey2);
    v = fmaxf(v, 0.f);
    float r = rsqrtf(v + EPSV);
    float a = g[o] * r;
    sc[o] = a;
    sh[o] = fmaf(-m, a, be[o]);
  }
}

// out[b, o, s] = relu(a*sel + c), sel = max if a>=0 else min
__global__ __launch_bounds__(256) void k_out(const float* __restrict__ maxb, const float* __restrict__ minb,
                                             const float* __restrict__ sc, const float* __restrict__ sh,
                                             float* __restrict__ out) {
  int flat = blockIdx.x * 256 + threadIdx.x;  // 2,097,152
  int b = flat >> 18;
  int o = (flat >> 10) & 255;
  int s = flat & 1023;
  float a = sc[o], c_ = sh[o];
  size_t mi = ((size_t)(b * 1024 + s)) * 256 + o;
  float v = (a >= 0.f) ? maxb[mi] : minb[mi];
  out[OUT_FEAT + flat] = fmaxf(fmaf(a, v, c_), 0.f);
}

extern "C" void kernel_launch(void* const* d_in, const int* in_sizes, int n_in,
                              void* d_out, int out_size, void* d_ws, size_t ws_size,
                              hipStream_t stream) {
  const float* xyz = (const float*)d_in[0];
  const float* pts = (const float*)d_in[1];
  const int* fps = (const int*)d_in[2];
  const float* W0 = (const float*)d_in[3];
  const float* b0 = (const float*)d_in[4];
  const float* g0 = (const float*)d_in[5];
  const float* be0 = (const float*)d_in[6];
  const float* W1 = (const float*)d_in[7];
  const float* b1 = (const float*)d_in[8];
  const float* g1 = (const float*)d_in[9];
  const float* be1 = (const float*)d_in[10];
  const float* W2 = (const float*)d_in[11];
  const float* b2 = (const float*)d_in[12];
  const float* g2 = (const float*)d_in[13];
  const float* be2 = (const float*)d_in[14];
  float* out = (float*)d_out;
  char* ws = (char*)d_ws;

  if (ws_size < WS_NEEDED) {
    k_newxyz<<<32, 256, 0, stream>>>(xyz, fps, out);
    return;
  }

  _Float16* ptsT = (_Float16*)(ws + O_PT);
  int* idxb = (int*)(ws + O_IDX);
  float* maxbf = (float*)(ws + O_MAXB);
  float* minbf = (float*)(ws + O_MINB);
  _Float16* W0h = (_Float16*)(ws + O_W0T);
  _Float16* W1h = (_Float16*)(ws + O_W1T);
  _Float16* W2h = (_Float16*)(ws + O_W2T);
  float* ps0 = (float*)(ws + O_PS0);
  float* pq0 = (float*)(ws + O_PQ0);
  float* ps1 = (float*)(ws + O_PS1);
  float* pq1 = (float*)(ws + O_PQ1);
  float* ps2 = (float*)(ws + O_PS2);
  float* pq2 = (float*)(ws + O_PQ2);
  float* sc0 = (float*)(ws + O_SC0);
  float* sh0 = (float*)(ws + O_SH0);
  float* sc1 = (float*)(ws + O_SC1);
  float* sh1 = (float*)(ws + O_SH1);
  float* sc2 = (float*)(ws + O_SC2);
  float* sh2 = (float*)(ws + O_SH2);
  _Float16* y = (_Float16*)(ws + O_Y);

  k_transpose_pts<<<dim3(NN / 64, DD / 64, BB), 256, 0, stream>>>(pts, ptsT);
  k_wt<<<272, 256, 0, stream>>>(W0, W1, W2, W0h, W1h, W2h);
  k_ballq<<<2048, 256, 0, stream>>>(xyz, fps, idxb, out);
  k_pass1<<<8192, 256, 0, stream>>>(xyz, ptsT, fps, idxb, W0h, b0, y, ps0, pq0);
  k_fin<<<128, 256, 0, stream>>>(ps0, pq0, g0, be0, sc0, sh0, 128);
  k_pass2<<<8192, 256, 0, stream>>>(sc0, sh0, W1h, b1, y, ps1, pq1);
  k_fin<<<128, 256, 0, stream>>>(ps1, pq1, g1, be1, sc1, sh1, 128);
  k_pass3<<<8192, 256, 0, stream>>>(sc1, sh1, W2h, b2, y, maxbf, minbf, ps2, pq2);
  k_fin<<<256, 256, 0, stream>>>(ps2, pq2, g2, be2, sc2, sh2, 256);
  k_out<<<8192, 256, 0, stream>>>(maxbf, minbf, sc2, sh2, out);
}

// Round 11
// 401.026 us; speedup vs baseline: 2.3679x; 1.0738x over previous
//
#include <hip/hip_runtime.h>

#define BB 8
#define NN 16384
#define SS 1024
#define NSMP 64
#define DD 128
#define R2 0.04f
#define EPSV 1e-5f

typedef _Float16 half8t __attribute__((ext_vector_type(8)));
typedef float f32x4 __attribute__((ext_vector_type(4)));

// ---- workspace layout (bytes); MUST stay under 256 MiB (harness ws size) ----
#define O_PT    0ull                 // pointsT fp16: 8*16384*128*2 = 33,554,432
#define O_IDX   33554432ull          // idx int32: 8192*64*4 = 2,097,152
#define O_MAXB  35651584ull          // 8192*256*4 = 8,388,608
#define O_MINB  44040192ull          // 8,388,608
#define O_W0T   52428800ull          // W0h fp16 [128][136] = 34,816
#define O_W1T   52463616ull          // W1h fp16 [128][136] = 34,816
#define O_W2T   52498432ull          // W2h fp16 [256][136] = 69,632
#define O_PS0   52568064ull          // per-block partials [8192][128] f32 = 4,194,304
#define O_PQ0   56762368ull          // 4,194,304
#define O_PS1   60956672ull          // 4,194,304
#define O_PQ1   65150976ull          // 4,194,304
#define O_PS2   69345280ull          // [8192][256] f32 = 8,388,608
#define O_PQ2   77733888ull          // 8,388,608
#define O_SC0   86122496ull
#define O_SH0   86123008ull
#define O_SC1   86123520ull
#define O_SH1   86124032ull
#define O_SC2   86124544ull
#define O_SH2   86125568ull
#define O_Y     86126592ull          // y fp16 [8192][64][128] = 134,217,728 (in-place L0->L1)
#define WS_NEEDED 220344320ull

#define OUT_XYZ 0
#define OUT_FEAT 24576
#define OUT_FPS (24576 + 2097152)

// fallback when workspace undersized
__global__ __launch_bounds__(256) void k_newxyz(const float* __restrict__ xyz, const int* __restrict__ fps,
                                                float* __restrict__ out) {
  int id = blockIdx.x * 256 + threadIdx.x;  // B*S
  int fi = fps[id];
  int b = id >> 10;
  const float* p = xyz + ((size_t)b * NN + fi) * 3;
  float* o = out + OUT_XYZ + (size_t)id * 3;
  o[0] = p[0]; o[1] = p[1]; o[2] = p[2];
  out[OUT_FPS + id] = (float)fi;
}

// ---- merged front kernel: transpose (blocks 0..4095) | ballq (4096..6143) | wt (6144..6415) ----
// The three are mutually independent (transpose: pts->ptsT; ballq: xyz->idxb/out; wt: W->Wh).
// Merging overlaps BW-bound transpose with latency-bound ballq and saves 2 launches.
__global__ __launch_bounds__(256) void k_front(const float* __restrict__ pts, _Float16* __restrict__ ptsT,
                                               const float* __restrict__ W0, const float* __restrict__ W1,
                                               const float* __restrict__ W2, _Float16* __restrict__ W0h,
                                               _Float16* __restrict__ W1h, _Float16* __restrict__ W2h,
                                               const float* __restrict__ xyz, const int* __restrict__ fps,
                                               int* __restrict__ idxb, float* __restrict__ out) {
  __shared__ float tile[64][65];
  int id = blockIdx.x;
  int t = threadIdx.x;
  if (id < 4096) {
    // transpose: points [B,D,N] fp32 -> pointsT [B,N,D] fp16, 64n x 64c tile
    int b = id >> 9;
    int c0 = ((id >> 8) & 1) * 64;
    int n0 = (id & 255) * 64;
    int cg = t >> 6, ln = t & 63;
#pragma unroll
    for (int k = 0; k < 16; k++) {
      int c = cg * 16 + k;
      tile[c][ln] = pts[((size_t)b * DD + c0 + c) * NN + n0 + ln];
    }
    __syncthreads();
    int n = t >> 2, sub = t & 3;
#pragma unroll
    for (int j = 0; j < 2; j++) {
      int cb = sub * 16 + j * 8;
      half8t h;
#pragma unroll
      for (int k = 0; k < 8; k++) h[k] = (_Float16)tile[cb + k][n];
      *(half8t*)(ptsT + ((size_t)b * NN + n0 + n) * DD + c0 + cb) = h;
    }
  } else if (id < 6144) {
    // ballq: one wave per (b,s); 4 points/lane/iter; first-NS ascending, pad first valid.
    int w = ((id - 4096) * 256 + t) >> 6;
    int lane = t & 63;
    int b = w >> 10;
    int fi = fps[w];
    const float* cp = xyz + ((size_t)b * NN + fi) * 3;
    float cx = cp[0], cy = cp[1], cz = cp[2];
    if (lane < 3) out[OUT_XYZ + (size_t)w * 3 + lane] = (lane == 0) ? cx : ((lane == 1) ? cy : cz);
    if (lane == 3) out[OUT_FPS + w] = (float)fi;
    float A = __fadd_rn(__fadd_rn(__fmul_rn(cx, cx), __fmul_rn(cy, cy)), __fmul_rn(cz, cz));
    const float* xb = xyz + (size_t)b * NN * 3;
    int cnt = 0, firstn = -1;
    int* myidx = idxb + (size_t)w * NSMP;
    unsigned long long below = (lane == 0) ? 0ull : (~0ull >> (64 - lane));
    for (int nb = 0; nb < NN && cnt < NSMP; nb += 256) {
      int n0 = nb + lane * 4;
      const f32x4* p4 = (const f32x4*)(xb + (size_t)n0 * 3);
      f32x4 f0 = p4[0], f1 = p4[1], f2 = p4[2];
      float px[4] = {f0[0], f0[3], f1[2], f2[1]};
      float py[4] = {f0[1], f1[0], f1[3], f2[2]};
      float pz[4] = {f0[2], f1[1], f2[0], f2[3]};
      unsigned m = 0;
#pragma unroll
      for (int j = 0; j < 4; j++) {
        float Bv = __fadd_rn(__fadd_rn(__fmul_rn(px[j], px[j]), __fmul_rn(py[j], py[j])),
                             __fmul_rn(pz[j], pz[j]));
        float dot = __fadd_rn(__fadd_rn(__fmul_rn(cx, px[j]), __fmul_rn(cy, py[j])),
                              __fmul_rn(cz, pz[j]));
        float d = __fsub_rn(__fadd_rn(A, Bv), __fmul_rn(2.0f, dot));
        if (!(d > R2)) m |= 1u << j;
      }
      unsigned long long bl0 = __ballot((m & 1u) != 0u);
      unsigned long long bl1 = __ballot((m & 2u) != 0u);
      unsigned long long bl2 = __ballot((m & 4u) != 0u);
      unsigned long long bl3 = __ballot((m & 8u) != 0u);
      unsigned long long anyb = bl0 | bl1 | bl2 | bl3;
      if (firstn < 0 && anyb) {
        int l0 = __builtin_ctzll(anyb);
        int j0 = ((bl0 >> l0) & 1ull) ? 0 : ((bl1 >> l0) & 1ull) ? 1 : ((bl2 >> l0) & 1ull) ? 2 : 3;
        firstn = nb + l0 * 4 + j0;
      }
      int excl = __popcll(bl0 & below) + __popcll(bl1 & below) +
                 __popcll(bl2 & below) + __popcll(bl3 & below);
      int pos = cnt + excl;
#pragma unroll
      for (int j = 0; j < 4; j++) {
        if (m & (1u << j)) {
          if (pos < NSMP) myidx[pos] = n0 + j;
          pos++;
        }
      }
      cnt += __popcll(bl0) + __popcll(bl1) + __popcll(bl2) + __popcll(bl3);
      if (cnt > NSMP) cnt = NSMP;
    }
    if (lane >= cnt) myidx[lane] = firstn;
  } else {
    // wt: weights -> fp16, [out][in] stride 136, zero-padded; W0 remapped (feats 0..127, relxyz 128..130)
    int idw = (id - 6144) * 256 + t;
    const int T0 = 128 * 136, T1 = 128 * 136, T2 = 256 * 136;
    if (idw < T0) {
      int o = idw / 136, c = idw % 136;
      float v = 0.f;
      if (c < 131) {
        int c0 = (c < 128) ? (c + 3) : (c - 128);
        v = W0[o * 131 + c0];
      }
      W0h[idw] = (_Float16)v;
    } else if (idw < T0 + T1) {
      int j = idw - T0;
      int o = j / 136, c = j % 136;
      W1h[j] = (_Float16)((c < 128) ? W1[o * 128 + c] : 0.f);
    } else if (idw < T0 + T1 + T2) {
      int j = idw - T0 - T1;
      int o = j / 136, c = j % 136;
      W2h[j] = (_Float16)((c < 128) ? W2[o * 128 + c] : 0.f);
    }
  }
}

// ---------- shared device pieces ----------

// wave-owned column group weight registers (NT groups of 16 cols, base cb)
template <int NT>
__device__ __forceinline__ void load_wregs(const _Float16* __restrict__ Wh,
                                           const float* __restrict__ bias, int cb, int lr, int lk,
                                           half8t bw[NT][4], float bv[NT]) {
#pragma unroll
  for (int nt = 0; nt < NT; nt++) {
#pragma unroll
    for (int kt = 0; kt < 4; kt++)
      bw[nt][kt] = *(const half8t*)(Wh + (cb + nt * 16 + lr) * 136 + kt * 32 + lk * 8);
    bv[nt] = bias[cb + nt * 16 + lr];
  }
}

// K=128 layer for all 64 rows of the wave's cols (W regs preloaded)
template <int NT>
__device__ __forceinline__ void mfma_cols(const _Float16* xh, const half8t bw[NT][4],
                                          const float bv[NT], int lr, int lk, f32x4 acc[4][NT]) {
#pragma unroll
  for (int m = 0; m < 4; m++) {
    half8t afr[4];
#pragma unroll
    for (int kt = 0; kt < 4; kt++)
      afr[kt] = *(const half8t*)(xh + (m * 16 + lr) * 136 + kt * 32 + lk * 8);
#pragma unroll
    for (int nt = 0; nt < NT; nt++) {
      f32x4 cv = {bv[nt], bv[nt], bv[nt], bv[nt]};
      acc[m][nt] = cv;
    }
#pragma unroll
    for (int kt = 0; kt < 4; kt++)
#pragma unroll
      for (int nt = 0; nt < NT; nt++)
        acc[m][nt] = __builtin_amdgcn_mfma_f32_16x16x32_f16(afr[kt], bw[nt][kt], acc[m][nt], 0, 0, 0);
  }
}

// gather one ball tile into xh (feats 0..127 + relxyz 128..130)
__device__ __forceinline__ void gather_tile(const float* __restrict__ xyz,
                                            const _Float16* __restrict__ ptsT,
                                            int b, int t, const int* smidx, const float* smc,
                                            _Float16* xh) {
  int row = t >> 2, qd = t & 3;
  int n = smidx[row];
  const half8t* src = (const half8t*)(ptsT + ((size_t)b * NN + n) * DD);
#pragma unroll
  for (int i = 0; i < 4; i++) {
    int j = qd + i * 4;
    *(half8t*)(xh + row * 136 + j * 8) = src[j];
  }
  if (t < 64) {
    int n2 = smidx[t];
    const float* p = xyz + ((size_t)b * NN + n2) * 3;
    xh[t * 136 + 128] = (_Float16)(p[0] - smc[0]);
    xh[t * 136 + 129] = (_Float16)(p[1] - smc[1]);
    xh[t * 136 + 130] = (_Float16)(p[2] - smc[2]);
  }
}

__device__ __forceinline__ void load_wx(const _Float16* __restrict__ W0h, int cb, int lr,
                                        float wx[2][3]) {
#pragma unroll
  for (int nt = 0; nt < 2; nt++) {
    const _Float16* wp = W0h + (cb + nt * 16 + lr) * 136 + 128;
    wx[nt][0] = (float)wp[0]; wx[nt][1] = (float)wp[1]; wx[nt][2] = (float)wp[2];
  }
}

// add the 3 relative-xyz channels (c=128..130) for layer0 on the VALU
__device__ __forceinline__ void add_relxyz(const _Float16* xh, const float wx[2][3],
                                           int lr, int lk, f32x4 acc[4][2]) {
#pragma unroll
  for (int m = 0; m < 4; m++) {
#pragma unroll
    for (int r = 0; r < 4; r++) {
      int row = m * 16 + lk * 4 + r;
      float x0 = (float)xh[row * 136 + 128];
      float x1 = (float)xh[row * 136 + 129];
      float x2 = (float)xh[row * 136 + 130];
#pragma unroll
      for (int nt = 0; nt < 2; nt++)
        acc[m][nt][r] += x0 * wx[nt][0] + x1 * wx[nt][1] + x2 * wx[nt][2];
    }
  }
}

// y staging: 8 coalesced half8 loads -> regs; later affine+relu -> xh
__device__ __forceinline__ void load_y_regs(const _Float16* __restrict__ yb, int t, half8t r[4]) {
#pragma unroll
  for (int i = 0; i < 4; i++) r[i] = *(const half8t*)(yb + (i * 256 + t) * 8);
}

__device__ __forceinline__ void aff_store(const half8t r[4], const float* __restrict__ sc,
                                          const float* __restrict__ sh, int t, _Float16* xh) {
#pragma unroll
  for (int i = 0; i < 4; i++) {
    int flat = (i * 256 + t) * 8;
    int row = flat >> 7, col = flat & 127;
    half8t o;
#pragma unroll
    for (int k = 0; k < 8; k++)
      o[k] = (_Float16)fmaxf(fmaf((float)r[i][k], sc[col + k], sh[col + k]), 0.f);
    *(half8t*)(xh + row * 136 + col) = o;
  }
}

// wave-private stats over all 64 rows of the wave's NT*16 cols; no LDS, no barrier.
template <int NT>
__device__ __forceinline__ void stats_cols(const f32x4 acc[4][NT], int lane, int cb, int lr,
                                           float* __restrict__ psum, float* __restrict__ psq,
                                           int bs, int nch) {
  float s[NT], q[NT];
#pragma unroll
  for (int nt = 0; nt < NT; nt++) { s[nt] = 0.f; q[nt] = 0.f; }
#pragma unroll
  for (int m = 0; m < 4; m++)
#pragma unroll
    for (int nt = 0; nt < NT; nt++) {
      f32x4 a = acc[m][nt];
      s[nt] += (a[0] + a[1]) + (a[2] + a[3]);
      q[nt] += fmaf(a[0], a[0], fmaf(a[1], a[1], fmaf(a[2], a[2], a[3] * a[3])));
    }
#pragma unroll
  for (int nt = 0; nt < NT; nt++) {
    s[nt] += __shfl_xor(s[nt], 16);
    s[nt] += __shfl_xor(s[nt], 32);
    q[nt] += __shfl_xor(q[nt], 16);
    q[nt] += __shfl_xor(q[nt], 32);
  }
  if (lane < 16) {
#pragma unroll
    for (int nt = 0; nt < NT; nt++) {
      int col = cb + nt * 16 + lr;
      psum[(size_t)bs * nch + col] = s[nt];
      psq[(size_t)bs * nch + col] = q[nt];
    }
  }
}

// raw acc -> y[bs] (fp16 scalar stores; each wave writes its own cols, all rows)
template <int NT>
__device__ __forceinline__ void write_y_cols(_Float16* __restrict__ yb, int cb, int lr, int lk,
                                             const f32x4 acc[4][NT]) {
#pragma unroll
  for (int nt = 0; nt < NT; nt++) {
    int col = cb + nt * 16 + lr;
#pragma unroll
    for (int m = 0; m < 4; m++)
#pragma unroll
      for (int r = 0; r < 4; r++)
        yb[(m * 16 + lk * 4 + r) * 128 + col] = (_Float16)acc[m][nt][r];
  }
}

// layer2 compute + stats/max/min for one tile (W regs preloaded)
__device__ __forceinline__ void l2_compute(const _Float16* xh, const half8t bw[4][4], const float bv[4],
                                           int lane, int lr, int lk, int cq, int bs,
                                           float* __restrict__ maxb, float* __restrict__ minb,
                                           float* __restrict__ psum, float* __restrict__ psq) {
  float s[4] = {0.f, 0.f, 0.f, 0.f}, q[4] = {0.f, 0.f, 0.f, 0.f};
  float mx[4], mn[4];
#pragma unroll
  for (int nt = 0; nt < 4; nt++) { mx[nt] = -3.4e38f; mn[nt] = 3.4e38f; }
#pragma unroll
  for (int m = 0; m < 4; m++) {
    half8t afr[4];
#pragma unroll
    for (int kt = 0; kt < 4; kt++)
      afr[kt] = *(const half8t*)(xh + (m * 16 + lr) * 136 + kt * 32 + lk * 8);
    f32x4 a2[4];
#pragma unroll
    for (int nt = 0; nt < 4; nt++) {
      f32x4 cv = {bv[nt], bv[nt], bv[nt], bv[nt]};
      a2[nt] = cv;
    }
#pragma unroll
    for (int kt = 0; kt < 4; kt++)
#pragma unroll
      for (int nt = 0; nt < 4; nt++)
        a2[nt] = __builtin_amdgcn_mfma_f32_16x16x32_f16(afr[kt], bw[nt][kt], a2[nt], 0, 0, 0);
#pragma unroll
    for (int nt = 0; nt < 4; nt++) {
      f32x4 a = a2[nt];
      s[nt] += (a[0] + a[1]) + (a[2] + a[3]);
      q[nt] += fmaf(a[0], a[0], fmaf(a[1], a[1], fmaf(a[2], a[2], a[3] * a[3])));
      mx[nt] = fmaxf(mx[nt], fmaxf(fmaxf(a[0], a[1]), fmaxf(a[2], a[3])));
      mn[nt] = fminf(mn[nt], fminf(fminf(a[0], a[1]), fminf(a[2], a[3])));
    }
  }
#pragma unroll
  for (int nt = 0; nt < 4; nt++) {
    s[nt] += __shfl_xor(s[nt], 16);
    s[nt] += __shfl_xor(s[nt], 32);
    q[nt] += __shfl_xor(q[nt], 16);
    q[nt] += __shfl_xor(q[nt], 32);
    mx[nt] = fmaxf(mx[nt], __shfl_xor(mx[nt], 16));
    mx[nt] = fmaxf(mx[nt], __shfl_xor(mx[nt], 32));
    mn[nt] = fminf(mn[nt], __shfl_xor(mn[nt], 16));
    mn[nt] = fminf(mn[nt], __shfl_xor(mn[nt], 32));
  }
  if (lane < 16) {
#pragma unroll
    for (int nt = 0; nt < 4; nt++) {
      int col = cq + nt * 16 + lr;
      maxb[(size_t)bs * 256 + col] = mx[nt];
      minb[(size_t)bs * 256 + col] = mn[nt];
      psum[(size_t)bs * 256 + col] = s[nt];
      psq[(size_t)bs * 256 + col] = q[nt];
    }
  }
}

// ---------- 2-tile pipelined passes ----------

// pass1: gather both tiles (2x memory-level parallelism) -> L0 each -> stats + raw y
__global__ __launch_bounds__(256) void k_pass1(const float* __restrict__ xyz,
                                               const _Float16* __restrict__ ptsT,
                                               const int* __restrict__ fps, const int* __restrict__ idxb,
                                               const _Float16* __restrict__ W0h, const float* __restrict__ b0,
                                               _Float16* __restrict__ y,
                                               float* __restrict__ psum, float* __restrict__ psq) {
  __shared__ _Float16 xh0[64 * 136], xh1[64 * 136];
  __shared__ int smidx0[64], smidx1[64];
  __shared__ float smc0[3], smc1[3];
  int t = threadIdx.x;
  int bs0 = blockIdx.x * 2, bs1 = bs0 + 1;
  int b = bs0 >> 10;  // bs0 even => bs0,bs1 always same batch
  if (t < 64) {
    smidx0[t] = idxb[(size_t)bs0 * 64 + t];
    smidx1[t] = idxb[(size_t)bs1 * 64 + t];
  }
  if (t < 3) {
    smc0[t] = xyz[((size_t)b * NN + fps[bs0]) * 3 + t];
    smc1[t] = xyz[((size_t)b * NN + fps[bs1]) * 3 + t];
  }
  __syncthreads();
  gather_tile(xyz, ptsT, b, t, smidx0, smc0, xh0);
  gather_tile(xyz, ptsT, b, t, smidx1, smc1, xh1);
  int lane = t & 63, wv = t >> 6;
  int lr = lane & 15, lk = lane >> 4;
  int cb = __builtin_amdgcn_readfirstlane(wv * 32);
  half8t bw[2][4];
  float bv[2], wx[2][3];
  load_wregs<2>(W0h, b0, cb, lr, lk, bw, bv);
  load_wx(W0h, cb, lr, wx);
  __syncthreads();
  f32x4 acc[4][2];
  mfma_cols<2>(xh0, bw, bv, lr, lk, acc);
  add_relxyz(xh0, wx, lr, lk, acc);
  stats_cols<2>(acc, lane, cb, lr, psum, psq, bs0, 128);
  write_y_cols<2>(y + (size_t)bs0 * 8192, cb, lr, lk, acc);
  mfma_cols<2>(xh1, bw, bv, lr, lk, acc);
  add_relxyz(xh1, wx, lr, lk, acc);
  stats_cols<2>(acc, lane, cb, lr, psum, psq, bs1, 128);
  write_y_cols<2>(y + (size_t)bs1 * 8192, cb, lr, lk, acc);
}

// pass2: tile1 y-load issues before tile0 compute (latency hidden); W regs loaded once
__global__ __launch_bounds__(256) void k_pass2(const float* __restrict__ sc0, const float* __restrict__ sh0,
                                               const _Float16* __restrict__ W1h, const float* __restrict__ b1,
                                               _Float16* __restrict__ y,
                                               float* __restrict__ psum, float* __restrict__ psq) {
  __shared__ _Float16 xh0[64 * 136], xh1[64 * 136];
  int t = threadIdx.x;
  int bs0 = blockIdx.x * 2, bs1 = bs0 + 1;
  _Float16* yb0 = y + (size_t)bs0 * 8192;
  _Float16* yb1 = y + (size_t)bs1 * 8192;
  int lane = t & 63, wv = t >> 6;
  int lr = lane & 15, lk = lane >> 4;
  int cb = __builtin_amdgcn_readfirstlane(wv * 32);
  half8t r0[4], r1[4];
  load_y_regs(yb0, t, r0);
  half8t bw[2][4];
  float bv[2];
  load_wregs<2>(W1h, b1, cb, lr, lk, bw, bv);
  aff_store(r0, sc0, sh0, t, xh0);
  __syncthreads();
  load_y_regs(yb1, t, r1);  // in flight during tile0 compute
  f32x4 acc[4][2];
  mfma_cols<2>(xh0, bw, bv, lr, lk, acc);
  stats_cols<2>(acc, lane, cb, lr, psum, psq, bs0, 128);
  write_y_cols<2>(yb0, cb, lr, lk, acc);
  aff_store(r1, sc0, sh0, t, xh1);
  __syncthreads();
  mfma_cols<2>(xh1, bw, bv, lr, lk, acc);
  stats_cols<2>(acc, lane, cb, lr, psum, psq, bs1, 128);
  write_y_cols<2>(yb1, cb, lr, lk, acc);
}

// pass3: same pipeline; L2 -> max/min + stats
__global__ __launch_bounds__(256) void k_pass3(const float* __restrict__ sc1, const float* __restrict__ sh1,
                                               const _Float16* __restrict__ W2h, const float* __restrict__ b2,
                                               const _Float16* __restrict__ y,
                                               float* __restrict__ maxb, float* __restrict__ minb,
                                               float* __restrict__ psum, float* __restrict__ psq) {
  __shared__ _Float16 xh0[64 * 136], xh1[64 * 136];
  int t = threadIdx.x;
  int bs0 = blockIdx.x * 2, bs1 = bs0 + 1;
  int lane = t & 63, wv = t >> 6;
  int lr = lane & 15, lk = lane >> 4;
  int cq = __builtin_amdgcn_readfirstlane(wv * 64);
  half8t r0[4], r1[4];
  load_y_regs(y + (size_t)bs0 * 8192, t, r0);
  half8t bw[4][4];
  float bv[4];
  load_wregs<4>(W2h, b2, cq, lr, lk, bw, bv);
  aff_store(r0, sc1, sh1, t, xh0);
  __syncthreads();
  load_y_regs(y + (size_t)bs1 * 8192, t, r1);  // in flight during tile0 compute
  l2_compute(xh0, bw, bv, lane, lr, lk, cq, bs0, maxb, minb, psum, psq);
  aff_store(r1, sc1, sh1, t, xh1);
  __syncthreads();
  l2_compute(xh1, bw, bv, lane, lr, lk, cq, bs1, maxb, minb, psum, psq);
}

// fold BN stats into per-channel affine: a = g*rsqrt(var+eps); c = be - mean*a
__global__ __launch_bounds__(256) void k_fin(const float* __restrict__ psum, const float* __restrict__ psq,
                                             const float* __restrict__ g, const float* __restrict__ be,
                                             float* __restrict__ sc, float* __restrict__ sh, int nch) {
  int o = blockIdx.x, t = threadIdx.x;
  float s = 0.f, q = 0.f;
  for (int k = t; k < 8192; k += 256) {
    s += psum[(size_t)k * nch + o];
    q += psq[(size_t)k * nch + o];
  }
#pragma unroll
  for (int off = 32; off > 0; off >>= 1) {
    s += __shfl_down(s, off);
    q += __shfl_down(q, off);
  }
  __shared__ float rs[4], rq[4];
  if ((t & 63) == 0) { rs[t >> 6] = s; rq[t >> 6] = q; }
  __syncthreads();
  if (t == 0) {
    s = (rs[0] + rs[1]) + (rs[2] + rs[3]);
    q = (rq[0] + rq[1]) + (rq[2] + rq[3]);
    const float inv = 1.0f / 524288.0f;
    float m = s * inv;
    float ey2 = q * inv;
    float v = fmaf(-m, m, ey2);
    v = fmaxf(v, 0.f);
    float r = rsqrtf(v + EPSV);
    float a = g[o] * r;
    sc[o] = a;
    sh[o] = fmaf(-m, a, be[o]);
  }
}

// out[b, o, s] = relu(a*sel + c), sel = max if a>=0 else min
__global__ __launch_bounds__(256) void k_out(const float* __restrict__ maxb, const float* __restrict__ minb,
                                             const float* __restrict__ sc, const float* __restrict__ sh,
                                             float* __restrict__ out) {
  int flat = blockIdx.x * 256 + threadIdx.x;  // 2,097,152
  int b = flat >> 18;
  int o = (flat >> 10) & 255;
  int s = flat & 1023;
  float a = sc[o], c_ = sh[o];
  size_t mi = ((size_t)(b * 1024 + s)) * 256 + o;
  float v = (a >= 0.f) ? maxb[mi] : minb[mi];
  out[OUT_FEAT + flat] = fmaxf(fmaf(a, v, c_), 0.f);
}

extern "C" void kernel_launch(void* const* d_in, const int* in_sizes, int n_in,
                              void* d_out, int out_size, void* d_ws, size_t ws_size,
                              hipStream_t stream) {
  const float* xyz = (const float*)d_in[0];
  const float* pts = (const float*)d_in[1];
  const int* fps = (const int*)d_in[2];
  const float* W0 = (const float*)d_in[3];
  const float* b0 = (const float*)d_in[4];
  const float* g0 = (const float*)d_in[5];
  const float* be0 = (const float*)d_in[6];
  const float* W1 = (const float*)d_in[7];
  const float* b1 = (const float*)d_in[8];
  const float* g1 = (const float*)d_in[9];
  const float* be1 = (const float*)d_in[10];
  const float* W2 = (const float*)d_in[11];
  const float* b2 = (const float*)d_in[12];
  const float* g2 = (const float*)d_in[13];
  const float* be2 = (const float*)d_in[14];
  float* out = (float*)d_out;
  char* ws = (char*)d_ws;

  if (ws_size < WS_NEEDED) {
    k_newxyz<<<32, 256, 0, stream>>>(xyz, fps, out);
    return;
  }

  _Float16* ptsT = (_Float16*)(ws + O_PT);
  int* idxb = (int*)(ws + O_IDX);
  float* maxbf = (float*)(ws + O_MAXB);
  float* minbf = (float*)(ws + O_MINB);
  _Float16* W0h = (_Float16*)(ws + O_W0T);
  _Float16* W1h = (_Float16*)(ws + O_W1T);
  _Float16* W2h = (_Float16*)(ws + O_W2T);
  float* ps0 = (float*)(ws + O_PS0);
  float* pq0 = (float*)(ws + O_PQ0);
  float* ps1 = (float*)(ws + O_PS1);
  float* pq1 = (float*)(ws + O_PQ1);
  float* ps2 = (float*)(ws + O_PS2);
  float* pq2 = (float*)(ws + O_PQ2);
  float* sc0 = (float*)(ws + O_SC0);
  float* sh0 = (float*)(ws + O_SH0);
  float* sc1 = (float*)(ws + O_SC1);
  float* sh1 = (float*)(ws + O_SH1);
  float* sc2 = (float*)(ws + O_SC2);
  float* sh2 = (float*)(ws + O_SH2);
  _Float16* y = (_Float16*)(ws + O_Y);

  k_front<<<6416, 256, 0, stream>>>(pts, ptsT, W0, W1, W2, W0h, W1h, W2h, xyz, fps, idxb, out);
  k_pass1<<<4096, 256, 0, stream>>>(xyz, ptsT, fps, idxb, W0h, b0, y, ps0, pq0);
  k_fin<<<128, 256, 0, stream>>>(ps0, pq0, g0, be0, sc0, sh0, 128);
  k_pass2<<<4096, 256, 0, stream>>>(sc0, sh0, W1h, b1, y, ps1, pq1);
  k_fin<<<128, 256, 0, stream>>>(ps1, pq1, g1, be1, sc1, sh1, 128);
  k_pass3<<<4096, 256, 0, stream>>>(sc1, sh1, W2h, b2, y, maxbf, minbf, ps2, pq2);
  k_fin<<<256, 256, 0, stream>>>(ps2, pq2, g2, be2, sc2, sh2, 256);
  k_out<<<8192, 256, 0, stream>>>(maxbf, minbf, sc2, sh2, out);
}

// Round 13
// 396.501 us; speedup vs baseline: 2.3950x; 1.0114x over previous
//
#include <hip/hip_runtime.h>

#define BB 8
#define NN 16384
#define SS 1024
#define NSMP 64
#define DD 128
#define R2 0.04f
#define EPSV 1e-5f

typedef _Float16 half8t __attribute__((ext_vector_type(8)));
typedef float f32x4 __attribute__((ext_vector_type(4)));

// ---- workspace layout (bytes); MUST stay under 256 MiB (harness ws size) ----
#define O_PT    0ull                 // pointsT fp16: 8*16384*128*2 = 33,554,432
#define O_IDX   33554432ull          // idx int32: 8192*64*4 = 2,097,152
#define O_MAXB  35651584ull          // 8192*256*4 = 8,388,608
#define O_MINB  44040192ull          // 8,388,608
#define O_W0T   52428800ull          // W0h fp16 [128][136] = 34,816
#define O_W1T   52463616ull          // W1h fp16 [128][136] = 34,816
#define O_W2T   52498432ull          // W2h fp16 [256][136] = 69,632
#define O_PS0   52568064ull          // per-block partials [8192][128] f32 = 4,194,304
#define O_PQ0   56762368ull          // 4,194,304
#define O_PS1   60956672ull          // 4,194,304
#define O_PQ1   65150976ull          // 4,194,304
#define O_PS2   69345280ull          // [8192][256] f32 = 8,388,608
#define O_PQ2   77733888ull          // 8,388,608
#define O_SC0   86122496ull
#define O_SH0   86123008ull
#define O_SC1   86123520ull
#define O_SH1   86124032ull
#define O_SC2   86124544ull
#define O_SH2   86125568ull
#define O_Y     86126592ull          // y fp16 [8192][64][128] = 134,217,728 (in-place L0->L1)
#define WS_NEEDED 220344320ull

#define OUT_XYZ 0
#define OUT_FEAT 24576
#define OUT_FPS (24576 + 2097152)

// fallback when workspace undersized
__global__ __launch_bounds__(256) void k_newxyz(const float* __restrict__ xyz, const int* __restrict__ fps,
                                                float* __restrict__ out) {
  int id = blockIdx.x * 256 + threadIdx.x;  // B*S
  int fi = fps[id];
  int b = id >> 10;
  const float* p = xyz + ((size_t)b * NN + fi) * 3;
  float* o = out + OUT_XYZ + (size_t)id * 3;
  o[0] = p[0]; o[1] = p[1]; o[2] = p[2];
  out[OUT_FPS + id] = (float)fi;
}

// ---- merged front kernel: transpose (blocks 0..4095) | ballq (4096..6143) | wt (6144..6415) ----
__global__ __launch_bounds__(256) void k_front(const float* __restrict__ pts, _Float16* __restrict__ ptsT,
                                               const float* __restrict__ W0, const float* __restrict__ W1,
                                               const float* __restrict__ W2, _Float16* __restrict__ W0h,
                                               _Float16* __restrict__ W1h, _Float16* __restrict__ W2h,
                                               const float* __restrict__ xyz, const int* __restrict__ fps,
                                               int* __restrict__ idxb, float* __restrict__ out) {
  __shared__ float tile[64][65];
  int id = blockIdx.x;
  int t = threadIdx.x;
  if (id < 4096) {
    // transpose: points [B,D,N] fp32 -> pointsT [B,N,D] fp16, 64n x 64c tile
    int b = id >> 9;
    int c0 = ((id >> 8) & 1) * 64;
    int n0 = (id & 255) * 64;
    int cg = t >> 6, ln = t & 63;
#pragma unroll
    for (int k = 0; k < 16; k++) {
      int c = cg * 16 + k;
      tile[c][ln] = pts[((size_t)b * DD + c0 + c) * NN + n0 + ln];
    }
    __syncthreads();
    int n = t >> 2, sub = t & 3;
#pragma unroll
    for (int j = 0; j < 2; j++) {
      int cb = sub * 16 + j * 8;
      half8t h;
#pragma unroll
      for (int k = 0; k < 8; k++) h[k] = (_Float16)tile[cb + k][n];
      *(half8t*)(ptsT + ((size_t)b * NN + n0 + n) * DD + c0 + cb) = h;
    }
  } else if (id < 6144) {
    // ballq: one wave per (b,s); 4 points/lane/iter with 1-deep software prefetch.
    // first-NS ascending, pad with first valid; distance arithmetic bit-identical.
    int w = ((id - 4096) * 256 + t) >> 6;
    int lane = t & 63;
    int b = w >> 10;
    int fi = fps[w];
    const float* cp = xyz + ((size_t)b * NN + fi) * 3;
    float cx = cp[0], cy = cp[1], cz = cp[2];
    if (lane < 3) out[OUT_XYZ + (size_t)w * 3 + lane] = (lane == 0) ? cx : ((lane == 1) ? cy : cz);
    if (lane == 3) out[OUT_FPS + w] = (float)fi;
    float A = __fadd_rn(__fadd_rn(__fmul_rn(cx, cx), __fmul_rn(cy, cy)), __fmul_rn(cz, cz));
    const float* xb = xyz + (size_t)b * NN * 3;
    int cnt = 0, firstn = -1;
    int* myidx = idxb + (size_t)w * NSMP;
    unsigned long long below = (lane == 0) ? 0ull : (~0ull >> (64 - lane));
    // preload chunk 0
    const f32x4* p4 = (const f32x4*)(xb + (size_t)(lane * 4) * 3);
    f32x4 f0 = p4[0], f1 = p4[1], f2 = p4[2];
    for (int nb = 0; nb < NN && cnt < NSMP; nb += 256) {
      // prefetch next chunk (clamped; wasted on last/exit iterations — harmless)
      int nbn = (nb + 256 < NN) ? nb + 256 : nb;
      const f32x4* p4n = (const f32x4*)(xb + (size_t)(nbn + lane * 4) * 3);
      f32x4 g0 = p4n[0], g1 = p4n[1], g2 = p4n[2];
      int n0 = nb + lane * 4;
      float px[4] = {f0[0], f0[3], f1[2], f2[1]};
      float py[4] = {f0[1], f1[0], f1[3], f2[2]};
      float pz[4] = {f0[2], f1[1], f2[0], f2[3]};
      unsigned m = 0;
#pragma unroll
      for (int j = 0; j < 4; j++) {
        float Bv = __fadd_rn(__fadd_rn(__fmul_rn(px[j], px[j]), __fmul_rn(py[j], py[j])),
                             __fmul_rn(pz[j], pz[j]));
        float dot = __fadd_rn(__fadd_rn(__fmul_rn(cx, px[j]), __fmul_rn(cy, py[j])),
                              __fmul_rn(cz, pz[j]));
        float d = __fsub_rn(__fadd_rn(A, Bv), __fmul_rn(2.0f, dot));
        if (!(d > R2)) m |= 1u << j;
      }
      unsigned long long bl0 = __ballot((m & 1u) != 0u);
      unsigned long long bl1 = __ballot((m & 2u) != 0u);
      unsigned long long bl2 = __ballot((m & 4u) != 0u);
      unsigned long long bl3 = __ballot((m & 8u) != 0u);
      unsigned long long anyb = bl0 | bl1 | bl2 | bl3;
      if (firstn < 0 && anyb) {
        int l0 = __builtin_ctzll(anyb);
        int j0 = ((bl0 >> l0) & 1ull) ? 0 : ((bl1 >> l0) & 1ull) ? 1 : ((bl2 >> l0) & 1ull) ? 2 : 3;
        firstn = nb + l0 * 4 + j0;
      }
      int excl = __popcll(bl0 & below) + __popcll(bl1 & below) +
                 __popcll(bl2 & below) + __popcll(bl3 & below);
      int pos = cnt + excl;
#pragma unroll
      for (int j = 0; j < 4; j++) {
        if (m & (1u << j)) {
          if (pos < NSMP) myidx[pos] = n0 + j;
          pos++;
        }
      }
      cnt += __popcll(bl0) + __popcll(bl1) + __popcll(bl2) + __popcll(bl3);
      if (cnt > NSMP) cnt = NSMP;
      f0 = g0; f1 = g1; f2 = g2;
    }
    if (lane >= cnt) myidx[lane] = firstn;
  } else {
    // wt: weights -> fp16, [out][in] stride 136, zero-padded; W0 remapped
    int idw = (id - 6144) * 256 + t;
    const int T0 = 128 * 136, T1 = 128 * 136, T2 = 256 * 136;
    if (idw < T0) {
      int o = idw / 136, c = idw % 136;
      float v = 0.f;
      if (c < 131) {
        int c0 = (c < 128) ? (c + 3) : (c - 128);
        v = W0[o * 131 + c0];
      }
      W0h[idw] = (_Float16)v;
    } else if (idw < T0 + T1) {
      int j = idw - T0;
      int o = j / 136, c = j % 136;
      W1h[j] = (_Float16)((c < 128) ? W1[o * 128 + c] : 0.f);
    } else if (idw < T0 + T1 + T2) {
      int j = idw - T0 - T1;
      int o = j / 136, c = j % 136;
      W2h[j] = (_Float16)((c < 128) ? W2[o * 128 + c] : 0.f);
    }
  }
}

// ---------- shared device pieces ----------

template <int NT>
__device__ __forceinline__ void load_wregs(const _Float16* __restrict__ Wh,
                                           const float* __restrict__ bias, int cb, int lr, int lk,
                                           half8t bw[NT][4], float bv[NT]) {
#pragma unroll
  for (int nt = 0; nt < NT; nt++) {
#pragma unroll
    for (int kt = 0; kt < 4; kt++)
      bw[nt][kt] = *(const half8t*)(Wh + (cb + nt * 16 + lr) * 136 + kt * 32 + lk * 8);
    bv[nt] = bias[cb + nt * 16 + lr];
  }
}

template <int NT>
__device__ __forceinline__ void mfma_cols(const _Float16* xh, const half8t bw[NT][4],
                                          const float bv[NT], int lr, int lk, f32x4 acc[4][NT]) {
#pragma unroll
  for (int m = 0; m < 4; m++) {
    half8t afr[4];
#pragma unroll
    for (int kt = 0; kt < 4; kt++)
      afr[kt] = *(const half8t*)(xh + (m * 16 + lr) * 136 + kt * 32 + lk * 8);
#pragma unroll
    for (int nt = 0; nt < NT; nt++) {
      f32x4 cv = {bv[nt], bv[nt], bv[nt], bv[nt]};
      acc[m][nt] = cv;
    }
#pragma unroll
    for (int kt = 0; kt < 4; kt++)
#pragma unroll
      for (int nt = 0; nt < NT; nt++)
        acc[m][nt] = __builtin_amdgcn_mfma_f32_16x16x32_f16(afr[kt], bw[nt][kt], acc[m][nt], 0, 0, 0);
  }
}

__device__ __forceinline__ void gather_tile(const float* __restrict__ xyz,
                                            const _Float16* __restrict__ ptsT,
                                            int b, int t, const int* smidx, const float* smc,
                                            _Float16* xh) {
  int row = t >> 2, qd = t & 3;
  int n = smidx[row];
  const half8t* src = (const half8t*)(ptsT + ((size_t)b * NN + n) * DD);
#pragma unroll
  for (int i = 0; i < 4; i++) {
    int j = qd + i * 4;
    *(half8t*)(xh + row * 136 + j * 8) = src[j];
  }
  if (t < 64) {
    int n2 = smidx[t];
    const float* p = xyz + ((size_t)b * NN + n2) * 3;
    xh[t * 136 + 128] = (_Float16)(p[0] - smc[0]);
    xh[t * 136 + 129] = (_Float16)(p[1] - smc[1]);
    xh[t * 136 + 130] = (_Float16)(p[2] - smc[2]);
  }
}

__device__ __forceinline__ void load_wx(const _Float16* __restrict__ W0h, int cb, int lr,
                                        float wx[2][3]) {
#pragma unroll
  for (int nt = 0; nt < 2; nt++) {
    const _Float16* wp = W0h + (cb + nt * 16 + lr) * 136 + 128;
    wx[nt][0] = (float)wp[0]; wx[nt][1] = (float)wp[1]; wx[nt][2] = (float)wp[2];
  }
}

__device__ __forceinline__ void add_relxyz(const _Float16* xh, const float wx[2][3],
                                           int lr, int lk, f32x4 acc[4][2]) {
#pragma unroll
  for (int m = 0; m < 4; m++) {
#pragma unroll
    for (int r = 0; r < 4; r++) {
      int row = m * 16 + lk * 4 + r;
      float x0 = (float)xh[row * 136 + 128];
      float x1 = (float)xh[row * 136 + 129];
      float x2 = (float)xh[row * 136 + 130];
#pragma unroll
      for (int nt = 0; nt < 2; nt++)
        acc[m][nt][r] += x0 * wx[nt][0] + x1 * wx[nt][1] + x2 * wx[nt][2];
    }
  }
}

__device__ __forceinline__ void load_y_regs(const _Float16* __restrict__ yb, int t, half8t r[4]) {
#pragma unroll
  for (int i = 0; i < 4; i++) r[i] = *(const half8t*)(yb + (i * 256 + t) * 8);
}

__device__ __forceinline__ void aff_store(const half8t r[4], const float* __restrict__ sc,
                                          const float* __restrict__ sh, int t, _Float16* xh) {
#pragma unroll
  for (int i = 0; i < 4; i++) {
    int flat = (i * 256 + t) * 8;
    int row = flat >> 7, col = flat & 127;
    half8t o;
#pragma unroll
    for (int k = 0; k < 8; k++)
      o[k] = (_Float16)fmaxf(fmaf((float)r[i][k], sc[col + k], sh[col + k]), 0.f);
    *(half8t*)(xh + row * 136 + col) = o;
  }
}

template <int NT>
__device__ __forceinline__ void stats_cols(const f32x4 acc[4][NT], int lane, int cb, int lr,
                                           float* __restrict__ psum, float* __restrict__ psq,
                                           int bs, int nch) {
  float s[NT], q[NT];
#pragma unroll
  for (int nt = 0; nt < NT; nt++) { s[nt] = 0.f; q[nt] = 0.f; }
#pragma unroll
  for (int m = 0; m < 4; m++)
#pragma unroll
    for (int nt = 0; nt < NT; nt++) {
      f32x4 a = acc[m][nt];
      s[nt] += (a[0] + a[1]) + (a[2] + a[3]);
      q[nt] += fmaf(a[0], a[0], fmaf(a[1], a[1], fmaf(a[2], a[2], a[3] * a[3])));
    }
#pragma unroll
  for (int nt = 0; nt < NT; nt++) {
    s[nt] += __shfl_xor(s[nt], 16);
    s[nt] += __shfl_xor(s[nt], 32);
    q[nt] += __shfl_xor(q[nt], 16);
    q[nt] += __shfl_xor(q[nt], 32);
  }
  if (lane < 16) {
#pragma unroll
    for (int nt = 0; nt < NT; nt++) {
      int col = cb + nt * 16 + lr;
      psum[(size_t)bs * nch + col] = s[nt];
      psq[(size_t)bs * nch + col] = q[nt];
    }
  }
}

template <int NT>
__device__ __forceinline__ void write_y_cols(_Float16* __restrict__ yb, int cb, int lr, int lk,
                                             const f32x4 acc[4][NT]) {
#pragma unroll
  for (int nt = 0; nt < NT; nt++) {
    int col = cb + nt * 16 + lr;
#pragma unroll
    for (int m = 0; m < 4; m++)
#pragma unroll
      for (int r = 0; r < 4; r++)
        yb[(m * 16 + lk * 4 + r) * 128 + col] = (_Float16)acc[m][nt][r];
  }
}

__device__ __forceinline__ void l2_compute(const _Float16* xh, const half8t bw[4][4], const float bv[4],
                                           int lane, int lr, int lk, int cq, int bs,
                                           float* __restrict__ maxb, float* __restrict__ minb,
                                           float* __restrict__ psum, float* __restrict__ psq) {
  float s[4] = {0.f, 0.f, 0.f, 0.f}, q[4] = {0.f, 0.f, 0.f, 0.f};
  float mx[4], mn[4];
#pragma unroll
  for (int nt = 0; nt < 4; nt++) { mx[nt] = -3.4e38f; mn[nt] = 3.4e38f; }
#pragma unroll
  for (int m = 0; m < 4; m++) {
    half8t afr[4];
#pragma unroll
    for (int kt = 0; kt < 4; kt++)
      afr[kt] = *(const half8t*)(xh + (m * 16 + lr) * 136 + kt * 32 + lk * 8);
    f32x4 a2[4];
#pragma unroll
    for (int nt = 0; nt < 4; nt++) {
      f32x4 cv = {bv[nt], bv[nt], bv[nt], bv[nt]};
      a2[nt] = cv;
    }
#pragma unroll
    for (int kt = 0; kt < 4; kt++)
#pragma unroll
      for (int nt = 0; nt < 4; nt++)
        a2[nt] = __builtin_amdgcn_mfma_f32_16x16x32_f16(afr[kt], bw[nt][kt], a2[nt], 0, 0, 0);
#pragma unroll
    for (int nt = 0; nt < 4; nt++) {
      f32x4 a = a2[nt];
      s[nt] += (a[0] + a[1]) + (a[2] + a[3]);
      q[nt] += fmaf(a[0], a[0], fmaf(a[1], a[1], fmaf(a[2], a[2], a[3] * a[3])));
      mx[nt] = fmaxf(mx[nt], fmaxf(fmaxf(a[0], a[1]), fmaxf(a[2], a[3])));
      mn[nt] = fminf(mn[nt], fminf(fminf(a[0], a[1]), fminf(a[2], a[3])));
    }
  }
#pragma unroll
  for (int nt = 0; nt < 4; nt++) {
    s[nt] += __shfl_xor(s[nt], 16);
    s[nt] += __shfl_xor(s[nt], 32);
    q[nt] += __shfl_xor(q[nt], 16);
    q[nt] += __shfl_xor(q[nt], 32);
    mx[nt] = fmaxf(mx[nt], __shfl_xor(mx[nt], 16));
    mx[nt] = fmaxf(mx[nt], __shfl_xor(mx[nt], 32));
    mn[nt] = fminf(mn[nt], __shfl_xor(mn[nt], 16));
    mn[nt] = fminf(mn[nt], __shfl_xor(mn[nt], 32));
  }
  if (lane < 16) {
#pragma unroll
    for (int nt = 0; nt < 4; nt++) {
      int col = cq + nt * 16 + lr;
      maxb[(size_t)bs * 256 + col] = mx[nt];
      minb[(size_t)bs * 256 + col] = mn[nt];
      psum[(size_t)bs * 256 + col] = s[nt];
      psq[(size_t)bs * 256 + col] = q[nt];
    }
  }
}

// ---------- pipelined passes ----------

// pass1: 2 tiles, gathers issued back-to-back (2x MLP)
__global__ __launch_bounds__(256) void k_pass1(const float* __restrict__ xyz,
                                               const _Float16* __restrict__ ptsT,
                                               const int* __restrict__ fps, const int* __restrict__ idxb,
                                               const _Float16* __restrict__ W0h, const float* __restrict__ b0,
                                               _Float16* __restrict__ y,
                                               float* __restrict__ psum, float* __restrict__ psq) {
  __shared__ _Float16 xh0[64 * 136], xh1[64 * 136];
  __shared__ int smidx0[64], smidx1[64];
  __shared__ float smc0[3], smc1[3];
  int t = threadIdx.x;
  int bs0 = blockIdx.x * 2, bs1 = bs0 + 1;
  int b = bs0 >> 10;
  if (t < 64) {
    smidx0[t] = idxb[(size_t)bs0 * 64 + t];
    smidx1[t] = idxb[(size_t)bs1 * 64 + t];
  }
  if (t < 3) {
    smc0[t] = xyz[((size_t)b * NN + fps[bs0]) * 3 + t];
    smc1[t] = xyz[((size_t)b * NN + fps[bs1]) * 3 + t];
  }
  __syncthreads();
  gather_tile(xyz, ptsT, b, t, smidx0, smc0, xh0);
  gather_tile(xyz, ptsT, b, t, smidx1, smc1, xh1);
  int lane = t & 63, wv = t >> 6;
  int lr = lane & 15, lk = lane >> 4;
  int cb = __builtin_amdgcn_readfirstlane(wv * 32);
  half8t bw[2][4];
  float bv[2], wx[2][3];
  load_wregs<2>(W0h, b0, cb, lr, lk, bw, bv);
  load_wx(W0h, cb, lr, wx);
  __syncthreads();
  f32x4 acc[4][2];
  mfma_cols<2>(xh0, bw, bv, lr, lk, acc);
  add_relxyz(xh0, wx, lr, lk, acc);
  stats_cols<2>(acc, lane, cb, lr, psum, psq, bs0, 128);
  write_y_cols<2>(y + (size_t)bs0 * 8192, cb, lr, lk, acc);
  mfma_cols<2>(xh1, bw, bv, lr, lk, acc);
  add_relxyz(xh1, wx, lr, lk, acc);
  stats_cols<2>(acc, lane, cb, lr, psum, psq, bs1, 128);
  write_y_cols<2>(y + (size_t)bs1 * 8192, cb, lr, lk, acc);
}

// pass2: 4 tiles/block, alternating rA/rB staging (y loads hidden under MFMA)
__global__ __launch_bounds__(256) void k_pass2(const float* __restrict__ sc0, const float* __restrict__ sh0,
                                               const _Float16* __restrict__ W1h, const float* __restrict__ b1,
                                               _Float16* __restrict__ y,
                                               float* __restrict__ psum, float* __restrict__ psq) {
  __shared__ _Float16 xh0[64 * 136], xh1[64 * 136];
  int t = threadIdx.x;
  int bs0 = blockIdx.x * 4;
  _Float16* yb0 = y + (size_t)bs0 * 8192;
  _Float16* yb1 = y + (size_t)(bs0 + 1) * 8192;
  _Float16* yb2 = y + (size_t)(bs0 + 2) * 8192;
  _Float16* yb3 = y + (size_t)(bs0 + 3) * 8192;
  int lane = t & 63, wv = t >> 6;
  int lr = lane & 15, lk = lane >> 4;
  int cb = __builtin_amdgcn_readfirstlane(wv * 32);
  half8t rA[4], rB[4];
  load_y_regs(yb0, t, rA);
  load_y_regs(yb1, t, rB);
  half8t bw[2][4];
  float bv[2];
  load_wregs<2>(W1h, b1, cb, lr, lk, bw, bv);
  f32x4 acc[4][2];
  aff_store(rA, sc0, sh0, t, xh0);
  __syncthreads();
  load_y_regs(yb2, t, rA);  // in flight during tile0 compute
  mfma_cols<2>(xh0, bw, bv, lr, lk, acc);
  stats_cols<2>(acc, lane, cb, lr, psum, psq, bs0, 128);
  write_y_cols<2>(yb0, cb, lr, lk, acc);
  aff_store(rB, sc0, sh0, t, xh1);
  __syncthreads();
  load_y_regs(yb3, t, rB);  // in flight during tile1 compute
  mfma_cols<2>(xh1, bw, bv, lr, lk, acc);
  stats_cols<2>(acc, lane, cb, lr, psum, psq, bs0 + 1, 128);
  write_y_cols<2>(yb1, cb, lr, lk, acc);
  aff_store(rA, sc0, sh0, t, xh0);
  __syncthreads();
  mfma_cols<2>(xh0, bw, bv, lr, lk, acc);
  stats_cols<2>(acc, lane, cb, lr, psum, psq, bs0 + 2, 128);
  write_y_cols<2>(yb2, cb, lr, lk, acc);
  aff_store(rB, sc0, sh0, t, xh1);
  __syncthreads();
  mfma_cols<2>(xh1, bw, bv, lr, lk, acc);
  stats_cols<2>(acc, lane, cb, lr, psum, psq, bs0 + 3, 128);
  write_y_cols<2>(yb3, cb, lr, lk, acc);
}

// pass3: 4 tiles/block, same staging; L2 -> max/min + stats
__global__ __launch_bounds__(256) void k_pass3(const float* __restrict__ sc1, const float* __restrict__ sh1,
                                               const _Float16* __restrict__ W2h, const float* __restrict__ b2,
                                               const _Float16* __restrict__ y,
                                               float* __restrict__ maxb, float* __restrict__ minb,
                                               float* __restrict__ psum, float* __restrict__ psq) {
  __shared__ _Float16 xh0[64 * 136], xh1[64 * 136];
  int t = threadIdx.x;
  int bs0 = blockIdx.x * 4;
  int lane = t & 63, wv = t >> 6;
  int lr = lane & 15, lk = lane >> 4;
  int cq = __builtin_amdgcn_readfirstlane(wv * 64);
  half8t rA[4], rB[4];
  load_y_regs(y + (size_t)bs0 * 8192, t, rA);
  load_y_regs(y + (size_t)(bs0 + 1) * 8192, t, rB);
  half8t bw[4][4];
  float bv[4];
  load_wregs<4>(W2h, b2, cq, lr, lk, bw, bv);
  aff_store(rA, sc1, sh1, t, xh0);
  __syncthreads();
  load_y_regs(y + (size_t)(bs0 + 2) * 8192, t, rA);
  l2_compute(xh0, bw, bv, lane, lr, lk, cq, bs0, maxb, minb, psum, psq);
  aff_store(rB, sc1, sh1, t, xh1);
  __syncthreads();
  load_y_regs(y + (size_t)(bs0 + 3) * 8192, t, rB);
  l2_compute(xh1, bw, bv, lane, lr, lk, cq, bs0 + 1, maxb, minb, psum, psq);
  aff_store(rA, sc1, sh1, t, xh0);
  __syncthreads();
  l2_compute(xh0, bw, bv, lane, lr, lk, cq, bs0 + 2, maxb, minb, psum, psq);
  aff_store(rB, sc1, sh1, t, xh1);
  __syncthreads();
  l2_compute(xh1, bw, bv, lane, lr, lk, cq, bs0 + 3, maxb, minb, psum, psq);
}

// fold BN stats into per-channel affine: a = g*rsqrt(var+eps); c = be - mean*a
__global__ __launch_bounds__(256) void k_fin(const float* __restrict__ psum, const float* __restrict__ psq,
                                             const float* __restrict__ g, const float* __restrict__ be,
                                             float* __restrict__ sc, float* __restrict__ sh, int nch) {
  int o = blockIdx.x, t = threadIdx.x;
  float s = 0.f, q = 0.f;
  for (int k = t; k < 8192; k += 256) {
    s += psum[(size_t)k * nch + o];
    q += psq[(size_t)k * nch + o];
  }
#pragma unroll
  for (int off = 32; off > 0; off >>= 1) {
    s += __shfl_down(s, off);
    q += __shfl_down(q, off);
  }
  __shared__ float rs[4], rq[4];
  if ((t & 63) == 0) { rs[t >> 6] = s; rq[t >> 6] = q; }
  __syncthreads();
  if (t == 0) {
    s = (rs[0] + rs[1]) + (rs[2] + rs[3]);
    q = (rq[0] + rq[1]) + (rq[2] + rq[3]);
    const float inv = 1.0f / 524288.0f;
    float m = s * inv;
    float ey2 = q * inv;
    float v = fmaf(-m, m, ey2);
    v = fmaxf(v, 0.f);
    float r = rsqrtf(v + EPSV);
    float a = g[o] * r;
    sc[o] = a;
    sh[o] = fmaf(-m, a, be[o]);
  }
}

// out[b, o, s] = relu(a*sel + c); 64s x 64o tile via LDS transpose:
// reads coalesced along o (was 16x overfetch at stride-1KB), writes coalesced along s.
__global__ __launch_bounds__(256) void k_out(const float* __restrict__ maxb, const float* __restrict__ minb,
                                             const float* __restrict__ sc, const float* __restrict__ sh,
                                             float* __restrict__ out) {
  __shared__ float tile[64][65];
  int id = blockIdx.x;  // 512 = b(8) x ot(4) x st(16)
  int b = id >> 6;
  int ot = (id >> 4) & 3;
  int st = id & 15;
  int o0 = ot * 64, s0 = st * 64;
  int t = threadIdx.x;
  {
    int oc = t & 63, sr = t >> 6;
    float a = sc[o0 + oc], c_ = sh[o0 + oc];
    const float* src = (a >= 0.f) ? maxb : minb;
#pragma unroll
    for (int i = 0; i < 16; i++) {
      int s = s0 + sr + i * 4;
      float v = src[((size_t)(b * 1024 + s)) * 256 + o0 + oc];
      tile[sr + i * 4][oc] = fmaxf(fmaf(a, v, c_), 0.f);
    }
  }
  __syncthreads();
  {
    int scol = t & 63, orow = t >> 6;
#pragma unroll
    for (int i = 0; i < 16; i++) {
      int o = orow + i * 4;
      out[OUT_FEAT + (size_t)b * 262144 + (size_t)(o0 + o) * 1024 + s0 + scol] = tile[scol][o];
    }
  }
}

extern "C" void kernel_launch(void* const* d_in, const int* in_sizes, int n_in,
                              void* d_out, int out_size, void* d_ws, size_t ws_size,
                              hipStream_t stream) {
  const float* xyz = (const float*)d_in[0];
  const float* pts = (const float*)d_in[1];
  const int* fps = (const int*)d_in[2];
  const float* W0 = (const float*)d_in[3];
  const float* b0 = (const float*)d_in[4];
  const float* g0 = (const float*)d_in[5];
  const float* be0 = (const float*)d_in[6];
  const float* W1 = (const float*)d_in[7];
  const float* b1 = (const float*)d_in[8];
  const float* g1 = (const float*)d_in[9];
  const float* be1 = (const float*)d_in[10];
  const float* W2 = (const float*)d_in[11];
  const float* b2 = (const float*)d_in[12];
  const float* g2 = (const float*)d_in[13];
  const float* be2 = (const float*)d_in[14];
  float* out = (float*)d_out;
  char* ws = (char*)d_ws;

  if (ws_size < WS_NEEDED) {
    k_newxyz<<<32, 256, 0, stream>>>(xyz, fps, out);
    return;
  }

  _Float16* ptsT = (_Float16*)(ws + O_PT);
  int* idxb = (int*)(ws + O_IDX);
  float* maxbf = (float*)(ws + O_MAXB);
  float* minbf = (float*)(ws + O_MINB);
  _Float16* W0h = (_Float16*)(ws + O_W0T);
  _Float16* W1h = (_Float16*)(ws + O_W1T);
  _Float16* W2h = (_Float16*)(ws + O_W2T);
  float* ps0 = (float*)(ws + O_PS0);
  float* pq0 = (float*)(ws + O_PQ0);
  float* ps1 = (float*)(ws + O_PS1);
  float* pq1 = (float*)(ws + O_PQ1);
  float* ps2 = (float*)(ws + O_PS2);
  float* pq2 = (float*)(ws + O_PQ2);
  float* sc0 = (float*)(ws + O_SC0);
  float* sh0 = (float*)(ws + O_SH0);
  float* sc1 = (float*)(ws + O_SC1);
  float* sh1 = (float*)(ws + O_SH1);
  float* sc2 = (float*)(ws + O_SC2);
  float* sh2 = (float*)(ws + O_SH2);
  _Float16* y = (_Float16*)(ws + O_Y);

  k_front<<<6416, 256, 0, stream>>>(pts, ptsT, W0, W1, W2, W0h, W1h, W2h, xyz, fps, idxb, out);
  k_pass1<<<4096, 256, 0, stream>>>(xyz, ptsT, fps, idxb, W0h, b0, y, ps0, pq0);
  k_fin<<<128, 256, 0, stream>>>(ps0, pq0, g0, be0, sc0, sh0, 128);
  k_pass2<<<2048, 256, 0, stream>>>(sc0, sh0, W1h, b1, y, ps1, pq1);
  k_fin<<<128, 256, 0, stream>>>(ps1, pq1, g1, be1, sc1, sh1, 128);
  k_pass3<<<2048, 256, 0, stream>>>(sc1, sh1, W2h, b2, y, maxbf, minbf, ps2, pq2);
  k_fin<<<256, 256, 0, stream>>>(ps2, pq2, g2, be2, sc2, sh2, 256);
  k_out<<<512, 256, 0, stream>>>(maxbf, minbf, sc2, sh2, out);
}